// Round 1
// baseline (647.026 us; speedup 1.0000x reference)
//
#include <hip/hip_runtime.h>
#include <stdint.h>

#define Nn 2048
#define Ff 1024
#define Mm 128
#define Cc 100
#define Ss 32
#define TS 116   // LDS table stride in floats (>=112, mult of 4, bank-friendly)
#define CS 28    // c-slice per lane (4 lanes * 28 = 112 >= 100)

// counter-based RNG, identical for all lanes of a chain
__device__ __forceinline__ float urand(uint32_t chain, uint32_t ctr) {
  uint64_t xx = (((uint64_t)chain) << 32) ^ (uint64_t)ctr;
  xx += 0x9E3779B97F4A7C15ULL;
  xx = (xx ^ (xx >> 30)) * 0xBF58476D1CE4E5B9ULL;
  xx = (xx ^ (xx >> 27)) * 0x94D049BB133111EBULL;
  xx ^= (xx >> 31);
  return (float)((uint32_t)(xx >> 40)) * (1.0f / 16777216.0f);
}

// ---------------- Kernel A: linear_pi = alpha_0 + x @ alpha^T  (N,M) ----------------
__global__ __launch_bounds__(256) void k_linpi(const float* __restrict__ x,
                                               const float* __restrict__ alpha0,
                                               const float* __restrict__ alpha,
                                               float* __restrict__ lpi) {
  __shared__ float xs[8 * 64];
  __shared__ float as[128 * 68];
  const int t = threadIdx.x;
  const int n0 = blockIdx.x * 8;
  const int m = t & 127;
  const int np = t >> 7;
  float acc[4] = {0.f, 0.f, 0.f, 0.f};
  for (int kk = 0; kk < 16; ++kk) {
    __syncthreads();
    // stage x tile: 8 rows x 64 f
    xs[t] = x[(n0 + (t >> 6)) * Ff + kk * 64 + (t & 63)];
    xs[t + 256] = x[(n0 + 4 + (t >> 6)) * Ff + kk * 64 + (t & 63)];
    // stage alpha tile: 128 m x 64 f (row-major, stride 68)
    #pragma unroll
    for (int r = 0; r < 8; ++r) {
      int idx4 = t + r * 256;
      int mm = idx4 >> 4, f4 = idx4 & 15;
      float4 v = *(const float4*)&alpha[mm * Ff + kk * 64 + f4 * 4];
      *(float4*)&as[mm * 68 + f4 * 4] = v;
    }
    __syncthreads();
    #pragma unroll
    for (int f4 = 0; f4 < 16; ++f4) {
      float4 a = *(const float4*)&as[m * 68 + f4 * 4];
      #pragma unroll
      for (int r = 0; r < 4; ++r) {
        float4 xv = *(const float4*)&xs[(np * 4 + r) * 64 + f4 * 4];
        acc[r] += a.x * xv.x + a.y * xv.y + a.z * xv.z + a.w * xv.w;
      }
    }
  }
  float a0v = alpha0[m];
  #pragma unroll
  for (int r = 0; r < 4; ++r)
    lpi[(n0 + np * 4 + r) * Mm + m] = acc[r] + a0v;
}

// ---------------- Kernel B: init + one Gibbs sweep, 4 lanes per chain ----------------
__global__ __launch_bounds__(512) void k_gibbs(const float* __restrict__ beta0,
                                               const float* __restrict__ beta,
                                               const int* __restrict__ y,
                                               const float* __restrict__ lpi,
                                               float* __restrict__ lse_out,
                                               uint32_t* __restrict__ zbits_out) {
  __shared__ float tab[Mm * TS];   // tab[j*TS + c] = exp(2*beta[c][j]); pad c>=100 -> 1.0
  __shared__ float elpi[4 * Mm];   // exp(linear_pi) for this block's 4 rows
  __shared__ int yl[4];
  const int t = threadIdx.x;
  const int n0 = blockIdx.x * 4;

  // build ep2 table (coalesced beta reads, scattered LDS writes - one-time)
  for (int idx = t; idx < Cc * (Mm / 4); idx += 512) {
    int c = idx >> 5;        // Mm/4 == 32
    int j4 = idx & 31;
    float4 bv = *(const float4*)&beta[c * Mm + j4 * 4];
    tab[(j4 * 4 + 0) * TS + c] = __expf(2.0f * bv.x);
    tab[(j4 * 4 + 1) * TS + c] = __expf(2.0f * bv.y);
    tab[(j4 * 4 + 2) * TS + c] = __expf(2.0f * bv.z);
    tab[(j4 * 4 + 3) * TS + c] = __expf(2.0f * bv.w);
  }
  for (int idx = t; idx < Mm * (TS - Cc); idx += 512) {
    int j = idx >> 4;        // TS-Cc == 16
    int c = Cc + (idx & 15);
    tab[j * TS + c] = 1.0f;
  }
  {
    int nl = t >> 7, j = t & 127;
    elpi[t] = __expf(lpi[(n0 + nl) * Mm + j]);
  }
  if (t < 4) yl[t] = y[n0 + t];
  __syncthreads();

  const int cl = t >> 2;                    // chain within block, 0..127
  const int q = t & 3;                      // lane within chain
  const int nl = cl >> 5;                   // 0..3
  const int s = cl & 31;
  const uint32_t chain = (uint32_t)((n0 + nl) * Ss + s);
  const int c0 = q * CS;
  const int yv = yl[nl];
  const float* elrow = &elpi[nl * Mm];
  const int lane = t & 63;

  // ---- init Z0 ~ 2*Bern(sigmoid(lpi))-1 : lane q draws word q, then share ----
  uint32_t zw0, zw1, zw2, zw3;
  {
    uint32_t zz = 0;
    for (int b5 = 0; b5 < 32; ++b5) {
      int m = q * 32 + b5;
      float u = urand(chain, (uint32_t)m);
      float el = elrow[m];
      zz |= (u * (1.0f + el) < el) ? (1u << b5) : 0u;
    }
    int base = lane & ~3;
    zw0 = (uint32_t)__shfl((int)zz, base + 0);
    zw1 = (uint32_t)__shfl((int)zz, base + 1);
    zw2 = (uint32_t)__shfl((int)zz, base + 2);
    zw3 = (uint32_t)__shfl((int)zz, base + 3);
  }

  // ---- init E = exp(beta_0 + Z0 . beta) over my c-slice ----
  float E[CS];
  #pragma unroll
  for (int i = 0; i < CS; ++i) {
    int c = c0 + i;
    int cc = (c < Cc) ? c : 0;
    float acc = beta0[cc];
    const float* bp = &beta[cc * Mm];
    #pragma unroll
    for (int w = 0; w < 4; ++w) {
      uint32_t zz = (w == 0) ? zw0 : ((w == 1) ? zw1 : ((w == 2) ? zw2 : zw3));
      #pragma unroll 1
      for (int m4 = 0; m4 < 8; ++m4) {
        float4 bv = *(const float4*)&bp[w * 32 + m4 * 4];
        int sh = m4 * 4;
        acc += ((zz >> (sh + 0)) & 1u) ? bv.x : -bv.x;
        acc += ((zz >> (sh + 1)) & 1u) ? bv.y : -bv.y;
        acc += ((zz >> (sh + 2)) & 1u) ? bv.z : -bv.z;
        acc += ((zz >> (sh + 3)) & 1u) ? bv.w : -bv.w;
      }
    }
    E[i] = (c < Cc) ? __expf(acc) : 0.0f;
  }
  float Sb = 0.f;
  #pragma unroll
  for (int i = 0; i < CS; ++i) Sb += E[i];
  Sb += __shfl_xor(Sb, 1);
  Sb += __shfl_xor(Sb, 2);

  // ---- one Gibbs sweep over coordinates j = 0..127 ----
  #pragma unroll
  for (int w = 0; w < 4; ++w) {
    uint32_t zwv = (w == 0) ? zw0 : ((w == 1) ? zw1 : ((w == 2) ? zw2 : zw3));
    #pragma unroll 1
    for (int j5 = 0; j5 < 32; ++j5) {
      const int j = w * 32 + j5;
      const uint32_t zjp = (zwv >> j5) & 1u;   // 1 if z_j == +1
      const float* tb = &tab[j * TS + c0];
      float ts[CS];
      float D = 0.f;
      // D = sum_c E[c] * (z=+1 ? em2 : ep2)  -> the "flipped" normalizer
      #pragma unroll
      for (int i4 = 0; i4 < CS / 4; ++i4) {
        float4 tv = *(const float4*)&tb[i4 * 4];
        float r0 = __builtin_amdgcn_rcpf(tv.x);
        float r1 = __builtin_amdgcn_rcpf(tv.y);
        float r2 = __builtin_amdgcn_rcpf(tv.z);
        float r3 = __builtin_amdgcn_rcpf(tv.w);
        float s0 = zjp ? r0 : tv.x;
        float s1 = zjp ? r1 : tv.y;
        float s2 = zjp ? r2 : tv.z;
        float s3 = zjp ? r3 : tv.w;
        ts[i4 * 4 + 0] = s0; ts[i4 * 4 + 1] = s1;
        ts[i4 * 4 + 2] = s2; ts[i4 * 4 + 3] = s3;
        D = fmaf(E[i4 * 4 + 0], s0, D);
        D = fmaf(E[i4 * 4 + 1], s1, D);
        D = fmaf(E[i4 * 4 + 2], s2, D);
        D = fmaf(E[i4 * 4 + 3], s3, D);
      }
      D += __shfl_xor(D, 1);
      D += __shfl_xor(D, 2);
      float Spos = zjp ? Sb : D;
      float Sneg = zjp ? D : Sb;
      // odds = exp(2*b_j[y]) * S_neg/S_pos * pij/(1-pij)
      float odds = tab[j * TS + yv] * Sneg * __builtin_amdgcn_rcpf(Spos) * elrow[j];
      float u = urand(chain, 256u + (uint32_t)j);
      uint32_t znp = (u * (1.0f + odds) < odds) ? 1u : 0u;
      uint32_t flip = znp ^ zjp;
      bool fl = (flip != 0u);
      #pragma unroll
      for (int i = 0; i < CS; ++i) E[i] = fl ? E[i] * ts[i] : E[i];
      Sb = fl ? D : Sb;
      zwv ^= (flip << j5);
    }
    if (w == 0) zw0 = zwv; else if (w == 1) zw1 = zwv;
    else if (w == 2) zw2 = zwv; else zw3 = zwv;
  }

  // ---- outputs: logsumexp (fresh sum) + final Z bits ----
  float Sf = 0.f;
  #pragma unroll
  for (int i = 0; i < CS; ++i) Sf += E[i];
  Sf += __shfl_xor(Sf, 1);
  Sf += __shfl_xor(Sf, 2);
  if (q == 0) lse_out[chain] = __logf(Sf);
  uint32_t zz = (q == 0) ? zw0 : ((q == 1) ? zw1 : ((q == 2) ? zw2 : zw3));
  zbits_out[chain * 4u + (uint32_t)q] = zz;
}

// ---------------- Kernel C: moments + all four terms, atomic scalar reduce ----------------
__global__ __launch_bounds__(128) void k_final(const float* __restrict__ lpi,
                                               const int* __restrict__ y,
                                               const float* __restrict__ beta0,
                                               const float* __restrict__ beta,
                                               const float* __restrict__ lse_in,
                                               const uint32_t* __restrict__ zbits,
                                               float* __restrict__ out) {
  __shared__ uint32_t zs[128];
  __shared__ float red[128];
  const int n = blockIdx.x;
  const int t = threadIdx.x;
  zs[t] = zbits[n * 128 + t];   // [s][w] for this n
  __syncthreads();
  const int w = t >> 5, bsh = t & 31;
  int cnt = 0;
  #pragma unroll
  for (int s = 0; s < 32; ++s) cnt += (int)((zs[s * 4 + w] >> bsh) & 1u);
  float EI = (float)cnt * (1.0f / 32.0f);   // mean (z+1)/2
  float EII = 2.0f * EI - 1.0f;             // mean z
  float l = lpi[n * Mm + t];
  int yv = y[n];
  float sp = (l > 20.0f) ? l : log1pf(__expf(l));  // softplus, stable
  float term = EII * beta[yv * Mm + t] + EI * l - sp;
  if (t < 32) term -= lse_in[n * 32 + t] * (1.0f / 32.0f);  // -TermII contribution
  red[t] = term;
  __syncthreads();
  for (int off = 64; off > 0; off >>= 1) {
    if (t < off) red[t] += red[t + off];
    __syncthreads();
  }
  if (t == 0) atomicAdd(out, red[0] + beta0[yv]);
}

extern "C" void kernel_launch(void* const* d_in, const int* in_sizes, int n_in,
                              void* d_out, int out_size, void* d_ws, size_t ws_size,
                              hipStream_t stream) {
  const float* x = (const float*)d_in[0];
  const int* y = (const int*)d_in[1];
  const float* alpha0 = (const float*)d_in[2];
  const float* alpha = (const float*)d_in[3];
  const float* beta0 = (const float*)d_in[4];
  const float* beta = (const float*)d_in[5];
  float* out = (float*)d_out;

  char* ws = (char*)d_ws;
  float* lpi = (float*)ws;                                       // N*M f32 = 1 MB
  float* lse = (float*)(ws + (size_t)Nn * Mm * 4);               // N*S f32 = 256 KB
  uint32_t* zb = (uint32_t*)(ws + (size_t)Nn * Mm * 4 + (size_t)Nn * Ss * 4);  // N*S*4 u32 = 1 MB

  hipMemsetAsync(d_out, 0, sizeof(float), stream);
  k_linpi<<<Nn / 8, 256, 0, stream>>>(x, alpha0, alpha, lpi);
  k_gibbs<<<Nn / 4, 512, 0, stream>>>(beta0, beta, y, lpi, lse, zb);
  k_final<<<Nn, 128, 0, stream>>>(lpi, y, beta0, beta, lse, zb, out);
}

// Round 2
// 599.646 us; speedup vs baseline: 1.0790x; 1.0790x over previous
//
#include <hip/hip_runtime.h>
#include <hip/hip_fp16.h>
#include <stdint.h>

#define Nn 2048
#define Ff 1024
#define Mm 128
#define Cc 100
#define Ss 32
#define CP 112     // padded C (4 lanes x 28)
#define CS 28      // c-slice per lane
#define ELS 132    // elpi stride in floats (kills 4-way bank conflict of stride 128)

// cheap 32-bit counter-based RNG (murmur/prospector finalizer), same for all lanes of a chain
__device__ __forceinline__ float urand(uint32_t chain, uint32_t ctr) {
  uint32_t h = chain * 0x9E3779B9u ^ (ctr * 0x85EBCA6Bu);
  h ^= h >> 16; h *= 0x7FEB352Du;
  h ^= h >> 15; h *= 0x846CA68Bu;
  h ^= h >> 16;
  return (float)(h >> 8) * (1.0f / 16777216.0f);
}

// ---------------- Kernel A: linear_pi = alpha_0 + x @ alpha^T  (N,M) ----------------
__global__ __launch_bounds__(256) void k_linpi(const float* __restrict__ x,
                                               const float* __restrict__ alpha0,
                                               const float* __restrict__ alpha,
                                               float* __restrict__ lpi) {
  __shared__ float xs[8 * 64];
  __shared__ float as[128 * 68];
  const int t = threadIdx.x;
  const int n0 = blockIdx.x * 8;
  const int m = t & 127;
  const int np = t >> 7;
  float acc[4] = {0.f, 0.f, 0.f, 0.f};
  for (int kk = 0; kk < 16; ++kk) {
    __syncthreads();
    xs[t] = x[(n0 + (t >> 6)) * Ff + kk * 64 + (t & 63)];
    xs[t + 256] = x[(n0 + 4 + (t >> 6)) * Ff + kk * 64 + (t & 63)];
    #pragma unroll
    for (int r = 0; r < 8; ++r) {
      int idx4 = t + r * 256;
      int mm = idx4 >> 4, f4 = idx4 & 15;
      float4 v = *(const float4*)&alpha[mm * Ff + kk * 64 + f4 * 4];
      *(float4*)&as[mm * 68 + f4 * 4] = v;
    }
    __syncthreads();
    #pragma unroll
    for (int f4 = 0; f4 < 16; ++f4) {
      float4 a = *(const float4*)&as[m * 68 + f4 * 4];
      #pragma unroll
      for (int r = 0; r < 4; ++r) {
        float4 xv = *(const float4*)&xs[(np * 4 + r) * 64 + f4 * 4];
        acc[r] += a.x * xv.x + a.y * xv.y + a.z * xv.z + a.w * xv.w;
      }
    }
  }
  float a0v = alpha0[m];
  #pragma unroll
  for (int r = 0; r < 4; ++r)
    lpi[(n0 + np * 4 + r) * Mm + m] = acc[r] + a0v;
}

// ---------------- Kernel B: init + one Gibbs sweep, 4 lanes per chain ----------------
// LDS: tabh[0][j][c] = exp(+2*beta[c][j]) as f16, tabh[1][j][c] = exp(-2*beta[c][j]).
// Per step the z_j-dependent choice (flip factor) is ONE address select, then 7x ds_read_b64.
__global__ __launch_bounds__(512, 4) void k_gibbs(const float* __restrict__ beta0,
                                                  const float* __restrict__ beta,
                                                  const int* __restrict__ y,
                                                  const float* __restrict__ lpi,
                                                  float* __restrict__ lse_out,
                                                  uint32_t* __restrict__ zbits_out) {
  __shared__ __half tabh[2][Mm][CP];   // 2*128*112*2 = 57344 B
  __shared__ float elpi[4 * ELS];      // exp(linear_pi), padded stride
  __shared__ int yl[4];
  const int t = threadIdx.x;
  const int n0 = blockIdx.x * 4;

  // build both tables (coalesced beta reads)
  for (int idx = t; idx < Cc * 32; idx += 512) {
    int c = idx >> 5;
    int j4 = idx & 31;
    float4 bv = *(const float4*)&beta[c * Mm + j4 * 4];
    int j = j4 * 4;
    tabh[0][j + 0][c] = __float2half(__expf(2.0f * bv.x));
    tabh[1][j + 0][c] = __float2half(__expf(-2.0f * bv.x));
    tabh[0][j + 1][c] = __float2half(__expf(2.0f * bv.y));
    tabh[1][j + 1][c] = __float2half(__expf(-2.0f * bv.y));
    tabh[0][j + 2][c] = __float2half(__expf(2.0f * bv.z));
    tabh[1][j + 2][c] = __float2half(__expf(-2.0f * bv.z));
    tabh[0][j + 3][c] = __float2half(__expf(2.0f * bv.w));
    tabh[1][j + 3][c] = __float2half(__expf(-2.0f * bv.w));
  }
  for (int idx = t; idx < Mm * (CP - Cc); idx += 512) {
    int j = idx / (CP - Cc);
    int c = Cc + idx % (CP - Cc);
    tabh[0][j][c] = __float2half(1.0f);  // finite pad: E=0 there, avoid NaN in fma
    tabh[1][j][c] = __float2half(1.0f);
  }
  {
    int nl = t >> 7, j = t & 127;
    elpi[nl * ELS + j] = __expf(lpi[(n0 + nl) * Mm + j]);
  }
  if (t < 4) yl[t] = y[n0 + t];
  __syncthreads();

  const int cl = t >> 2;                    // chain within block, 0..127
  const int q = t & 3;                      // lane within chain
  const int nl = cl >> 5;                   // n-row 0..3
  const int s = cl & 31;
  const uint32_t chain = (uint32_t)((n0 + nl) * Ss + s);
  const int c0 = q * CS;
  const int yv = yl[nl];
  const float* elrow = &elpi[nl * ELS];
  const int lane = t & 63;

  // ---- init Z0 ~ 2*Bern(sigmoid(lpi))-1 : lane q draws word q, then share ----
  uint32_t zw0, zw1, zw2, zw3;
  {
    uint32_t zz = 0;
    #pragma unroll 1
    for (int b5 = 0; b5 < 32; ++b5) {
      int m = q * 32 + b5;
      float u = urand(chain, (uint32_t)m);
      float el = elrow[m];
      zz |= (u * (1.0f + el) < el) ? (1u << b5) : 0u;
    }
    int base = lane & ~3;
    zw0 = (uint32_t)__shfl((int)zz, base + 0);
    zw1 = (uint32_t)__shfl((int)zz, base + 1);
    zw2 = (uint32_t)__shfl((int)zz, base + 2);
    zw3 = (uint32_t)__shfl((int)zz, base + 3);
  }

  // ---- init E = exp(beta_0 + Z0 . beta) over my c-slice (f32 exact) ----
  float E[CS];
  #pragma unroll 1
  for (int i = 0; i < CS; ++i) {
    int c = c0 + i;
    int cc = (c < Cc) ? c : 0;
    float acc = beta0[cc];
    const float* bp = &beta[cc * Mm];
    #pragma unroll
    for (int w = 0; w < 4; ++w) {
      uint32_t zz = (w == 0) ? zw0 : ((w == 1) ? zw1 : ((w == 2) ? zw2 : zw3));
      #pragma unroll
      for (int m4 = 0; m4 < 8; ++m4) {
        float4 bv = *(const float4*)&bp[w * 32 + m4 * 4];
        int sh = m4 * 4;
        acc += ((zz >> (sh + 0)) & 1u) ? bv.x : -bv.x;
        acc += ((zz >> (sh + 1)) & 1u) ? bv.y : -bv.y;
        acc += ((zz >> (sh + 2)) & 1u) ? bv.z : -bv.z;
        acc += ((zz >> (sh + 3)) & 1u) ? bv.w : -bv.w;
      }
    }
    E[i] = (c < Cc) ? __expf(acc) : 0.0f;
  }
  float Sb = 0.f;
  #pragma unroll
  for (int i = 0; i < CS; ++i) Sb += E[i];
  Sb += __shfl_xor(Sb, 1);
  Sb += __shfl_xor(Sb, 2);

  // ---- one Gibbs sweep over coordinates j = 0..127 ----
  const char* tb_base = (const char*)&tabh[0][0][0] + (size_t)(q * (CS * 2));  // q*56 B
  const int HOFF = Mm * CP * 2;  // byte offset of em2 table

  #pragma unroll
  for (int w = 0; w < 4; ++w) {
    uint32_t zwv = (w == 0) ? zw0 : ((w == 1) ? zw1 : ((w == 2) ? zw2 : zw3));
    #pragma unroll 1
    for (int j5 = 0; j5 < 32; ++j5) {
      const int j = w * 32 + j5;
      const uint32_t zjp = (zwv >> j5) & 1u;   // 1 if z_j == +1
      // flip-factor slice: em2 if z=+1 else ep2 (one address select)
      const char* p = tb_base + j * (CP * 2) + (zjp ? HOFF : 0);
      float ts[CS];
      float d0 = 0.f, d1 = 0.f, d2 = 0.f, d3 = 0.f;
      #pragma unroll
      for (int k = 0; k < 7; ++k) {
        uint2 v = *(const uint2*)(p + k * 8);
        __half2 ha = *(__half2*)&v.x;
        __half2 hb = *(__half2*)&v.y;
        float2 fa = __half22float2(ha);
        float2 fb = __half22float2(hb);
        ts[k * 4 + 0] = fa.x; ts[k * 4 + 1] = fa.y;
        ts[k * 4 + 2] = fb.x; ts[k * 4 + 3] = fb.y;
        d0 = fmaf(E[k * 4 + 0], fa.x, d0);
        d1 = fmaf(E[k * 4 + 1], fa.y, d1);
        d2 = fmaf(E[k * 4 + 2], fb.x, d2);
        d3 = fmaf(E[k * 4 + 3], fb.y, d3);
      }
      float D = (d0 + d1) + (d2 + d3);
      D += __shfl_xor(D, 1);
      D += __shfl_xor(D, 2);
      float Spos = zjp ? Sb : D;
      float Sneg = zjp ? D : Sb;
      // odds = exp(2*b_j[y]) * Sneg/Spos * pij/(1-pij)
      float ep2y = __half2float(tabh[0][j][yv]);
      float odds = ep2y * Sneg * __builtin_amdgcn_rcpf(Spos) * elrow[j];
      float u = urand(chain, 256u + (uint32_t)j);
      uint32_t znp = (u * (1.0f + odds) < odds) ? 1u : 0u;
      uint32_t flip = znp ^ zjp;
      bool fl = (flip != 0u);
      #pragma unroll
      for (int i = 0; i < CS; ++i) E[i] = fl ? E[i] * ts[i] : E[i];
      Sb = fl ? D : Sb;
      zwv ^= (flip << j5);
    }
    if (w == 0) zw0 = zwv; else if (w == 1) zw1 = zwv;
    else if (w == 2) zw2 = zwv; else zw3 = zwv;
  }

  // ---- outputs: logsumexp (fresh sum) + final Z bits ----
  float Sf = 0.f;
  #pragma unroll
  for (int i = 0; i < CS; ++i) Sf += E[i];
  Sf += __shfl_xor(Sf, 1);
  Sf += __shfl_xor(Sf, 2);
  if (q == 0) lse_out[chain] = __logf(Sf);
  uint32_t zz = (q == 0) ? zw0 : ((q == 1) ? zw1 : ((q == 2) ? zw2 : zw3));
  zbits_out[chain * 4u + (uint32_t)q] = zz;
}

// ---------------- Kernel C: moments + all four terms, atomic scalar reduce ----------------
__global__ __launch_bounds__(128) void k_final(const float* __restrict__ lpi,
                                               const int* __restrict__ y,
                                               const float* __restrict__ beta0,
                                               const float* __restrict__ beta,
                                               const float* __restrict__ lse_in,
                                               const uint32_t* __restrict__ zbits,
                                               float* __restrict__ out) {
  __shared__ uint32_t zs[128];
  __shared__ float red[128];
  const int n = blockIdx.x;
  const int t = threadIdx.x;
  zs[t] = zbits[n * 128 + t];   // [s][w] for this n
  __syncthreads();
  const int w = t >> 5, bsh = t & 31;
  int cnt = 0;
  #pragma unroll
  for (int s = 0; s < 32; ++s) cnt += (int)((zs[s * 4 + w] >> bsh) & 1u);
  float EI = (float)cnt * (1.0f / 32.0f);   // mean (z+1)/2
  float EII = 2.0f * EI - 1.0f;             // mean z
  float l = lpi[n * Mm + t];
  int yv = y[n];
  float sp = (l > 20.0f) ? l : log1pf(__expf(l));  // stable softplus
  float term = EII * beta[yv * Mm + t] + EI * l - sp;
  if (t < 32) term -= lse_in[n * 32 + t] * (1.0f / 32.0f);  // -TermII contribution
  red[t] = term;
  __syncthreads();
  for (int off = 64; off > 0; off >>= 1) {
    if (t < off) red[t] += red[t + off];
    __syncthreads();
  }
  if (t == 0) atomicAdd(out, red[0] + beta0[yv]);
}

extern "C" void kernel_launch(void* const* d_in, const int* in_sizes, int n_in,
                              void* d_out, int out_size, void* d_ws, size_t ws_size,
                              hipStream_t stream) {
  const float* x = (const float*)d_in[0];
  const int* y = (const int*)d_in[1];
  const float* alpha0 = (const float*)d_in[2];
  const float* alpha = (const float*)d_in[3];
  const float* beta0 = (const float*)d_in[4];
  const float* beta = (const float*)d_in[5];
  float* out = (float*)d_out;

  char* ws = (char*)d_ws;
  float* lpi = (float*)ws;                                       // N*M f32 = 1 MB
  float* lse = (float*)(ws + (size_t)Nn * Mm * 4);               // N*S f32 = 256 KB
  uint32_t* zb = (uint32_t*)(ws + (size_t)Nn * Mm * 4 + (size_t)Nn * Ss * 4);  // N*S*4 u32 = 1 MB

  hipMemsetAsync(d_out, 0, sizeof(float), stream);
  k_linpi<<<Nn / 8, 256, 0, stream>>>(x, alpha0, alpha, lpi);
  k_gibbs<<<Nn / 4, 512, 0, stream>>>(beta0, beta, y, lpi, lse, zb);
  k_final<<<Nn, 128, 0, stream>>>(lpi, y, beta0, beta, lse, zb, out);
}

// Round 3
// 568.117 us; speedup vs baseline: 1.1389x; 1.0555x over previous
//
#include <hip/hip_runtime.h>
#include <hip/hip_fp16.h>
#include <stdint.h>

#define Nn 2048
#define Ff 1024
#define Mm 128
#define Cc 100
#define Ss 32
#define CP 112     // padded C (4 lanes x 28)
#define CS 28      // classes per lane
#define CH 14      // half2 per lane
#define ELS 132    // elpi stride in floats
#define ESC 0.015625f   // 2^-6 scale on E (headroom for half2)
#define ESCLOG 4.15888308336f  // 6*ln2

typedef _Float16 h2f __attribute__((ext_vector_type(2)));

__device__ __forceinline__ float dot2f(h2f a, h2f b, float c) {
#if __has_builtin(__builtin_amdgcn_fdot2)
  return __builtin_amdgcn_fdot2(a, b, c, false);
#else
  return fmaf((float)a[0], (float)b[0], fmaf((float)a[1], (float)b[1], c));
#endif
}

// cheap 32-bit counter-based RNG, same for all lanes of a chain
__device__ __forceinline__ float urand(uint32_t chain, uint32_t ctr) {
  uint32_t h = chain * 0x9E3779B9u ^ (ctr * 0x85EBCA6Bu);
  h ^= h >> 16; h *= 0x7FEB352Du;
  h ^= h >> 15; h *= 0x846CA68Bu;
  h ^= h >> 16;
  return (float)(h >> 8) * (1.0f / 16777216.0f);
}

// ---------------- Kernel A: linear_pi = alpha_0 + x @ alpha^T  (N,M) ----------------
__global__ __launch_bounds__(256) void k_linpi(const float* __restrict__ x,
                                               const float* __restrict__ alpha0,
                                               const float* __restrict__ alpha,
                                               float* __restrict__ lpi) {
  __shared__ float xs[8 * 64];
  __shared__ float as[128 * 68];
  const int t = threadIdx.x;
  const int n0 = blockIdx.x * 8;
  const int m = t & 127;
  const int np = t >> 7;
  float acc[4] = {0.f, 0.f, 0.f, 0.f};
  for (int kk = 0; kk < 16; ++kk) {
    __syncthreads();
    xs[t] = x[(n0 + (t >> 6)) * Ff + kk * 64 + (t & 63)];
    xs[t + 256] = x[(n0 + 4 + (t >> 6)) * Ff + kk * 64 + (t & 63)];
    #pragma unroll
    for (int r = 0; r < 8; ++r) {
      int idx4 = t + r * 256;
      int mm = idx4 >> 4, f4 = idx4 & 15;
      float4 v = *(const float4*)&alpha[mm * Ff + kk * 64 + f4 * 4];
      *(float4*)&as[mm * 68 + f4 * 4] = v;
    }
    __syncthreads();
    #pragma unroll
    for (int f4 = 0; f4 < 16; ++f4) {
      float4 a = *(const float4*)&as[m * 68 + f4 * 4];
      #pragma unroll
      for (int r = 0; r < 4; ++r) {
        float4 xv = *(const float4*)&xs[(np * 4 + r) * 64 + f4 * 4];
        acc[r] += a.x * xv.x + a.y * xv.y + a.z * xv.z + a.w * xv.w;
      }
    }
  }
  float a0v = alpha0[m];
  #pragma unroll
  for (int r = 0; r < 4; ++r)
    lpi[(n0 + np * 4 + r) * Mm + m] = acc[r] + a0v;
}

// ---------------- Kernel B: init + one Gibbs sweep, 4 lanes per chain ----------------
__global__ __launch_bounds__(512, 4) void k_gibbs(const float* __restrict__ beta0,
                                                  const float* __restrict__ beta,
                                                  const int* __restrict__ y,
                                                  const float* __restrict__ lpi,
                                                  float* __restrict__ lse_out,
                                                  uint32_t* __restrict__ zbits_out) {
  __shared__ __half tabh[2][Mm][CP];   // [0]=exp(+2b), [1]=exp(-2b); 57344 B
  __shared__ float elpi[4 * ELS];
  __shared__ int yl[4];
  const int t = threadIdx.x;
  const int n0 = blockIdx.x * 4;

  for (int idx = t; idx < Cc * 32; idx += 512) {
    int c = idx >> 5;
    int j4 = idx & 31;
    float4 bv = *(const float4*)&beta[c * Mm + j4 * 4];
    int j = j4 * 4;
    tabh[0][j + 0][c] = __float2half(__expf(2.0f * bv.x));
    tabh[1][j + 0][c] = __float2half(__expf(-2.0f * bv.x));
    tabh[0][j + 1][c] = __float2half(__expf(2.0f * bv.y));
    tabh[1][j + 1][c] = __float2half(__expf(-2.0f * bv.y));
    tabh[0][j + 2][c] = __float2half(__expf(2.0f * bv.z));
    tabh[1][j + 2][c] = __float2half(__expf(-2.0f * bv.z));
    tabh[0][j + 3][c] = __float2half(__expf(2.0f * bv.w));
    tabh[1][j + 3][c] = __float2half(__expf(-2.0f * bv.w));
  }
  for (int idx = t; idx < Mm * (CP - Cc); idx += 512) {
    int j = idx / (CP - Cc);
    int c = Cc + idx % (CP - Cc);
    tabh[0][j][c] = __float2half(1.0f);
    tabh[1][j][c] = __float2half(1.0f);
  }
  {
    int nl = t >> 7, j = t & 127;
    elpi[nl * ELS + j] = __expf(lpi[(n0 + nl) * Mm + j]);
  }
  if (t < 4) yl[t] = y[n0 + t];
  __syncthreads();

  const int cl = t >> 2;                    // chain within block, 0..127
  const int q = t & 3;                      // lane within chain
  const int nl = cl >> 5;
  const int s = cl & 31;
  const uint32_t chain = (uint32_t)((n0 + nl) * Ss + s);
  const int c0 = q * CS;
  const int yv = yl[nl];
  const float* elrow = &elpi[nl * ELS];
  const int lane = t & 63;

  // ---- init Z0 (staggered LDS reads to avoid same-bank) ----
  uint32_t zw0, zw1, zw2, zw3;
  {
    uint32_t zz = 0;
    #pragma unroll 1
    for (int b5 = 0; b5 < 32; ++b5) {
      int mloc = (b5 + q * 8) & 31;
      int m = q * 32 + mloc;
      float u = urand(chain, (uint32_t)m);
      float el = elrow[m];
      zz |= (u * (1.0f + el) < el) ? (1u << mloc) : 0u;
    }
    int base = lane & ~3;
    zw0 = (uint32_t)__shfl((int)zz, base + 0);
    zw1 = (uint32_t)__shfl((int)zz, base + 1);
    zw2 = (uint32_t)__shfl((int)zz, base + 2);
    zw3 = (uint32_t)__shfl((int)zz, base + 3);
  }

  // ---- init lin = Z0 . beta over my c-slice (f32, all arrays static-indexed) ----
  int rowoff[CS];
  #pragma unroll
  for (int i = 0; i < CS; ++i) {
    int c = c0 + i;
    rowoff[i] = ((c < Cc) ? c : 0) * Mm;
  }
  float acc[CS];
  #pragma unroll
  for (int i = 0; i < CS; ++i) acc[i] = 0.0f;
  #pragma unroll 1
  for (int mb = 0; mb < 32; ++mb) {
    int w = mb >> 3;
    uint32_t zz = (w == 0) ? zw0 : ((w == 1) ? zw1 : ((w == 2) ? zw2 : zw3));
    int sh = (mb & 7) * 4;
    float s0 = ((zz >> (sh + 0)) & 1u) ? 1.0f : -1.0f;
    float s1 = ((zz >> (sh + 1)) & 1u) ? 1.0f : -1.0f;
    float s2 = ((zz >> (sh + 2)) & 1u) ? 1.0f : -1.0f;
    float s3 = ((zz >> (sh + 3)) & 1u) ? 1.0f : -1.0f;
    int m0 = mb * 4;
    #pragma unroll
    for (int i = 0; i < CS; ++i) {
      float4 bv = *(const float4*)&beta[rowoff[i] + m0];
      float a = fmaf(s0, bv.x, acc[i]);
      a = fmaf(s1, bv.y, a);
      a = fmaf(s2, bv.z, a);
      acc[i] = fmaf(s3, bv.w, a);
    }
  }

  // ---- E = exp(beta0 + lin) * 2^-6 as half2 pairs ----
  h2f E2[CH];
  #pragma unroll
  for (int i2 = 0; i2 < CH; ++i2) {
    int ca = c0 + 2 * i2, cb = ca + 1;
    float ba = beta0[(ca < Cc) ? ca : 0];
    float bb = beta0[(cb < Cc) ? cb : 0];
    float ea = (ca < Cc) ? __expf(acc[2 * i2 + 0] + ba) * ESC : 0.0f;
    float eb = (cb < Cc) ? __expf(acc[2 * i2 + 1] + bb) * ESC : 0.0f;
    h2f e; e[0] = (_Float16)ea; e[1] = (_Float16)eb;
    E2[i2] = e;
  }
  const h2f one2 = {(_Float16)1.0f, (_Float16)1.0f};
  float Sb = 0.f;
  #pragma unroll
  for (int k = 0; k < CH; ++k) Sb = dot2f(E2[k], one2, Sb);
  Sb += __shfl_xor(Sb, 1);
  Sb += __shfl_xor(Sb, 2);

  // ---- Gibbs sweep, 4 steps per iteration, bits pre-extracted ----
  const char* tb = (const char*)&tabh[0][0][0] + (size_t)(q * (CS * 2));
  const int HOFF = Mm * CP * 2;

  #pragma unroll 1
  for (int jb = 0; jb < Mm; jb += 4) {
    int w = jb >> 5;
    uint32_t zwv = (w == 0) ? zw0 : ((w == 1) ? zw1 : ((w == 2) ? zw2 : zw3));
    const int sh = jb & 31;
    uint32_t b0 = (zwv >> (sh + 0)) & 1u;
    uint32_t b1 = (zwv >> (sh + 1)) & 1u;
    uint32_t b2 = (zwv >> (sh + 2)) & 1u;
    uint32_t b3 = (zwv >> (sh + 3)) & 1u;
    const char* p0 = tb + (jb + 0) * (CP * 2) + (b0 ? HOFF : 0);
    const char* p1 = tb + (jb + 1) * (CP * 2) + (b1 ? HOFF : 0);
    const char* p2 = tb + (jb + 2) * (CP * 2) + (b2 ? HOFF : 0);
    const char* p3 = tb + (jb + 3) * (CP * 2) + (b3 ? HOFF : 0);

    auto step = [&](int j, const char* p, uint32_t zjp) -> uint32_t {
      uint2 v[7];
      #pragma unroll
      for (int k = 0; k < 7; ++k) v[k] = *(const uint2*)(p + k * 8);
      float d0 = 0.f, d1 = 0.f;
      #pragma unroll
      for (int k = 0; k < 7; ++k) {
        h2f ta = __builtin_bit_cast(h2f, v[k].x);
        h2f tbv = __builtin_bit_cast(h2f, v[k].y);
        d0 = dot2f(E2[2 * k + 0], ta, d0);
        d1 = dot2f(E2[2 * k + 1], tbv, d1);
      }
      float D = d0 + d1;
      D += __shfl_xor(D, 1);
      D += __shfl_xor(D, 2);
      float Spos = zjp ? Sb : D;
      float Sneg = zjp ? D : Sb;
      float ep2y = __half2float(tabh[0][j][yv]);
      float odds = ep2y * Sneg * __builtin_amdgcn_rcpf(Spos) * elrow[j];
      float u = urand(chain, 256u + (uint32_t)j);
      uint32_t znp = (u * (1.0f + odds) < odds) ? 1u : 0u;
      uint32_t flip = znp ^ zjp;
      bool fl = (flip != 0u);
      #pragma unroll
      for (int k = 0; k < 7; ++k) {
        h2f ta = __builtin_bit_cast(h2f, v[k].x);
        h2f tbv = __builtin_bit_cast(h2f, v[k].y);
        h2f ma = E2[2 * k + 0] * ta;
        h2f mb = E2[2 * k + 1] * tbv;
        E2[2 * k + 0] = fl ? ma : E2[2 * k + 0];
        E2[2 * k + 1] = fl ? mb : E2[2 * k + 1];
      }
      Sb = fl ? D : Sb;
      return znp;
    };
    b0 = step(jb + 0, p0, b0);
    b1 = step(jb + 1, p1, b1);
    b2 = step(jb + 2, p2, b2);
    b3 = step(jb + 3, p3, b3);

    uint32_t nib = b0 | (b1 << 1) | (b2 << 2) | (b3 << 3);
    zwv = (zwv & ~(0xFu << sh)) | (nib << sh);
    if (w == 0) zw0 = zwv; else if (w == 1) zw1 = zwv;
    else if (w == 2) zw2 = zwv; else zw3 = zwv;
  }

  // ---- outputs ----
  float Sf = 0.f;
  #pragma unroll
  for (int k = 0; k < CH; ++k) Sf = dot2f(E2[k], one2, Sf);
  Sf += __shfl_xor(Sf, 1);
  Sf += __shfl_xor(Sf, 2);
  if (q == 0) lse_out[chain] = __logf(Sf) + ESCLOG;
  uint32_t zz = (q == 0) ? zw0 : ((q == 1) ? zw1 : ((q == 2) ? zw2 : zw3));
  zbits_out[chain * 4u + (uint32_t)q] = zz;
}

// ---------------- Kernel C: moments + all four terms, atomic scalar reduce ----------------
__global__ __launch_bounds__(128) void k_final(const float* __restrict__ lpi,
                                               const int* __restrict__ y,
                                               const float* __restrict__ beta0,
                                               const float* __restrict__ beta,
                                               const float* __restrict__ lse_in,
                                               const uint32_t* __restrict__ zbits,
                                               float* __restrict__ out) {
  __shared__ uint32_t zs[128];
  __shared__ float red[128];
  const int n = blockIdx.x;
  const int t = threadIdx.x;
  zs[t] = zbits[n * 128 + t];
  __syncthreads();
  const int w = t >> 5, bsh = t & 31;
  int cnt = 0;
  #pragma unroll
  for (int s = 0; s < 32; ++s) cnt += (int)((zs[s * 4 + w] >> bsh) & 1u);
  float EI = (float)cnt * (1.0f / 32.0f);
  float EII = 2.0f * EI - 1.0f;
  float l = lpi[n * Mm + t];
  int yv = y[n];
  float sp = (l > 20.0f) ? l : log1pf(__expf(l));
  float term = EII * beta[yv * Mm + t] + EI * l - sp;
  if (t < 32) term -= lse_in[n * 32 + t] * (1.0f / 32.0f);
  red[t] = term;
  __syncthreads();
  for (int off = 64; off > 0; off >>= 1) {
    if (t < off) red[t] += red[t + off];
    __syncthreads();
  }
  if (t == 0) atomicAdd(out, red[0] + beta0[yv]);
}

extern "C" void kernel_launch(void* const* d_in, const int* in_sizes, int n_in,
                              void* d_out, int out_size, void* d_ws, size_t ws_size,
                              hipStream_t stream) {
  const float* x = (const float*)d_in[0];
  const int* y = (const int*)d_in[1];
  const float* alpha0 = (const float*)d_in[2];
  const float* alpha = (const float*)d_in[3];
  const float* beta0 = (const float*)d_in[4];
  const float* beta = (const float*)d_in[5];
  float* out = (float*)d_out;

  char* ws = (char*)d_ws;
  float* lpi = (float*)ws;
  float* lse = (float*)(ws + (size_t)Nn * Mm * 4);
  uint32_t* zb = (uint32_t*)(ws + (size_t)Nn * Mm * 4 + (size_t)Nn * Ss * 4);

  hipMemsetAsync(d_out, 0, sizeof(float), stream);
  k_linpi<<<Nn / 8, 256, 0, stream>>>(x, alpha0, alpha, lpi);
  k_gibbs<<<Nn / 4, 512, 0, stream>>>(beta0, beta, y, lpi, lse, zb);
  k_final<<<Nn, 128, 0, stream>>>(lpi, y, beta0, beta, lse, zb, out);
}

// Round 4
// 225.773 us; speedup vs baseline: 2.8658x; 2.5163x over previous
//
#include <hip/hip_runtime.h>
#include <hip/hip_fp16.h>
#include <stdint.h>

#define Nn 2048
#define Ff 1024
#define Mm 128
#define Cc 100
#define Ss 32
#define CP 112     // padded C (4 lanes x 28)
#define CS 28      // classes per lane
#define CH 14      // half2 per lane
#define ELS 132    // elpi stride in floats
#define BSTR 134   // staged-beta stride: 28*134 mod 32 == 8 -> 4 q-groups on disjoint bank pairs
#define ESC 0.015625f          // 2^-6 scale on E
#define ESCLOG 4.15888308336f  // 6*ln2
#define TOT (Nn * Ss * 4)      // total lanes = 262144

typedef _Float16 h2f __attribute__((ext_vector_type(2)));

__device__ __forceinline__ float dot2f(h2f a, h2f b, float c) {
#if __has_builtin(__builtin_amdgcn_fdot2)
  return __builtin_amdgcn_fdot2(a, b, c, false);
#else
  return fmaf((float)a[0], (float)b[0], fmaf((float)a[1], (float)b[1], c));
#endif
}

// sum over the 4-lane chain group via DPP quad_perm (no LDS, ~8 cycles)
__device__ __forceinline__ float qsum4(float x) {
  int a = __builtin_amdgcn_update_dpp(0, __builtin_bit_cast(int, x), 0xB1, 0xF, 0xF, false);
  float xf = x + __builtin_bit_cast(float, a);
  int b = __builtin_amdgcn_update_dpp(0, __builtin_bit_cast(int, xf), 0x4E, 0xF, 0xF, false);
  return xf + __builtin_bit_cast(float, b);
}

// cheap 32-bit counter-based RNG, same for all lanes of a chain
__device__ __forceinline__ float urand(uint32_t chain, uint32_t ctr) {
  uint32_t h = chain * 0x9E3779B9u ^ (ctr * 0x85EBCA6Bu);
  h ^= h >> 16; h *= 0x7FEB352Du;
  h ^= h >> 15; h *= 0x846CA68Bu;
  h ^= h >> 16;
  return (float)(h >> 8) * (1.0f / 16777216.0f);
}

// ---------------- Kernel A: linear_pi = alpha_0 + x @ alpha^T  (N,M) ----------------
__global__ __launch_bounds__(256) void k_linpi(const float* __restrict__ x,
                                               const float* __restrict__ alpha0,
                                               const float* __restrict__ alpha,
                                               float* __restrict__ lpi) {
  __shared__ float xs[8 * 64];
  __shared__ float as[128 * 68];
  const int t = threadIdx.x;
  const int n0 = blockIdx.x * 8;
  const int m = t & 127;
  const int np = t >> 7;
  float acc[4] = {0.f, 0.f, 0.f, 0.f};
  for (int kk = 0; kk < 16; ++kk) {
    __syncthreads();
    xs[t] = x[(n0 + (t >> 6)) * Ff + kk * 64 + (t & 63)];
    xs[t + 256] = x[(n0 + 4 + (t >> 6)) * Ff + kk * 64 + (t & 63)];
    #pragma unroll
    for (int r = 0; r < 8; ++r) {
      int idx4 = t + r * 256;
      int mm = idx4 >> 4, f4 = idx4 & 15;
      float4 v = *(const float4*)&alpha[mm * Ff + kk * 64 + f4 * 4];
      *(float4*)&as[mm * 68 + f4 * 4] = v;
    }
    __syncthreads();
    #pragma unroll
    for (int f4 = 0; f4 < 16; ++f4) {
      float4 a = *(const float4*)&as[m * 68 + f4 * 4];
      #pragma unroll
      for (int r = 0; r < 4; ++r) {
        float4 xv = *(const float4*)&xs[(np * 4 + r) * 64 + f4 * 4];
        acc[r] += a.x * xv.x + a.y * xv.y + a.z * xv.z + a.w * xv.w;
      }
    }
  }
  float a0v = alpha0[m];
  #pragma unroll
  for (int r = 0; r < 4; ++r)
    lpi[(n0 + np * 4 + r) * Mm + m] = acc[r] + a0v;
}

// ---------------- Kernel B1: Z0 sample + E-init (beta staged in LDS) ----------------
__global__ __launch_bounds__(512, 4) void k_init(const float* __restrict__ beta0,
                                                 const float* __restrict__ beta,
                                                 const float* __restrict__ lpi,
                                                 uint32_t* __restrict__ zws,
                                                 uint32_t* __restrict__ E2s) {
  __shared__ float bs[CP * BSTR];   // 60032 B
  __shared__ float elpi[4 * ELS];   // 2112 B
  const int t = threadIdx.x;
  const int n0 = blockIdx.x * 4;

  // stage beta rows (f32); pad rows >= Cc with 0
  for (int idx = t; idx < CP * 64; idx += 512) {
    int row = idx >> 6, col2 = (idx & 63) * 2;
    float2 v;
    if (row < Cc) v = *(const float2*)&beta[row * Mm + col2];
    else { v.x = 0.f; v.y = 0.f; }
    *(float2*)&bs[row * BSTR + col2] = v;
  }
  {
    int nl = t >> 7, j = t & 127;
    elpi[nl * ELS + j] = __expf(lpi[(n0 + nl) * Mm + j]);
  }
  __syncthreads();

  const int cl = t >> 2;
  const int q = t & 3;
  const int nl = cl >> 5;
  const int s = cl & 31;
  const uint32_t chain = (uint32_t)((n0 + nl) * Ss + s);
  const int c0 = q * CS;
  const float* elrow = &elpi[nl * ELS];
  const int lane = t & 63;

  // ---- Z0 ~ 2*Bern(sigmoid(lpi))-1 (staggered LDS reads) ----
  uint32_t zw0, zw1, zw2, zw3;
  {
    uint32_t zz = 0;
    #pragma unroll 1
    for (int b5 = 0; b5 < 32; ++b5) {
      int mloc = (b5 + q * 8) & 31;
      int m = q * 32 + mloc;
      float u = urand(chain, (uint32_t)m);
      float el = elrow[m];
      zz |= (u * (1.0f + el) < el) ? (1u << mloc) : 0u;
    }
    int base = lane & ~3;
    zw0 = (uint32_t)__shfl((int)zz, base + 0);
    zw1 = (uint32_t)__shfl((int)zz, base + 1);
    zw2 = (uint32_t)__shfl((int)zz, base + 2);
    zw3 = (uint32_t)__shfl((int)zz, base + 3);
  }

  // ---- lin = Z0 . beta over my c-slice, from LDS ----
  float acc[CS];
  #pragma unroll
  for (int i = 0; i < CS; ++i) acc[i] = 0.0f;
  #pragma unroll 1
  for (int mb = 0; mb < 32; ++mb) {
    int w = mb >> 3;
    uint32_t zz = (w == 0) ? zw0 : ((w == 1) ? zw1 : ((w == 2) ? zw2 : zw3));
    int sh = (mb & 7) * 4;
    float s0 = ((zz >> (sh + 0)) & 1u) ? 1.0f : -1.0f;
    float s1 = ((zz >> (sh + 1)) & 1u) ? 1.0f : -1.0f;
    float s2 = ((zz >> (sh + 2)) & 1u) ? 1.0f : -1.0f;
    float s3 = ((zz >> (sh + 3)) & 1u) ? 1.0f : -1.0f;
    int m0 = mb * 4;
    #pragma unroll
    for (int i = 0; i < CS; ++i) {
      float2 a = *(const float2*)&bs[(c0 + i) * BSTR + m0];
      float2 b = *(const float2*)&bs[(c0 + i) * BSTR + m0 + 2];
      acc[i] = fmaf(s0, a.x, fmaf(s1, a.y, fmaf(s2, b.x, fmaf(s3, b.y, acc[i]))));
    }
  }

  // ---- E = exp(beta0 + lin) * 2^-6, packed f16 pairs; store state ----
  const int gid = blockIdx.x * 512 + t;
  #pragma unroll
  for (int i2 = 0; i2 < CH; ++i2) {
    int ca = c0 + 2 * i2, cb = ca + 1;
    float ba = beta0[(ca < Cc) ? ca : 0];
    float bb = beta0[(cb < Cc) ? cb : 0];
    float ea = (ca < Cc) ? __expf(acc[2 * i2 + 0] + ba) * ESC : 0.0f;
    float eb = (cb < Cc) ? __expf(acc[2 * i2 + 1] + bb) * ESC : 0.0f;
    h2f e; e[0] = (_Float16)ea; e[1] = (_Float16)eb;
    E2s[i2 * TOT + gid] = __builtin_bit_cast(uint32_t, e);
  }
  uint32_t myz = (q == 0) ? zw0 : ((q == 1) ? zw1 : ((q == 2) ? zw2 : zw3));
  zws[gid] = myz;
}

// ---------------- Kernel B2: one Gibbs sweep from staged state ----------------
__global__ __launch_bounds__(512, 4) void k_sweep(const float* __restrict__ beta,
                                                  const int* __restrict__ y,
                                                  const float* __restrict__ lpi,
                                                  const uint32_t* __restrict__ zws,
                                                  const uint32_t* __restrict__ E2s,
                                                  float* __restrict__ lse_out,
                                                  uint32_t* __restrict__ zbits_out) {
  __shared__ __half tabh[2][Mm][CP];   // 57344 B
  __shared__ float elpi[4 * ELS];
  __shared__ int yl[4];
  const int t = threadIdx.x;
  const int n0 = blockIdx.x * 4;

  // build tables; lanes iterate over c (bank-spread LDS writes; beta stays L2-hot)
  for (int idx = t; idx < 32 * Cc; idx += 512) {
    int j4 = idx / Cc;
    int c = idx - j4 * Cc;
    float4 bv = *(const float4*)&beta[c * Mm + j4 * 4];
    int j = j4 * 4;
    tabh[0][j + 0][c] = __float2half(__expf(2.0f * bv.x));
    tabh[1][j + 0][c] = __float2half(__expf(-2.0f * bv.x));
    tabh[0][j + 1][c] = __float2half(__expf(2.0f * bv.y));
    tabh[1][j + 1][c] = __float2half(__expf(-2.0f * bv.y));
    tabh[0][j + 2][c] = __float2half(__expf(2.0f * bv.z));
    tabh[1][j + 2][c] = __float2half(__expf(-2.0f * bv.z));
    tabh[0][j + 3][c] = __float2half(__expf(2.0f * bv.w));
    tabh[1][j + 3][c] = __float2half(__expf(-2.0f * bv.w));
  }
  for (int idx = t; idx < Mm * (CP - Cc); idx += 512) {
    int j = idx / (CP - Cc);
    int c = Cc + idx % (CP - Cc);
    tabh[0][j][c] = __float2half(1.0f);
    tabh[1][j][c] = __float2half(1.0f);
  }
  {
    int nl = t >> 7, j = t & 127;
    elpi[nl * ELS + j] = __expf(lpi[(n0 + nl) * Mm + j]);
  }
  if (t < 4) yl[t] = y[n0 + t];
  __syncthreads();

  const int cl = t >> 2;
  const int q = t & 3;
  const int nl = cl >> 5;
  const int s = cl & 31;
  const uint32_t chain = (uint32_t)((n0 + nl) * Ss + s);
  const int c0 = q * CS;
  const int yv = yl[nl];
  const float* elrow = &elpi[nl * ELS];
  const int lane = t & 63;
  const int gid = blockIdx.x * 512 + t;

  // ---- load state ----
  h2f E2[CH];
  #pragma unroll
  for (int k = 0; k < CH; ++k)
    E2[k] = __builtin_bit_cast(h2f, E2s[k * TOT + gid]);
  uint32_t zw0, zw1, zw2, zw3;
  {
    uint32_t myz = zws[gid];
    int base = lane & ~3;
    zw0 = (uint32_t)__shfl((int)myz, base + 0);
    zw1 = (uint32_t)__shfl((int)myz, base + 1);
    zw2 = (uint32_t)__shfl((int)myz, base + 2);
    zw3 = (uint32_t)__shfl((int)myz, base + 3);
  }
  const h2f one2 = {(_Float16)1.0f, (_Float16)1.0f};
  float Sb = 0.f;
  #pragma unroll
  for (int k = 0; k < CH; ++k) Sb = dot2f(E2[k], one2, Sb);
  Sb = qsum4(Sb);

  // ---- Gibbs sweep, 4 steps per group; preloads off the decision chain ----
  #pragma unroll 1
  for (int jb = 0; jb < Mm; jb += 4) {
    int w = jb >> 5;
    uint32_t zwv = (w == 0) ? zw0 : ((w == 1) ? zw1 : ((w == 2) ? zw2 : zw3));
    const int sh = jb & 31;
    uint32_t b0 = (zwv >> (sh + 0)) & 1u;
    uint32_t b1 = (zwv >> (sh + 1)) & 1u;
    uint32_t b2 = (zwv >> (sh + 2)) & 1u;
    uint32_t b3 = (zwv >> (sh + 3)) & 1u;
    // group-top preloads (state-independent)
    float4 elv = *(const float4*)&elpi[nl * ELS + jb];
    float ey0 = __half2float(tabh[0][jb + 0][yv]);
    float ey1 = __half2float(tabh[0][jb + 1][yv]);
    float ey2 = __half2float(tabh[0][jb + 2][yv]);
    float ey3 = __half2float(tabh[0][jb + 3][yv]);
    float u0 = urand(chain, 256u + (uint32_t)(jb + 0));
    float u1 = urand(chain, 256u + (uint32_t)(jb + 1));
    float u2 = urand(chain, 256u + (uint32_t)(jb + 2));
    float u3 = urand(chain, 256u + (uint32_t)(jb + 3));

    auto step = [&](int j, uint32_t zjp, float ey, float el, float u) -> uint32_t {
      int hsel = (int)zjp;   // z=+1 -> need em2 (flip factor), which is tabh[1]
      uint2 v[7];
      #pragma unroll
      for (int k = 0; k < 7; ++k)
        v[k] = *(const uint2*)&tabh[hsel][j][c0 + 4 * k];
      float d0 = 0.f, d1 = 0.f;
      #pragma unroll
      for (int k = 0; k < 7; ++k) {
        h2f ta = __builtin_bit_cast(h2f, v[k].x);
        h2f tb = __builtin_bit_cast(h2f, v[k].y);
        d0 = dot2f(E2[2 * k + 0], ta, d0);
        d1 = dot2f(E2[2 * k + 1], tb, d1);
      }
      float D = qsum4(d0 + d1);
      float Spos = zjp ? Sb : D;
      float Sneg = zjp ? D : Sb;
      float odds = ey * Sneg * __builtin_amdgcn_rcpf(Spos) * el;
      uint32_t znp = (u * (1.0f + odds) < odds) ? 1u : 0u;
      uint32_t flip = znp ^ zjp;
      bool fl = (flip != 0u);
      #pragma unroll
      for (int k = 0; k < 7; ++k) {
        h2f ta = __builtin_bit_cast(h2f, v[k].x);
        h2f tb = __builtin_bit_cast(h2f, v[k].y);
        h2f fa = fl ? ta : one2;
        h2f fb = fl ? tb : one2;
        E2[2 * k + 0] *= fa;
        E2[2 * k + 1] *= fb;
      }
      Sb = fl ? D : Sb;
      return znp;
    };
    b0 = step(jb + 0, b0, ey0, elv.x, u0);
    b1 = step(jb + 1, b1, ey1, elv.y, u1);
    b2 = step(jb + 2, b2, ey2, elv.z, u2);
    b3 = step(jb + 3, b3, ey3, elv.w, u3);

    uint32_t nib = b0 | (b1 << 1) | (b2 << 2) | (b3 << 3);
    zwv = (zwv & ~(0xFu << sh)) | (nib << sh);
    if (w == 0) zw0 = zwv; else if (w == 1) zw1 = zwv;
    else if (w == 2) zw2 = zwv; else zw3 = zwv;
  }

  // ---- outputs ----
  float Sf = 0.f;
  #pragma unroll
  for (int k = 0; k < CH; ++k) Sf = dot2f(E2[k], one2, Sf);
  Sf = qsum4(Sf);
  if (q == 0) lse_out[chain] = __logf(Sf) + ESCLOG;
  uint32_t zz = (q == 0) ? zw0 : ((q == 1) ? zw1 : ((q == 2) ? zw2 : zw3));
  zbits_out[chain * 4u + (uint32_t)q] = zz;
}

// ---------------- Kernel C: moments + all four terms, atomic scalar reduce ----------------
__global__ __launch_bounds__(128) void k_final(const float* __restrict__ lpi,
                                               const int* __restrict__ y,
                                               const float* __restrict__ beta0,
                                               const float* __restrict__ beta,
                                               const float* __restrict__ lse_in,
                                               const uint32_t* __restrict__ zbits,
                                               float* __restrict__ out) {
  __shared__ uint32_t zs[128];
  __shared__ float red[128];
  const int n = blockIdx.x;
  const int t = threadIdx.x;
  zs[t] = zbits[n * 128 + t];
  __syncthreads();
  const int w = t >> 5, bsh = t & 31;
  int cnt = 0;
  #pragma unroll
  for (int s = 0; s < 32; ++s) cnt += (int)((zs[s * 4 + w] >> bsh) & 1u);
  float EI = (float)cnt * (1.0f / 32.0f);
  float EII = 2.0f * EI - 1.0f;
  float l = lpi[n * Mm + t];
  int yv = y[n];
  float sp = (l > 20.0f) ? l : log1pf(__expf(l));
  float term = EII * beta[yv * Mm + t] + EI * l - sp;
  if (t < 32) term -= lse_in[n * 32 + t] * (1.0f / 32.0f);
  red[t] = term;
  __syncthreads();
  for (int off = 64; off > 0; off >>= 1) {
    if (t < off) red[t] += red[t + off];
    __syncthreads();
  }
  if (t == 0) atomicAdd(out, red[0] + beta0[yv]);
}

extern "C" void kernel_launch(void* const* d_in, const int* in_sizes, int n_in,
                              void* d_out, int out_size, void* d_ws, size_t ws_size,
                              hipStream_t stream) {
  const float* x = (const float*)d_in[0];
  const int* y = (const int*)d_in[1];
  const float* alpha0 = (const float*)d_in[2];
  const float* alpha = (const float*)d_in[3];
  const float* beta0 = (const float*)d_in[4];
  const float* beta = (const float*)d_in[5];
  float* out = (float*)d_out;

  char* ws = (char*)d_ws;
  float* lpi = (float*)ws;                                   // 1 MB
  float* lse = (float*)(ws + (1u << 20));                    // 256 KB
  uint32_t* zb = (uint32_t*)(ws + (1u << 20) + (1u << 18));  // 1 MB
  uint32_t* zws = (uint32_t*)(ws + (1u << 20) + (1u << 18) + (1u << 20));  // 1 MB
  uint32_t* E2s = (uint32_t*)(ws + 2 * (1u << 20) + (1u << 18) + (1u << 20));  // 14 MB

  hipMemsetAsync(d_out, 0, sizeof(float), stream);
  k_linpi<<<Nn / 8, 256, 0, stream>>>(x, alpha0, alpha, lpi);
  k_init<<<Nn / 4, 512, 0, stream>>>(beta0, beta, lpi, zws, E2s);
  k_sweep<<<Nn / 4, 512, 0, stream>>>(beta, y, lpi, zws, E2s, lse, zb);
  k_final<<<Nn, 128, 0, stream>>>(lpi, y, beta0, beta, lse, zb, out);
}

// Round 5
// 172.296 us; speedup vs baseline: 3.7553x; 1.3104x over previous
//
#include <hip/hip_runtime.h>
#include <hip/hip_fp16.h>
#include <stdint.h>

#define Nn 2048
#define Ff 1024
#define Mm 128
#define Cc 100
#define Ss 32
#define NCH (Nn * Ss)   // 65536 chains
// k_init geometry (4 lanes/chain)
#define CS 28
#define CH 14
#define BSTR 132        // staged-beta stride (f32), 16B-aligned rows, 2-way banks
// k_sweep geometry (2 lanes/chain)
#define SCP 104         // table row stride in halfs (52*2, 8B-aligned half-slices)
#define SCH 26          // half2 per sweep lane
#define ELS 132
#define ESC 0.015625f          // 2^-6 scale on E
#define ESCLOG 4.15888308336f  // 6*ln2

typedef _Float16 h2f __attribute__((ext_vector_type(2)));
typedef short bf8 __attribute__((ext_vector_type(8)));    // 8 bf16 in 4 VGPRs
typedef float f32x4 __attribute__((ext_vector_type(4)));

__device__ __forceinline__ float dot2f(h2f a, h2f b, float c) {
#if __has_builtin(__builtin_amdgcn_fdot2)
  return __builtin_amdgcn_fdot2(a, b, c, false);
#else
  return fmaf((float)a[0], (float)b[0], fmaf((float)a[1], (float)b[1], c));
#endif
}

// pair-sum (lane t with lane t^1) via DPP quad_perm [1,0,3,2]
__device__ __forceinline__ float qsum2(float x) {
  int a = __builtin_amdgcn_update_dpp(0, __builtin_bit_cast(int, x), 0xB1, 0xF, 0xF, false);
  return x + __builtin_bit_cast(float, a);
}
// 4-lane sum (used by k_init's 4-lane groups is not needed; keep for Sb in init? no)

__device__ __forceinline__ float urand(uint32_t chain, uint32_t ctr) {
  uint32_t h = chain * 0x9E3779B9u ^ (ctr * 0x85EBCA6Bu);
  h ^= h >> 16; h *= 0x7FEB352Du;
  h ^= h >> 15; h *= 0x846CA68Bu;
  h ^= h >> 16;
  return (float)(h >> 8) * (1.0f / 16777216.0f);
}

__device__ __forceinline__ uint32_t f2bf(float f) {
  uint32_t b = __builtin_bit_cast(uint32_t, f);
  return (b + 0x7FFFu + ((b >> 16) & 1u)) >> 16;
}

// ---------------- Kernel P: convert x,alpha -> bf16; init lpi = alpha0 ----------------
__global__ __launch_bounds__(256) void k_prep(const float* __restrict__ x,
                                              const float* __restrict__ alpha,
                                              const float* __restrict__ alpha0,
                                              uint16_t* __restrict__ xb,
                                              uint16_t* __restrict__ ab,
                                              float* __restrict__ lpi) {
  const int tg = blockIdx.x * 256 + threadIdx.x;   // 131072 threads
  // xb: 2M elements = 262144 chunks of 8
  for (int c = tg; c < (Nn * Ff) / 8; c += 131072) {
    float4 f0 = *(const float4*)&x[c * 8];
    float4 f1 = *(const float4*)&x[c * 8 + 4];
    uint4 o;
    o.x = f2bf(f0.x) | (f2bf(f0.y) << 16);
    o.y = f2bf(f0.z) | (f2bf(f0.w) << 16);
    o.z = f2bf(f1.x) | (f2bf(f1.y) << 16);
    o.w = f2bf(f1.z) | (f2bf(f1.w) << 16);
    *(uint4*)&xb[c * 8] = o;
  }
  if (tg < (Mm * Ff) / 8) {
    int c = tg;
    float4 f0 = *(const float4*)&alpha[c * 8];
    float4 f1 = *(const float4*)&alpha[c * 8 + 4];
    uint4 o;
    o.x = f2bf(f0.x) | (f2bf(f0.y) << 16);
    o.y = f2bf(f0.z) | (f2bf(f0.w) << 16);
    o.z = f2bf(f1.x) | (f2bf(f1.y) << 16);
    o.w = f2bf(f1.z) | (f2bf(f1.w) << 16);
    *(uint4*)&ab[c * 8] = o;
  }
  if (tg < (Nn * Mm) / 8) {
    int idx = tg * 8;
    int col = idx & 127;
    float4 a0 = *(const float4*)&alpha0[col];
    float4 a1 = *(const float4*)&alpha0[col + 4];
    *(float4*)&lpi[idx] = a0;
    *(float4*)&lpi[idx + 4] = a1;
  }
}

// ---------------- Kernel A: lpi += xb @ ab^T via MFMA (split-K x4, atomic f32) ----------------
__global__ __launch_bounds__(256) void k_lingemm(const uint16_t* __restrict__ xb,
                                                 const uint16_t* __restrict__ ab,
                                                 float* __restrict__ lpi) {
  __shared__ uint4 sA[256];    // 32 rows x 8 chunks of 16B (64 bf16/row), swizzled
  __shared__ uint4 sB[1024];   // 128 rows x 8 chunks
  const int t = threadIdx.x;
  const int mt = blockIdx.x >> 2;
  const int ks = blockIdx.x & 3;
  const int m0 = mt * 32;
  const int w = t >> 6;
  const int l = t & 63;

  f32x4 acc[2][2] = {{{0.f, 0.f, 0.f, 0.f}, {0.f, 0.f, 0.f, 0.f}},
                     {{0.f, 0.f, 0.f, 0.f}, {0.f, 0.f, 0.f, 0.f}}};

  for (int kk = 0; kk < 4; ++kk) {
    const int k0 = ks * 256 + kk * 64;
    __syncthreads();
    {
      int row = t >> 3, c = t & 7;
      uint4 v = *(const uint4*)&xb[(m0 + row) * Ff + k0 + c * 8];
      sA[row * 8 + (c ^ (row & 7))] = v;
      #pragma unroll
      for (int rr = 0; rr < 4; ++rr) {
        int idx = t + rr * 256;
        int rowb = idx >> 3, cb = idx & 7;
        uint4 vb = *(const uint4*)&ab[rowb * Ff + k0 + cb * 8];
        sB[rowb * 8 + (cb ^ (rowb & 7))] = vb;
      }
    }
    __syncthreads();
    #pragma unroll
    for (int kc = 0; kc < 2; ++kc) {
      int chunk = kc * 4 + (l >> 4);
      bf8 av[2], bv[2];
      #pragma unroll
      for (int fm = 0; fm < 2; ++fm) {
        int row = fm * 16 + (l & 15);
        av[fm] = __builtin_bit_cast(bf8, sA[row * 8 + (chunk ^ (row & 7))]);
      }
      #pragma unroll
      for (int fn = 0; fn < 2; ++fn) {
        int rowb = w * 32 + fn * 16 + (l & 15);
        bv[fn] = __builtin_bit_cast(bf8, sB[rowb * 8 + (chunk ^ (rowb & 7))]);
      }
      #pragma unroll
      for (int fm = 0; fm < 2; ++fm)
        #pragma unroll
        for (int fn = 0; fn < 2; ++fn)
          acc[fm][fn] = __builtin_amdgcn_mfma_f32_16x16x32_bf16(av[fm], bv[fn], acc[fm][fn], 0, 0, 0);
    }
  }
  // C layout: col = lane&15, row = (lane>>4)*4 + reg  [m89-verified]
  #pragma unroll
  for (int fm = 0; fm < 2; ++fm)
    #pragma unroll
    for (int fn = 0; fn < 2; ++fn)
      #pragma unroll
      for (int r = 0; r < 4; ++r) {
        int row = m0 + fm * 16 + (l >> 4) * 4 + r;
        int col = w * 32 + fn * 16 + (l & 15);
        atomicAdd(&lpi[row * Mm + col], acc[fm][fn][r]);
      }
}

// ---------------- Kernel B1: Z0 sample + E-init (beta staged in LDS, 4 lanes/chain) ----------------
__global__ __launch_bounds__(512, 4) void k_init(const float* __restrict__ beta0,
                                                 const float* __restrict__ beta,
                                                 const float* __restrict__ lpi,
                                                 uint32_t* __restrict__ zws,
                                                 uint32_t* __restrict__ E2s) {
  __shared__ float bs[112 * BSTR];  // 112 class rows (>=100 zero-padded)
  __shared__ float elpi[4 * ELS];
  const int t = threadIdx.x;
  const int n0 = blockIdx.x * 4;

  for (int idx = t; idx < 112 * 64; idx += 512) {
    int row = idx >> 6, col2 = (idx & 63) * 2;
    float2 v;
    if (row < Cc) v = *(const float2*)&beta[row * Mm + col2];
    else { v.x = 0.f; v.y = 0.f; }
    *(float2*)&bs[row * BSTR + col2] = v;
  }
  {
    int nl = t >> 7, j = t & 127;
    elpi[nl * ELS + j] = __expf(lpi[(n0 + nl) * Mm + j]);
  }
  __syncthreads();

  const int cl = t >> 2;
  const int q = t & 3;
  const int nl = cl >> 5;
  const int s = cl & 31;
  const uint32_t chain = (uint32_t)((n0 + nl) * Ss + s);
  const int c0 = q * CS;
  const float* elrow = &elpi[nl * ELS];
  const int lane = t & 63;

  uint32_t zw0, zw1, zw2, zw3;
  {
    uint32_t zz = 0;
    #pragma unroll 1
    for (int b5 = 0; b5 < 32; ++b5) {
      int mloc = (b5 + q * 8) & 31;
      int m = q * 32 + mloc;
      float u = urand(chain, (uint32_t)m);
      float el = elrow[m];
      zz |= (u * (1.0f + el) < el) ? (1u << mloc) : 0u;
    }
    int base = lane & ~3;
    zw0 = (uint32_t)__shfl((int)zz, base + 0);
    zw1 = (uint32_t)__shfl((int)zz, base + 1);
    zw2 = (uint32_t)__shfl((int)zz, base + 2);
    zw3 = (uint32_t)__shfl((int)zz, base + 3);
  }

  float acc[CS];
  #pragma unroll
  for (int i = 0; i < CS; ++i) acc[i] = 0.0f;
  #pragma unroll 1
  for (int mb = 0; mb < 32; ++mb) {
    int w = mb >> 3;
    uint32_t zz = (w == 0) ? zw0 : ((w == 1) ? zw1 : ((w == 2) ? zw2 : zw3));
    int sh = (mb & 7) * 4;
    float s0 = ((zz >> (sh + 0)) & 1u) ? 1.0f : -1.0f;
    float s1 = ((zz >> (sh + 1)) & 1u) ? 1.0f : -1.0f;
    float s2 = ((zz >> (sh + 2)) & 1u) ? 1.0f : -1.0f;
    float s3 = ((zz >> (sh + 3)) & 1u) ? 1.0f : -1.0f;
    int m0 = mb * 4;
    #pragma unroll
    for (int i = 0; i < CS; ++i) {
      float4 bv = *(const float4*)&bs[(c0 + i) * BSTR + m0];
      acc[i] = fmaf(s0, bv.x, fmaf(s1, bv.y, fmaf(s2, bv.z, fmaf(s3, bv.w, acc[i]))));
    }
  }

  // E = exp(beta0 + lin) * 2^-6; store planes k = q*14+i2 (k<52)
  #pragma unroll
  for (int i2 = 0; i2 < CH; ++i2) {
    int k = q * CH + i2;
    if (k < 52) {
      int ca = c0 + 2 * i2, cb = ca + 1;
      float ba = beta0[(ca < Cc) ? ca : 0];
      float bb = beta0[(cb < Cc) ? cb : 0];
      float ea = (ca < Cc) ? __expf(acc[2 * i2 + 0] + ba) * ESC : 0.0f;
      float eb = (cb < Cc) ? __expf(acc[2 * i2 + 1] + bb) * ESC : 0.0f;
      h2f e; e[0] = (_Float16)ea; e[1] = (_Float16)eb;
      E2s[k * NCH + chain] = __builtin_bit_cast(uint32_t, e);
    }
  }
  zws[blockIdx.x * 512 + t] = (q == 0) ? zw0 : ((q == 1) ? zw1 : ((q == 2) ? zw2 : zw3));
}

// ---------------- Kernel B2: one Gibbs sweep, 2 lanes/chain, 256 chains/block ----------------
__global__ __launch_bounds__(512, 2) void k_sweep(const float* __restrict__ beta,
                                                  const int* __restrict__ y,
                                                  const float* __restrict__ lpi,
                                                  const uint32_t* __restrict__ zws,
                                                  const uint32_t* __restrict__ E2s,
                                                  float* __restrict__ lse_out,
                                                  uint32_t* __restrict__ zbits_out) {
  __shared__ __half tabh[2][Mm][SCP];   // 53248 B
  __shared__ float elpi[8 * ELS];
  __shared__ int yl[8];
  const int t = threadIdx.x;
  const int n0 = blockIdx.x * 8;

  for (int idx = t; idx < 32 * Cc; idx += 512) {
    int j4 = idx / Cc;
    int c = idx - j4 * Cc;
    float4 bv = *(const float4*)&beta[c * Mm + j4 * 4];
    int j = j4 * 4;
    tabh[0][j + 0][c] = __float2half(__expf(2.0f * bv.x));
    tabh[1][j + 0][c] = __float2half(__expf(-2.0f * bv.x));
    tabh[0][j + 1][c] = __float2half(__expf(2.0f * bv.y));
    tabh[1][j + 1][c] = __float2half(__expf(-2.0f * bv.y));
    tabh[0][j + 2][c] = __float2half(__expf(2.0f * bv.z));
    tabh[1][j + 2][c] = __float2half(__expf(-2.0f * bv.z));
    tabh[0][j + 3][c] = __float2half(__expf(2.0f * bv.w));
    tabh[1][j + 3][c] = __float2half(__expf(-2.0f * bv.w));
  }
  // pad classes 100..103 -> 1.0 (E there is 0; keep factors finite)
  for (int idx = t; idx < 2 * Mm * 4; idx += 512) {
    int hsel = idx >> 9, j = (idx >> 2) & 127, c = Cc + (idx & 3);
    tabh[hsel][j][c] = __float2half(1.0f);
  }
  for (int idx = t; idx < 8 * Mm; idx += 512) {
    int nl = idx >> 7, j = idx & 127;
    elpi[nl * ELS + j] = __expf(lpi[(n0 + nl) * Mm + j]);
  }
  if (t < 8) yl[t] = y[n0 + t];
  __syncthreads();

  const int cl = t >> 1;      // chain in block 0..255
  const int q = t & 1;        // class-half
  const int nl = cl >> 5;
  const uint32_t chain = (uint32_t)(blockIdx.x * 256 + cl);
  const int c0 = q * 52;
  const int yv = yl[nl];

  // state
  uint4 zz4 = *(const uint4*)&zws[chain * 4u];
  uint32_t zw0 = zz4.x, zw1 = zz4.y, zw2 = zz4.z, zw3 = zz4.w;
  h2f E2[SCH];
  #pragma unroll
  for (int k = 0; k < SCH; ++k)
    E2[k] = __builtin_bit_cast(h2f, E2s[(q * SCH + k) * NCH + chain]);

  const h2f one2 = {(_Float16)1.0f, (_Float16)1.0f};
  float Sb;
  {
    float a0 = 0.f, a1 = 0.f, a2 = 0.f, a3 = 0.f;
    #pragma unroll
    for (int k = 0; k < SCH; ++k) {
      if ((k & 3) == 0) a0 = dot2f(E2[k], one2, a0);
      if ((k & 3) == 1) a1 = dot2f(E2[k], one2, a1);
      if ((k & 3) == 2) a2 = dot2f(E2[k], one2, a2);
      if ((k & 3) == 3) a3 = dot2f(E2[k], one2, a3);
    }
    Sb = qsum2((a0 + a1) + (a2 + a3));
  }

  #pragma unroll 1
  for (int jb = 0; jb < Mm; jb += 4) {
    int w = jb >> 5;
    uint32_t zwv = (w == 0) ? zw0 : ((w == 1) ? zw1 : ((w == 2) ? zw2 : zw3));
    const int sh = jb & 31;
    uint32_t b0 = (zwv >> (sh + 0)) & 1u;
    uint32_t b1 = (zwv >> (sh + 1)) & 1u;
    uint32_t b2 = (zwv >> (sh + 2)) & 1u;
    uint32_t b3 = (zwv >> (sh + 3)) & 1u;
    float4 elv = *(const float4*)&elpi[nl * ELS + jb];
    float ey0 = __half2float(tabh[0][jb + 0][yv]);
    float ey1 = __half2float(tabh[0][jb + 1][yv]);
    float ey2 = __half2float(tabh[0][jb + 2][yv]);
    float ey3 = __half2float(tabh[0][jb + 3][yv]);
    float u0 = urand(chain, 256u + (uint32_t)(jb + 0));
    float u1 = urand(chain, 256u + (uint32_t)(jb + 1));
    float u2 = urand(chain, 256u + (uint32_t)(jb + 2));
    float u3 = urand(chain, 256u + (uint32_t)(jb + 3));

    auto step = [&](int j, uint32_t zjp, float ey, float el, float u) -> uint32_t {
      const __half* p = &tabh[(int)zjp][j][c0];
      uint2 v[13];
      #pragma unroll
      for (int k = 0; k < 13; ++k) v[k] = *(const uint2*)(p + 4 * k);
      float d0 = 0.f, d1 = 0.f, d2 = 0.f, d3 = 0.f;
      #pragma unroll
      for (int k = 0; k < 13; ++k) {
        h2f ta = __builtin_bit_cast(h2f, v[k].x);
        h2f tb = __builtin_bit_cast(h2f, v[k].y);
        if (k & 1) { d2 = dot2f(E2[2 * k + 0], ta, d2); d3 = dot2f(E2[2 * k + 1], tb, d3); }
        else       { d0 = dot2f(E2[2 * k + 0], ta, d0); d1 = dot2f(E2[2 * k + 1], tb, d1); }
      }
      float D = qsum2((d0 + d1) + (d2 + d3));
      float Spos = zjp ? Sb : D;
      float Sneg = zjp ? D : Sb;
      float odds = ey * Sneg * __builtin_amdgcn_rcpf(Spos) * el;
      uint32_t znp = (u * (1.0f + odds) < odds) ? 1u : 0u;
      uint32_t flip = znp ^ zjp;
      bool fl = (flip != 0u);
      #pragma unroll
      for (int k = 0; k < 13; ++k) {
        h2f ta = __builtin_bit_cast(h2f, v[k].x);
        h2f tb = __builtin_bit_cast(h2f, v[k].y);
        h2f fa = fl ? ta : one2;
        h2f fb = fl ? tb : one2;
        E2[2 * k + 0] *= fa;
        E2[2 * k + 1] *= fb;
      }
      Sb = fl ? D : Sb;
      return znp;
    };
    b0 = step(jb + 0, b0, ey0, elv.x, u0);
    b1 = step(jb + 1, b1, ey1, elv.y, u1);
    b2 = step(jb + 2, b2, ey2, elv.z, u2);
    b3 = step(jb + 3, b3, ey3, elv.w, u3);

    uint32_t nib = b0 | (b1 << 1) | (b2 << 2) | (b3 << 3);
    zwv = (zwv & ~(0xFu << sh)) | (nib << sh);
    if (w == 0) zw0 = zwv; else if (w == 1) zw1 = zwv;
    else if (w == 2) zw2 = zwv; else zw3 = zwv;
  }

  float Sf;
  {
    float a0 = 0.f, a1 = 0.f, a2 = 0.f, a3 = 0.f;
    #pragma unroll
    for (int k = 0; k < SCH; ++k) {
      if ((k & 3) == 0) a0 = dot2f(E2[k], one2, a0);
      if ((k & 3) == 1) a1 = dot2f(E2[k], one2, a1);
      if ((k & 3) == 2) a2 = dot2f(E2[k], one2, a2);
      if ((k & 3) == 3) a3 = dot2f(E2[k], one2, a3);
    }
    Sf = qsum2((a0 + a1) + (a2 + a3));
  }
  if (q == 0) {
    lse_out[chain] = __logf(Sf) + ESCLOG;
    uint4 o; o.x = zw0; o.y = zw1; o.z = zw2; o.w = zw3;
    *(uint4*)&zbits_out[chain * 4u] = o;
  }
}

// ---------------- Kernel C: moments + all four terms, atomic scalar reduce ----------------
__global__ __launch_bounds__(128) void k_final(const float* __restrict__ lpi,
                                               const int* __restrict__ y,
                                               const float* __restrict__ beta0,
                                               const float* __restrict__ beta,
                                               const float* __restrict__ lse_in,
                                               const uint32_t* __restrict__ zbits,
                                               float* __restrict__ out) {
  __shared__ uint32_t zs[128];
  __shared__ float red[128];
  const int n = blockIdx.x;
  const int t = threadIdx.x;
  zs[t] = zbits[n * 128 + t];
  __syncthreads();
  const int w = t >> 5, bsh = t & 31;
  int cnt = 0;
  #pragma unroll
  for (int s = 0; s < 32; ++s) cnt += (int)((zs[s * 4 + w] >> bsh) & 1u);
  float EI = (float)cnt * (1.0f / 32.0f);
  float EII = 2.0f * EI - 1.0f;
  float l = lpi[n * Mm + t];
  int yv = y[n];
  float sp = (l > 20.0f) ? l : log1pf(__expf(l));
  float term = EII * beta[yv * Mm + t] + EI * l - sp;
  if (t < 32) term -= lse_in[n * 32 + t] * (1.0f / 32.0f);
  red[t] = term;
  __syncthreads();
  for (int off = 64; off > 0; off >>= 1) {
    if (t < off) red[t] += red[t + off];
    __syncthreads();
  }
  if (t == 0) atomicAdd(out, red[0] + beta0[yv]);
}

extern "C" void kernel_launch(void* const* d_in, const int* in_sizes, int n_in,
                              void* d_out, int out_size, void* d_ws, size_t ws_size,
                              hipStream_t stream) {
  const float* x = (const float*)d_in[0];
  const int* y = (const int*)d_in[1];
  const float* alpha0 = (const float*)d_in[2];
  const float* alpha = (const float*)d_in[3];
  const float* beta0 = (const float*)d_in[4];
  const float* beta = (const float*)d_in[5];
  float* out = (float*)d_out;

  char* ws = (char*)d_ws;
  float* lpi = (float*)ws;                                    // 1 MB   [gemm..final]
  float* lse = (float*)(ws + (1u << 20));                     // 256 KB [sweep..final]
  uint32_t* zb = (uint32_t*)(ws + (1u << 20) + (1u << 18));   // 1 MB   [sweep..final]
  uint32_t* zws = (uint32_t*)(ws + 2 * (1u << 20) + (1u << 18));        // 1 MB [init..sweep]
  char* unionbase = ws + 3 * (1u << 20) + (1u << 18);
  uint16_t* xb = (uint16_t*)unionbase;                        // 4 MB   [prep..gemm]
  uint16_t* ab = (uint16_t*)(unionbase + 4 * (1u << 20));     // 256 KB [prep..gemm]
  uint32_t* E2s = (uint32_t*)unionbase;                       // 13.6 MB [init..sweep] (overlaps xb/ab)

  hipMemsetAsync(d_out, 0, sizeof(float), stream);
  k_prep<<<512, 256, 0, stream>>>(x, alpha, alpha0, xb, ab, lpi);
  k_lingemm<<<256, 256, 0, stream>>>(xb, ab, lpi);
  k_init<<<Nn / 4, 512, 0, stream>>>(beta0, beta, lpi, zws, E2s);
  k_sweep<<<Nn / 8, 512, 0, stream>>>(beta, y, lpi, zws, E2s, lse, zb);
  k_final<<<Nn, 128, 0, stream>>>(lpi, y, beta0, beta, lse, zb, out);
}

// Round 6
// 144.746 us; speedup vs baseline: 4.4701x; 1.1903x over previous
//
#include <hip/hip_runtime.h>
#include <hip/hip_fp16.h>
#include <stdint.h>

#define Nn 2048
#define Ff 1024
#define Mm 128
#define Cc 100
#define Ss 32
#define NCH (Nn * Ss)   // 65536 chains
// k_init geometry (4 lanes/chain)
#define CS 28
#define CH 14
#define BSTR 132        // staged-beta stride (f32)
// k_sweep geometry (2 lanes/chain)
#define SCP 104         // table row stride in halfs
#define SCH 26          // half2 per sweep lane
#define ELS 132
#define ESC 0.015625f          // 2^-6 scale on E
#define ESCLOG 4.15888308336f  // 6*ln2

typedef _Float16 h2f __attribute__((ext_vector_type(2)));
typedef short bf8 __attribute__((ext_vector_type(8)));
typedef float f32x4 __attribute__((ext_vector_type(4)));

__device__ __forceinline__ float dot2f(h2f a, h2f b, float c) {
#if __has_builtin(__builtin_amdgcn_fdot2)
  return __builtin_amdgcn_fdot2(a, b, c, false);
#else
  return fmaf((float)a[0], (float)b[0], fmaf((float)a[1], (float)b[1], c));
#endif
}

// pair-sum (lane t with lane t^1) via DPP quad_perm [1,0,3,2]
__device__ __forceinline__ float qsum2(float x) {
  int a = __builtin_amdgcn_update_dpp(0, __builtin_bit_cast(int, x), 0xB1, 0xF, 0xF, false);
  return x + __builtin_bit_cast(float, a);
}

__device__ __forceinline__ float urand(uint32_t chain, uint32_t ctr) {
  uint32_t h = chain * 0x9E3779B9u ^ (ctr * 0x85EBCA6Bu);
  h ^= h >> 16; h *= 0x7FEB352Du;
  h ^= h >> 15; h *= 0x846CA68Bu;
  h ^= h >> 16;
  return (float)(h >> 8) * (1.0f / 16777216.0f);
}

__device__ __forceinline__ uint32_t f2bf(float f) {
  uint32_t b = __builtin_bit_cast(uint32_t, f);
  return (b + 0x7FFFu + ((b >> 16) & 1u)) >> 16;
}

// ------------- Kernel A: lpi += x @ alpha^T via MFMA, inline f32->bf16 cvt -------------
__global__ __launch_bounds__(256) void k_lingemm(const float* __restrict__ x,
                                                 const float* __restrict__ alpha,
                                                 float* __restrict__ lpi) {
  __shared__ uint4 sA[256];    // 32 rows x 8 chunks (64 bf16/row), swizzled
  __shared__ uint4 sB[1024];   // 128 rows x 8 chunks
  const int t = threadIdx.x;
  const int mt = blockIdx.x >> 2;
  const int ks = blockIdx.x & 3;
  const int m0 = mt * 32;
  const int w = t >> 6;
  const int l = t & 63;

  f32x4 acc[2][2] = {{{0.f, 0.f, 0.f, 0.f}, {0.f, 0.f, 0.f, 0.f}},
                     {{0.f, 0.f, 0.f, 0.f}, {0.f, 0.f, 0.f, 0.f}}};

  for (int kk = 0; kk < 4; ++kk) {
    const int k0 = ks * 256 + kk * 64;
    __syncthreads();
    {
      int row = t >> 3, c = t & 7;
      const float* px = &x[(m0 + row) * Ff + k0 + c * 8];
      float4 f0 = *(const float4*)px;
      float4 f1 = *(const float4*)(px + 4);
      uint4 v;
      v.x = f2bf(f0.x) | (f2bf(f0.y) << 16);
      v.y = f2bf(f0.z) | (f2bf(f0.w) << 16);
      v.z = f2bf(f1.x) | (f2bf(f1.y) << 16);
      v.w = f2bf(f1.z) | (f2bf(f1.w) << 16);
      sA[row * 8 + (c ^ (row & 7))] = v;
      #pragma unroll
      for (int rr = 0; rr < 4; ++rr) {
        int idx = t + rr * 256;
        int rowb = idx >> 3, cb = idx & 7;
        const float* pa = &alpha[rowb * Ff + k0 + cb * 8];
        float4 g0 = *(const float4*)pa;
        float4 g1 = *(const float4*)(pa + 4);
        uint4 vb;
        vb.x = f2bf(g0.x) | (f2bf(g0.y) << 16);
        vb.y = f2bf(g0.z) | (f2bf(g0.w) << 16);
        vb.z = f2bf(g1.x) | (f2bf(g1.y) << 16);
        vb.w = f2bf(g1.z) | (f2bf(g1.w) << 16);
        sB[rowb * 8 + (cb ^ (rowb & 7))] = vb;
      }
    }
    __syncthreads();
    #pragma unroll
    for (int kc = 0; kc < 2; ++kc) {
      int chunk = kc * 4 + (l >> 4);
      bf8 av[2], bv[2];
      #pragma unroll
      for (int fm = 0; fm < 2; ++fm) {
        int row = fm * 16 + (l & 15);
        av[fm] = __builtin_bit_cast(bf8, sA[row * 8 + (chunk ^ (row & 7))]);
      }
      #pragma unroll
      for (int fn = 0; fn < 2; ++fn) {
        int rowb = w * 32 + fn * 16 + (l & 15);
        bv[fn] = __builtin_bit_cast(bf8, sB[rowb * 8 + (chunk ^ (rowb & 7))]);
      }
      #pragma unroll
      for (int fm = 0; fm < 2; ++fm)
        #pragma unroll
        for (int fn = 0; fn < 2; ++fn)
          acc[fm][fn] = __builtin_amdgcn_mfma_f32_16x16x32_bf16(av[fm], bv[fn], acc[fm][fn], 0, 0, 0);
    }
  }
  #pragma unroll
  for (int fm = 0; fm < 2; ++fm)
    #pragma unroll
    for (int fn = 0; fn < 2; ++fn)
      #pragma unroll
      for (int r = 0; r < 4; ++r) {
        int row = m0 + fm * 16 + (l >> 4) * 4 + r;
        int col = w * 32 + fn * 16 + (l & 15);
        atomicAdd(&lpi[row * Mm + col], acc[fm][fn][r]);
      }
}

// ------------- Kernel B1: Z0 sample + E-init (beta staged in LDS, 4 lanes/chain) -------------
__global__ __launch_bounds__(512, 4) void k_init(const float* __restrict__ beta0,
                                                 const float* __restrict__ beta,
                                                 const float* __restrict__ alpha0,
                                                 const float* __restrict__ lpi,
                                                 uint32_t* __restrict__ zws,
                                                 uint32_t* __restrict__ E2s) {
  __shared__ float bs[112 * BSTR];
  __shared__ float elpi[4 * ELS];
  const int t = threadIdx.x;
  const int n0 = blockIdx.x * 4;

  for (int idx = t; idx < 112 * 64; idx += 512) {
    int row = idx >> 6, col2 = (idx & 63) * 2;
    float2 v;
    if (row < Cc) v = *(const float2*)&beta[row * Mm + col2];
    else { v.x = 0.f; v.y = 0.f; }
    *(float2*)&bs[row * BSTR + col2] = v;
  }
  {
    int nl = t >> 7, j = t & 127;
    elpi[nl * ELS + j] = __expf(lpi[(n0 + nl) * Mm + j] + alpha0[j]);
  }
  __syncthreads();

  const int cl = t >> 2;
  const int q = t & 3;
  const int nl = cl >> 5;
  const int s = cl & 31;
  const uint32_t chain = (uint32_t)((n0 + nl) * Ss + s);
  const int c0 = q * CS;
  const float* elrow = &elpi[nl * ELS];
  const int lane = t & 63;

  uint32_t zw0, zw1, zw2, zw3;
  {
    uint32_t zz = 0;
    #pragma unroll 1
    for (int b5 = 0; b5 < 32; ++b5) {
      int mloc = (b5 + q * 8) & 31;
      int m = q * 32 + mloc;
      float u = urand(chain, (uint32_t)m);
      float el = elrow[m];
      zz |= (u * (1.0f + el) < el) ? (1u << mloc) : 0u;
    }
    int base = lane & ~3;
    zw0 = (uint32_t)__shfl((int)zz, base + 0);
    zw1 = (uint32_t)__shfl((int)zz, base + 1);
    zw2 = (uint32_t)__shfl((int)zz, base + 2);
    zw3 = (uint32_t)__shfl((int)zz, base + 3);
  }

  float acc[CS];
  #pragma unroll
  for (int i = 0; i < CS; ++i) acc[i] = 0.0f;
  #pragma unroll 1
  for (int mb = 0; mb < 32; ++mb) {
    int w = mb >> 3;
    uint32_t zz = (w == 0) ? zw0 : ((w == 1) ? zw1 : ((w == 2) ? zw2 : zw3));
    int sh = (mb & 7) * 4;
    float s0 = ((zz >> (sh + 0)) & 1u) ? 1.0f : -1.0f;
    float s1 = ((zz >> (sh + 1)) & 1u) ? 1.0f : -1.0f;
    float s2 = ((zz >> (sh + 2)) & 1u) ? 1.0f : -1.0f;
    float s3 = ((zz >> (sh + 3)) & 1u) ? 1.0f : -1.0f;
    int m0 = mb * 4;
    #pragma unroll
    for (int i = 0; i < CS; ++i) {
      float4 bv = *(const float4*)&bs[(c0 + i) * BSTR + m0];
      acc[i] = fmaf(s0, bv.x, fmaf(s1, bv.y, fmaf(s2, bv.z, fmaf(s3, bv.w, acc[i]))));
    }
  }

  #pragma unroll
  for (int i2 = 0; i2 < CH; ++i2) {
    int k = q * CH + i2;
    if (k < 52) {
      int ca = c0 + 2 * i2, cb = ca + 1;
      float ba = beta0[(ca < Cc) ? ca : 0];
      float bb = beta0[(cb < Cc) ? cb : 0];
      float ea = (ca < Cc) ? __expf(acc[2 * i2 + 0] + ba) * ESC : 0.0f;
      float eb = (cb < Cc) ? __expf(acc[2 * i2 + 1] + bb) * ESC : 0.0f;
      h2f e; e[0] = (_Float16)ea; e[1] = (_Float16)eb;
      E2s[k * NCH + chain] = __builtin_bit_cast(uint32_t, e);
    }
  }
  zws[blockIdx.x * 512 + t] = (q == 0) ? zw0 : ((q == 1) ? zw1 : ((q == 2) ? zw2 : zw3));
}

// ------------- Kernel B2: Gibbs sweep (software-pipelined) + fused final reduction -------------
__global__ __launch_bounds__(512, 2) void k_sweep(const float* __restrict__ beta,
                                                  const int* __restrict__ y,
                                                  const float* __restrict__ beta0,
                                                  const float* __restrict__ alpha0,
                                                  const float* __restrict__ lpi,
                                                  const uint32_t* __restrict__ zws,
                                                  const uint32_t* __restrict__ E2s,
                                                  float* __restrict__ out) {
  __shared__ __half tabh[2][Mm][SCP];   // 53248 B
  __shared__ float elpi[8 * ELS];
  __shared__ float lpil[8 * Mm];
  __shared__ uint32_t zsl[256][4];
  __shared__ float lsel[256];
  __shared__ float red[512];
  __shared__ int yl[8];
  const int t = threadIdx.x;
  const int n0 = blockIdx.x * 8;

  for (int idx = t; idx < 32 * Cc; idx += 512) {
    int j4 = idx / Cc;
    int c = idx - j4 * Cc;
    float4 bv = *(const float4*)&beta[c * Mm + j4 * 4];
    int j = j4 * 4;
    tabh[0][j + 0][c] = __float2half(__expf(2.0f * bv.x));
    tabh[1][j + 0][c] = __float2half(__expf(-2.0f * bv.x));
    tabh[0][j + 1][c] = __float2half(__expf(2.0f * bv.y));
    tabh[1][j + 1][c] = __float2half(__expf(-2.0f * bv.y));
    tabh[0][j + 2][c] = __float2half(__expf(2.0f * bv.z));
    tabh[1][j + 2][c] = __float2half(__expf(-2.0f * bv.z));
    tabh[0][j + 3][c] = __float2half(__expf(2.0f * bv.w));
    tabh[1][j + 3][c] = __float2half(__expf(-2.0f * bv.w));
  }
  for (int idx = t; idx < 2 * Mm * 4; idx += 512) {
    int hsel = idx >> 9, j = (idx >> 2) & 127, c = Cc + (idx & 3);
    tabh[hsel][j][c] = __float2half(1.0f);
  }
  for (int idx = t; idx < 8 * Mm; idx += 512) {
    int nl = idx >> 7, j = idx & 127;
    float lv = lpi[(n0 + nl) * Mm + j] + alpha0[j];
    lpil[idx] = lv;
    elpi[nl * ELS + j] = __expf(lv);
  }
  if (t < 8) yl[t] = y[n0 + t];
  __syncthreads();

  const int cl = t >> 1;
  const int q = t & 1;
  const int nl = cl >> 5;
  const uint32_t chain = (uint32_t)(blockIdx.x * 256 + cl);
  const int c0 = q * 52;
  const int yv = yl[nl];

  uint4 zz4 = *(const uint4*)&zws[chain * 4u];
  uint32_t zw0 = zz4.x, zw1 = zz4.y, zw2 = zz4.z, zw3 = zz4.w;
  h2f E2[SCH];
  #pragma unroll
  for (int k = 0; k < SCH; ++k)
    E2[k] = __builtin_bit_cast(h2f, E2s[(q * SCH + k) * NCH + chain]);

  const h2f one2 = {(_Float16)1.0f, (_Float16)1.0f};
  float Sb;
  {
    float a0 = 0.f, a1 = 0.f, a2 = 0.f, a3 = 0.f;
    #pragma unroll
    for (int k = 0; k < SCH; ++k) {
      if ((k & 3) == 0) a0 = dot2f(E2[k], one2, a0);
      if ((k & 3) == 1) a1 = dot2f(E2[k], one2, a1);
      if ((k & 3) == 2) a2 = dot2f(E2[k], one2, a2);
      if ((k & 3) == 3) a3 = dot2f(E2[k], one2, a3);
    }
    Sb = qsum2((a0 + a1) + (a2 + a3));
  }

  uint2 va[13], vb[13];
  auto pf = [&](uint2 (&dst)[13], uint32_t bit, int j) {
    const __half* p = &tabh[(int)bit][j][c0];
    #pragma unroll
    for (int k = 0; k < 13; ++k) dst[k] = *(const uint2*)(p + 4 * k);
  };
  auto step = [&](uint2 (&v)[13], int j, uint32_t zjp, float ey, float el, float u) -> uint32_t {
    float d0 = 0.f, d1 = 0.f, d2 = 0.f, d3 = 0.f;
    #pragma unroll
    for (int k = 0; k < 13; ++k) {
      h2f ta = __builtin_bit_cast(h2f, v[k].x);
      h2f tb = __builtin_bit_cast(h2f, v[k].y);
      if (k & 1) { d2 = dot2f(E2[2 * k + 0], ta, d2); d3 = dot2f(E2[2 * k + 1], tb, d3); }
      else       { d0 = dot2f(E2[2 * k + 0], ta, d0); d1 = dot2f(E2[2 * k + 1], tb, d1); }
    }
    float D = qsum2((d0 + d1) + (d2 + d3));
    float Spos = zjp ? Sb : D;
    float Sneg = zjp ? D : Sb;
    float odds = ey * Sneg * __builtin_amdgcn_rcpf(Spos) * el;
    uint32_t znp = (u * (1.0f + odds) < odds) ? 1u : 0u;
    uint32_t flip = znp ^ zjp;
    bool fl = (flip != 0u);
    #pragma unroll
    for (int k = 0; k < 13; ++k) {
      h2f ta = __builtin_bit_cast(h2f, v[k].x);
      h2f tb = __builtin_bit_cast(h2f, v[k].y);
      h2f fa = fl ? ta : one2;
      h2f fb = fl ? tb : one2;
      E2[2 * k + 0] *= fa;
      E2[2 * k + 1] *= fb;
    }
    Sb = fl ? D : Sb;
    return znp;
  };

  pf(va, zw0 & 1u, 0);   // prologue: step-0 data

  #pragma unroll 1
  for (int jb = 0; jb < Mm; jb += 4) {
    int w = jb >> 5;
    uint32_t zwv = (w == 0) ? zw0 : ((w == 1) ? zw1 : ((w == 2) ? zw2 : zw3));
    const int sh = jb & 31;
    uint32_t b0 = (zwv >> (sh + 0)) & 1u;
    uint32_t b1 = (zwv >> (sh + 1)) & 1u;
    uint32_t b2 = (zwv >> (sh + 2)) & 1u;
    uint32_t b3 = (zwv >> (sh + 3)) & 1u;
    uint32_t b4;
    if (sh == 28) {
      uint32_t nw = (w == 0) ? zw1 : ((w == 1) ? zw2 : ((w == 2) ? zw3 : 0u));
      b4 = nw & 1u;
    } else {
      b4 = (zwv >> (sh + 4)) & 1u;
    }
    float4 elv = *(const float4*)&elpi[nl * ELS + jb];
    float ey0 = __half2float(tabh[0][jb + 0][yv]);
    float ey1 = __half2float(tabh[0][jb + 1][yv]);
    float ey2 = __half2float(tabh[0][jb + 2][yv]);
    float ey3 = __half2float(tabh[0][jb + 3][yv]);
    float u0 = urand(chain, 256u + (uint32_t)(jb + 0));
    float u1 = urand(chain, 256u + (uint32_t)(jb + 1));
    float u2 = urand(chain, 256u + (uint32_t)(jb + 2));
    float u3 = urand(chain, 256u + (uint32_t)(jb + 3));

    pf(vb, b1, jb + 1);
    b0 = step(va, jb + 0, b0, ey0, elv.x, u0);
    pf(va, b2, jb + 2);
    b1 = step(vb, jb + 1, b1, ey1, elv.y, u1);
    pf(vb, b3, jb + 3);
    b2 = step(va, jb + 2, b2, ey2, elv.z, u2);
    pf(va, b4, (jb + 4) & 127);
    b3 = step(vb, jb + 3, b3, ey3, elv.w, u3);

    uint32_t nib = b0 | (b1 << 1) | (b2 << 2) | (b3 << 3);
    zwv = (zwv & ~(0xFu << sh)) | (nib << sh);
    if (w == 0) zw0 = zwv; else if (w == 1) zw1 = zwv;
    else if (w == 2) zw2 = zwv; else zw3 = zwv;
  }

  float Sf;
  {
    float a0 = 0.f, a1 = 0.f, a2 = 0.f, a3 = 0.f;
    #pragma unroll
    for (int k = 0; k < SCH; ++k) {
      if ((k & 3) == 0) a0 = dot2f(E2[k], one2, a0);
      if ((k & 3) == 1) a1 = dot2f(E2[k], one2, a1);
      if ((k & 3) == 2) a2 = dot2f(E2[k], one2, a2);
      if ((k & 3) == 3) a3 = dot2f(E2[k], one2, a3);
    }
    Sf = qsum2((a0 + a1) + (a2 + a3));
  }
  if (q == 0) {
    lsel[cl] = __logf(Sf) + ESCLOG;
    zsl[cl][0] = zw0; zsl[cl][1] = zw1; zsl[cl][2] = zw2; zsl[cl][3] = zw3;
  }
  __syncthreads();

  // ---- fused final: moments + TermI..IV for this block's 8 n-rows ----
  {
    int nl2 = t >> 6;          // 0..7
    int mp = t & 63;           // handles m = 2*mp, 2*mp+1
    int wsel = mp >> 4;
    int sh0 = (mp * 2) & 31;
    int cnt0 = 0, cnt1 = 0;
    #pragma unroll 1
    for (int s = 0; s < 32; ++s) {
      uint32_t wv = zsl[nl2 * 32 + s][wsel];
      cnt0 += (int)((wv >> sh0) & 1u);
      cnt1 += (int)((wv >> (sh0 + 1)) & 1u);
    }
    int yv2 = yl[nl2];
    int m0i = mp * 2;
    float EI0 = (float)cnt0 * (1.0f / 32.0f), EI1 = (float)cnt1 * (1.0f / 32.0f);
    float EII0 = 2.0f * EI0 - 1.0f, EII1 = 2.0f * EI1 - 1.0f;
    float l0 = lpil[nl2 * Mm + m0i], l1 = lpil[nl2 * Mm + m0i + 1];
    float bb0 = beta[yv2 * Mm + m0i], bb1 = beta[yv2 * Mm + m0i + 1];
    float sp0 = (l0 > 20.0f) ? l0 : __logf(1.0f + __expf(l0));
    float sp1 = (l1 > 20.0f) ? l1 : __logf(1.0f + __expf(l1));
    float term = EII0 * bb0 + EI0 * l0 - sp0 + EII1 * bb1 + EI1 * l1 - sp1;
    if (t < 256) term -= lsel[t] * (1.0f / 32.0f);
    if (t < 8) term += beta0[yl[t]];
    red[t] = term;
  }
  __syncthreads();
  for (int off = 256; off > 0; off >>= 1) {
    if (t < off) red[t] += red[t + off];
    __syncthreads();
  }
  if (t == 0) atomicAdd(out, red[0]);
}

extern "C" void kernel_launch(void* const* d_in, const int* in_sizes, int n_in,
                              void* d_out, int out_size, void* d_ws, size_t ws_size,
                              hipStream_t stream) {
  const float* x = (const float*)d_in[0];
  const int* y = (const int*)d_in[1];
  const float* alpha0 = (const float*)d_in[2];
  const float* alpha = (const float*)d_in[3];
  const float* beta0 = (const float*)d_in[4];
  const float* beta = (const float*)d_in[5];
  float* out = (float*)d_out;

  char* ws = (char*)d_ws;
  float* lpi = (float*)ws;                                  // 1 MB  [gemm..sweep]
  uint32_t* zws = (uint32_t*)(ws + (1u << 20));             // 1 MB  [init..sweep]
  uint32_t* E2s = (uint32_t*)(ws + 2 * (1u << 20));         // 13.6 MB [init..sweep]

  hipMemsetAsync(d_out, 0, sizeof(float), stream);
  hipMemsetAsync(lpi, 0, (size_t)Nn * Mm * sizeof(float), stream);
  k_lingemm<<<256, 256, 0, stream>>>(x, alpha, lpi);
  k_init<<<Nn / 4, 512, 0, stream>>>(beta0, beta, alpha0, lpi, zws, E2s);
  k_sweep<<<Nn / 8, 512, 0, stream>>>(beta, y, beta0, alpha0, lpi, zws, E2s, out);
}

// Round 7
// 131.227 us; speedup vs baseline: 4.9306x; 1.1030x over previous
//
#include <hip/hip_runtime.h>
#include <hip/hip_fp16.h>
#include <stdint.h>

#define Nn 2048
#define Ff 1024
#define Mm 128
#define Cc 100
#define Ss 32
#define NM (Nn * Mm)
#define NCH (Nn * Ss)   // 65536 chains
// k_init geometry (4 lanes/chain)
#define CS 28
#define CH 14
#define BSTR 132        // staged-beta stride (f32)
// k_sweep geometry (2 lanes/chain): classes padded to 112, lane covers 56
#define SCP 112         // table row stride in halfs
#define TOFF 14368      // half-offset of em2 table (128*112 + 32 -> bank-disjoint)
#define ELS 132
#define ESC 0.015625f          // 2^-6 scale on E
#define ESCLOG 4.15888308336f  // 6*ln2

typedef _Float16 h2f __attribute__((ext_vector_type(2)));
typedef short bf8 __attribute__((ext_vector_type(8)));
typedef float f32x4 __attribute__((ext_vector_type(4)));

// pair-sum (lane t with lane t^1) via DPP quad_perm [1,0,3,2]
__device__ __forceinline__ float qsum2(float x) {
  int a = __builtin_amdgcn_update_dpp(0, __builtin_bit_cast(int, x), 0xB1, 0xF, 0xF, false);
  return x + __builtin_bit_cast(float, a);
}

__device__ __forceinline__ uint32_t hash32(uint32_t chain, uint32_t ctr) {
  uint32_t h = chain * 0x9E3779B9u ^ (ctr * 0x85EBCA6Bu);
  h ^= h >> 16; h *= 0x7FEB352Du;
  h ^= h >> 15; h *= 0x846CA68Bu;
  h ^= h >> 16;
  return h;
}
__device__ __forceinline__ float urand(uint32_t chain, uint32_t ctr) {
  return (float)(hash32(chain, ctr) >> 8) * (1.0f / 16777216.0f);
}

__device__ __forceinline__ uint32_t f2bf(float f) {
  uint32_t b = __builtin_bit_cast(uint32_t, f);
  return (b + 0x7FFFu + ((b >> 16) & 1u)) >> 16;
}
__device__ __forceinline__ float bf2f(uint16_t u) {
  uint32_t b = ((uint32_t)u) << 16;
  return __builtin_bit_cast(float, b);
}

// ------------- Kernel A: lpib[ks] = bf16 partial of x @ alpha^T (split-K x4) -------------
__global__ __launch_bounds__(256) void k_lingemm(const float* __restrict__ x,
                                                 const float* __restrict__ alpha,
                                                 uint16_t* __restrict__ lpib) {
  __shared__ uint4 sA[256];    // 32 rows x 8 chunks (64 bf16/row), swizzled
  __shared__ uint4 sB[1024];   // 128 rows x 8 chunks
  const int t = threadIdx.x;
  const int mt = blockIdx.x >> 2;
  const int ks = blockIdx.x & 3;
  const int m0 = mt * 32;
  const int w = t >> 6;
  const int l = t & 63;

  f32x4 acc[2][2] = {{{0.f, 0.f, 0.f, 0.f}, {0.f, 0.f, 0.f, 0.f}},
                     {{0.f, 0.f, 0.f, 0.f}, {0.f, 0.f, 0.f, 0.f}}};

  for (int kk = 0; kk < 4; ++kk) {
    const int k0 = ks * 256 + kk * 64;
    __syncthreads();
    {
      int row = t >> 3, c = t & 7;
      const float* px = &x[(m0 + row) * Ff + k0 + c * 8];
      float4 f0 = *(const float4*)px;
      float4 f1 = *(const float4*)(px + 4);
      uint4 v;
      v.x = f2bf(f0.x) | (f2bf(f0.y) << 16);
      v.y = f2bf(f0.z) | (f2bf(f0.w) << 16);
      v.z = f2bf(f1.x) | (f2bf(f1.y) << 16);
      v.w = f2bf(f1.z) | (f2bf(f1.w) << 16);
      sA[row * 8 + (c ^ (row & 7))] = v;
      #pragma unroll
      for (int rr = 0; rr < 4; ++rr) {
        int idx = t + rr * 256;
        int rowb = idx >> 3, cb = idx & 7;
        const float* pa = &alpha[rowb * Ff + k0 + cb * 8];
        float4 g0 = *(const float4*)pa;
        float4 g1 = *(const float4*)(pa + 4);
        uint4 vb;
        vb.x = f2bf(g0.x) | (f2bf(g0.y) << 16);
        vb.y = f2bf(g0.z) | (f2bf(g0.w) << 16);
        vb.z = f2bf(g1.x) | (f2bf(g1.y) << 16);
        vb.w = f2bf(g1.z) | (f2bf(g1.w) << 16);
        sB[rowb * 8 + (cb ^ (rowb & 7))] = vb;
      }
    }
    __syncthreads();
    #pragma unroll
    for (int kc = 0; kc < 2; ++kc) {
      int chunk = kc * 4 + (l >> 4);
      bf8 av[2], bv[2];
      #pragma unroll
      for (int fm = 0; fm < 2; ++fm) {
        int row = fm * 16 + (l & 15);
        av[fm] = __builtin_bit_cast(bf8, sA[row * 8 + (chunk ^ (row & 7))]);
      }
      #pragma unroll
      for (int fn = 0; fn < 2; ++fn) {
        int rowb = w * 32 + fn * 16 + (l & 15);
        bv[fn] = __builtin_bit_cast(bf8, sB[rowb * 8 + (chunk ^ (rowb & 7))]);
      }
      #pragma unroll
      for (int fm = 0; fm < 2; ++fm)
        #pragma unroll
        for (int fn = 0; fn < 2; ++fn)
          acc[fm][fn] = __builtin_amdgcn_mfma_f32_16x16x32_bf16(av[fm], bv[fn], acc[fm][fn], 0, 0, 0);
    }
  }
  #pragma unroll
  for (int fm = 0; fm < 2; ++fm)
    #pragma unroll
    for (int fn = 0; fn < 2; ++fn)
      #pragma unroll
      for (int r = 0; r < 4; ++r) {
        int row = m0 + fm * 16 + (l >> 4) * 4 + r;
        int col = w * 32 + fn * 16 + (l & 15);
        lpib[ks * NM + row * Mm + col] = (uint16_t)f2bf(acc[fm][fn][r]);
      }
}

// ------------- Kernel B1: Z0 sample + E-init (beta staged in LDS, 4 lanes/chain) -------------
__global__ __launch_bounds__(512, 4) void k_init(const float* __restrict__ beta0,
                                                 const float* __restrict__ beta,
                                                 const float* __restrict__ alpha0,
                                                 const uint16_t* __restrict__ lpib,
                                                 uint32_t* __restrict__ zws,
                                                 uint32_t* __restrict__ E2s) {
  __shared__ float bs[112 * BSTR];
  __shared__ float elpi[4 * ELS];
  const int t = threadIdx.x;
  const int n0 = blockIdx.x * 4;

  for (int idx = t; idx < 112 * 64; idx += 512) {
    int row = idx >> 6, col2 = (idx & 63) * 2;
    float2 v;
    if (row < Cc) v = *(const float2*)&beta[row * Mm + col2];
    else { v.x = 0.f; v.y = 0.f; }
    *(float2*)&bs[row * BSTR + col2] = v;
  }
  {
    int nl = t >> 7, j = t & 127;
    int g = (n0 + nl) * Mm + j;
    float lv = bf2f(lpib[g]) + bf2f(lpib[NM + g]) + bf2f(lpib[2 * NM + g]) +
               bf2f(lpib[3 * NM + g]) + alpha0[j];
    elpi[nl * ELS + j] = __expf(lv);
  }
  __syncthreads();

  const int cl = t >> 2;
  const int q = t & 3;
  const int nl = cl >> 5;
  const int s = cl & 31;
  const uint32_t chain = (uint32_t)((n0 + nl) * Ss + s);
  const int c0 = q * CS;
  const float* elrow = &elpi[nl * ELS];
  const int lane = t & 63;

  uint32_t zw0, zw1, zw2, zw3;
  {
    uint32_t zz = 0;
    #pragma unroll 1
    for (int b5 = 0; b5 < 32; ++b5) {
      int mloc = (b5 + q * 8) & 31;
      int m = q * 32 + mloc;
      float u = urand(chain, (uint32_t)m);
      float el = elrow[m];
      zz |= (u * (1.0f + el) < el) ? (1u << mloc) : 0u;
    }
    int base = lane & ~3;
    zw0 = (uint32_t)__shfl((int)zz, base + 0);
    zw1 = (uint32_t)__shfl((int)zz, base + 1);
    zw2 = (uint32_t)__shfl((int)zz, base + 2);
    zw3 = (uint32_t)__shfl((int)zz, base + 3);
  }

  float acc[CS];
  #pragma unroll
  for (int i = 0; i < CS; ++i) acc[i] = 0.0f;
  #pragma unroll 1
  for (int mb = 0; mb < 32; ++mb) {
    int w = mb >> 3;
    uint32_t zz = (w == 0) ? zw0 : ((w == 1) ? zw1 : ((w == 2) ? zw2 : zw3));
    int sh = (mb & 7) * 4;
    float s0 = ((zz >> (sh + 0)) & 1u) ? 1.0f : -1.0f;
    float s1 = ((zz >> (sh + 1)) & 1u) ? 1.0f : -1.0f;
    float s2 = ((zz >> (sh + 2)) & 1u) ? 1.0f : -1.0f;
    float s3 = ((zz >> (sh + 3)) & 1u) ? 1.0f : -1.0f;
    int m0 = mb * 4;
    #pragma unroll
    for (int i = 0; i < CS; ++i) {
      float4 bv = *(const float4*)&bs[(c0 + i) * BSTR + m0];
      acc[i] = fmaf(s0, bv.x, fmaf(s1, bv.y, fmaf(s2, bv.z, fmaf(s3, bv.w, acc[i]))));
    }
  }

  #pragma unroll
  for (int i2 = 0; i2 < CH; ++i2) {
    int k = q * CH + i2;
    if (k < 52) {
      int ca = c0 + 2 * i2, cb = ca + 1;
      float ba = beta0[(ca < Cc) ? ca : 0];
      float bb = beta0[(cb < Cc) ? cb : 0];
      float ea = (ca < Cc) ? __expf(acc[2 * i2 + 0] + ba) * ESC : 0.0f;
      float eb = (cb < Cc) ? __expf(acc[2 * i2 + 1] + bb) * ESC : 0.0f;
      h2f e; e[0] = (_Float16)ea; e[1] = (_Float16)eb;
      E2s[k * NCH + chain] = __builtin_bit_cast(uint32_t, e);
    }
  }
  zws[blockIdx.x * 512 + t] = (q == 0) ? zw0 : ((q == 1) ? zw1 : ((q == 2) ? zw2 : zw3));
}

// ------------- Kernel B2: Gibbs sweep (packed-f16, exec-masked update) + fused final -------------
__global__ __launch_bounds__(512, 2) void k_sweep(const float* __restrict__ beta,
                                                  const int* __restrict__ y,
                                                  const float* __restrict__ beta0,
                                                  const float* __restrict__ alpha0,
                                                  const uint16_t* __restrict__ lpib,
                                                  const uint32_t* __restrict__ zws,
                                                  const uint32_t* __restrict__ E2s,
                                                  float* __restrict__ out) {
  __shared__ __attribute__((aligned(16))) __half tab[2 * TOFF];  // ep2 @0, em2 @TOFF
  __shared__ float elpi[8 * ELS];
  __shared__ float lpil[8 * Mm];
  __shared__ uint32_t zsl[256][4];
  __shared__ float lsel[256];
  __shared__ float red[512];
  __shared__ int yl[8];
  const int t = threadIdx.x;
  const int n0 = blockIdx.x * 8;

  for (int idx = t; idx < 32 * Cc; idx += 512) {
    int j4 = idx / Cc;
    int c = idx - j4 * Cc;
    float4 bv = *(const float4*)&beta[c * Mm + j4 * 4];
    int j = j4 * 4;
    tab[(j + 0) * SCP + c] = __float2half(__expf(2.0f * bv.x));
    tab[TOFF + (j + 0) * SCP + c] = __float2half(__expf(-2.0f * bv.x));
    tab[(j + 1) * SCP + c] = __float2half(__expf(2.0f * bv.y));
    tab[TOFF + (j + 1) * SCP + c] = __float2half(__expf(-2.0f * bv.y));
    tab[(j + 2) * SCP + c] = __float2half(__expf(2.0f * bv.z));
    tab[TOFF + (j + 2) * SCP + c] = __float2half(__expf(-2.0f * bv.z));
    tab[(j + 3) * SCP + c] = __float2half(__expf(2.0f * bv.w));
    tab[TOFF + (j + 3) * SCP + c] = __float2half(__expf(-2.0f * bv.w));
  }
  for (int idx = t; idx < 2 * Mm * 12; idx += 512) {
    int h = idx / (Mm * 12);
    int r = idx - h * (Mm * 12);
    int j = r / 12;
    int c = Cc + (r - j * 12);
    tab[h * TOFF + j * SCP + c] = __float2half(1.0f);
  }
  for (int idx = t; idx < 8 * Mm; idx += 512) {
    int nl = idx >> 7, j = idx & 127;
    int g = (n0 + nl) * Mm + j;
    float lv = bf2f(lpib[g]) + bf2f(lpib[NM + g]) + bf2f(lpib[2 * NM + g]) +
               bf2f(lpib[3 * NM + g]) + alpha0[j];
    lpil[idx] = lv;
    elpi[nl * ELS + j] = __expf(lv);
  }
  if (t < 8) yl[t] = y[n0 + t];
  __syncthreads();

  const int cl = t >> 1;
  const int q = t & 1;
  const int nl = cl >> 5;
  const uint32_t chain = (uint32_t)(blockIdx.x * 256 + cl);
  const int c0 = q * 56;     // half index of my class slice
  const int yv = yl[nl];

  uint4 zz4 = *(const uint4*)&zws[chain * 4u];
  uint32_t zw0 = zz4.x, zw1 = zz4.y, zw2 = zz4.z, zw3 = zz4.w;

  const __half2 HZERO = __builtin_bit_cast(__half2, 0u);
  __half2 E2[28];
  #pragma unroll
  for (int k = 0; k < 28; ++k)
    E2[k] = __builtin_bit_cast(__half2, E2s[(q * 28 + k) * NCH + chain]);
  if (q) { E2[24] = HZERO; E2[25] = HZERO; E2[26] = HZERO; E2[27] = HZERO; }

  float Sb;
  {
    const __half2 one2 = __floats2half2_rn(1.0f, 1.0f);
    __half2 a0 = HZERO, a1 = HZERO, a2 = HZERO, a3 = HZERO;
    #pragma unroll
    for (int k = 0; k < 7; ++k) {
      a0 = __hfma2(E2[4 * k + 0], one2, a0);
      a1 = __hfma2(E2[4 * k + 1], one2, a1);
      a2 = __hfma2(E2[4 * k + 2], one2, a2);
      a3 = __hfma2(E2[4 * k + 3], one2, a3);
    }
    __half2 sv = __hadd2(__hadd2(a0, a1), __hadd2(a2, a3));
    Sb = qsum2(__low2float(sv) + __high2float(sv));
  }

  uint4 va[7], vb[7];
  auto pf = [&](uint4 (&dst)[7], uint32_t bit, int j) {
    const uint4* p4 = (const uint4*)(tab + (bit ? TOFF : 0) + j * SCP + c0);
    #pragma unroll
    for (int k = 0; k < 7; ++k) dst[k] = p4[k];
  };
  auto step = [&](uint4 (&v)[7], uint32_t zjp, float eyel, float u) -> uint32_t {
    __half2 a0 = HZERO, a1 = HZERO, a2 = HZERO, a3 = HZERO;
    #pragma unroll
    for (int k = 0; k < 7; ++k) {
      a0 = __hfma2(E2[4 * k + 0], __builtin_bit_cast(__half2, v[k].x), a0);
      a1 = __hfma2(E2[4 * k + 1], __builtin_bit_cast(__half2, v[k].y), a1);
      a2 = __hfma2(E2[4 * k + 2], __builtin_bit_cast(__half2, v[k].z), a2);
      a3 = __hfma2(E2[4 * k + 3], __builtin_bit_cast(__half2, v[k].w), a3);
    }
    __half2 sv = __hadd2(__hadd2(a0, a1), __hadd2(a2, a3));
    float D = qsum2(__low2float(sv) + __high2float(sv));
    float Spos = zjp ? Sb : D;
    float Sneg = zjp ? D : Sb;
    float odds = eyel * Sneg * __builtin_amdgcn_rcpf(Spos);
    uint32_t znp = (u * (1.0f + odds) < odds) ? 1u : 0u;
    if ((znp ^ zjp) != 0u) {
      #pragma unroll
      for (int k = 0; k < 7; ++k) {
        E2[4 * k + 0] = __hmul2(E2[4 * k + 0], __builtin_bit_cast(__half2, v[k].x));
        E2[4 * k + 1] = __hmul2(E2[4 * k + 1], __builtin_bit_cast(__half2, v[k].y));
        E2[4 * k + 2] = __hmul2(E2[4 * k + 2], __builtin_bit_cast(__half2, v[k].z));
        E2[4 * k + 3] = __hmul2(E2[4 * k + 3], __builtin_bit_cast(__half2, v[k].w));
      }
      Sb = D;
    }
    return znp;
  };

  pf(va, zw0 & 1u, 0);   // prologue

  #pragma unroll 1
  for (int jb = 0; jb < Mm; jb += 4) {
    int w = jb >> 5;
    uint32_t zwv = (w == 0) ? zw0 : ((w == 1) ? zw1 : ((w == 2) ? zw2 : zw3));
    const int sh = jb & 31;
    uint32_t b0 = (zwv >> (sh + 0)) & 1u;
    uint32_t b1 = (zwv >> (sh + 1)) & 1u;
    uint32_t b2 = (zwv >> (sh + 2)) & 1u;
    uint32_t b3 = (zwv >> (sh + 3)) & 1u;
    uint32_t b4;
    if (sh == 28) {
      uint32_t nw = (w == 0) ? zw1 : ((w == 1) ? zw2 : ((w == 2) ? zw3 : 0u));
      b4 = nw & 1u;
    } else {
      b4 = (zwv >> (sh + 4)) & 1u;
    }
    float4 elv = *(const float4*)&elpi[nl * ELS + jb];
    float eyel0 = __half2float(tab[(jb + 0) * SCP + yv]) * elv.x;
    float eyel1 = __half2float(tab[(jb + 1) * SCP + yv]) * elv.y;
    float eyel2 = __half2float(tab[(jb + 2) * SCP + yv]) * elv.z;
    float eyel3 = __half2float(tab[(jb + 3) * SCP + yv]) * elv.w;
    uint32_t h1 = hash32(chain, 256u + (uint32_t)jb);
    uint32_t h2 = hash32(chain, 258u + (uint32_t)jb);
    float u0 = (float)(h1 & 0xFFFFu) * (1.0f / 65536.0f);
    float u1 = (float)(h1 >> 16) * (1.0f / 65536.0f);
    float u2 = (float)(h2 & 0xFFFFu) * (1.0f / 65536.0f);
    float u3 = (float)(h2 >> 16) * (1.0f / 65536.0f);

    pf(vb, b1, jb + 1);
    b0 = step(va, b0, eyel0, u0);
    pf(va, b2, jb + 2);
    b1 = step(vb, b1, eyel1, u1);
    pf(vb, b3, jb + 3);
    b2 = step(va, b2, eyel2, u2);
    pf(va, b4, (jb + 4) & 127);
    b3 = step(vb, b3, eyel3, u3);

    uint32_t nib = b0 | (b1 << 1) | (b2 << 2) | (b3 << 3);
    zwv = (zwv & ~(0xFu << sh)) | (nib << sh);
    if (w == 0) zw0 = zwv; else if (w == 1) zw1 = zwv;
    else if (w == 2) zw2 = zwv; else zw3 = zwv;
  }

  float Sf;
  {
    const __half2 one2 = __floats2half2_rn(1.0f, 1.0f);
    __half2 a0 = HZERO, a1 = HZERO, a2 = HZERO, a3 = HZERO;
    #pragma unroll
    for (int k = 0; k < 7; ++k) {
      a0 = __hfma2(E2[4 * k + 0], one2, a0);
      a1 = __hfma2(E2[4 * k + 1], one2, a1);
      a2 = __hfma2(E2[4 * k + 2], one2, a2);
      a3 = __hfma2(E2[4 * k + 3], one2, a3);
    }
    __half2 sv = __hadd2(__hadd2(a0, a1), __hadd2(a2, a3));
    Sf = qsum2(__low2float(sv) + __high2float(sv));
  }
  if (q == 0) {
    lsel[cl] = __logf(Sf) + ESCLOG;
    zsl[cl][0] = zw0; zsl[cl][1] = zw1; zsl[cl][2] = zw2; zsl[cl][3] = zw3;
  }
  __syncthreads();

  // ---- fused final: moments + TermI..IV for this block's 8 n-rows ----
  {
    int nl2 = t >> 6;
    int mp = t & 63;
    int wsel = mp >> 4;
    int sh0 = (mp * 2) & 31;
    int cnt0 = 0, cnt1 = 0;
    #pragma unroll 1
    for (int s = 0; s < 32; ++s) {
      uint32_t wv = zsl[nl2 * 32 + s][wsel];
      cnt0 += (int)((wv >> sh0) & 1u);
      cnt1 += (int)((wv >> (sh0 + 1)) & 1u);
    }
    int yv2 = yl[nl2];
    int m0i = mp * 2;
    float EI0 = (float)cnt0 * (1.0f / 32.0f), EI1 = (float)cnt1 * (1.0f / 32.0f);
    float EII0 = 2.0f * EI0 - 1.0f, EII1 = 2.0f * EI1 - 1.0f;
    float l0 = lpil[nl2 * Mm + m0i], l1 = lpil[nl2 * Mm + m0i + 1];
    float bb0 = beta[yv2 * Mm + m0i], bb1 = beta[yv2 * Mm + m0i + 1];
    float sp0 = (l0 > 20.0f) ? l0 : __logf(1.0f + __expf(l0));
    float sp1 = (l1 > 20.0f) ? l1 : __logf(1.0f + __expf(l1));
    float term = EII0 * bb0 + EI0 * l0 - sp0 + EII1 * bb1 + EI1 * l1 - sp1;
    if (t < 256) term -= lsel[t] * (1.0f / 32.0f);
    if (t < 8) term += beta0[yl[t]];
    red[t] = term;
  }
  __syncthreads();
  for (int off = 256; off > 0; off >>= 1) {
    if (t < off) red[t] += red[t + off];
    __syncthreads();
  }
  if (t == 0) atomicAdd(out, red[0]);
}

extern "C" void kernel_launch(void* const* d_in, const int* in_sizes, int n_in,
                              void* d_out, int out_size, void* d_ws, size_t ws_size,
                              hipStream_t stream) {
  const float* x = (const float*)d_in[0];
  const int* y = (const int*)d_in[1];
  const float* alpha0 = (const float*)d_in[2];
  const float* alpha = (const float*)d_in[3];
  const float* beta0 = (const float*)d_in[4];
  const float* beta = (const float*)d_in[5];
  float* out = (float*)d_out;

  char* ws = (char*)d_ws;
  uint16_t* lpib = (uint16_t*)ws;                           // 4 planes bf16 = 2 MB
  uint32_t* zws = (uint32_t*)(ws + 2 * (1u << 20));         // 1 MB
  uint32_t* E2s = (uint32_t*)(ws + 3 * (1u << 20));         // 52 planes = 13.6 MB (+pad reads ok)

  hipMemsetAsync(d_out, 0, sizeof(float), stream);
  k_lingemm<<<256, 256, 0, stream>>>(x, alpha, lpib);
  k_init<<<Nn / 4, 512, 0, stream>>>(beta0, beta, alpha0, lpib, zws, E2s);
  k_sweep<<<Nn / 8, 512, 0, stream>>>(beta, y, beta0, alpha0, lpib, zws, E2s, out);
}

// Round 8
// 103.998 us; speedup vs baseline: 6.2215x; 1.2618x over previous
//
#include <hip/hip_runtime.h>
#include <hip/hip_fp16.h>
#include <stdint.h>

#define Nn 2048
#define Ff 1024
#define Mm 128
#define Cc 100
#define Ss 32
#define NM (Nn * Mm)
#define ELS 132
#define SCP 128          // table row stride in halfs
#define TOFF 16400       // em2 table offset in halfs (+16 halfs -> disjoint bank quads)
#define ESC 0.015625f          // 2^-6 scale on E
#define ESCLOG 4.15888308336f  // 6*ln2

typedef short bf8 __attribute__((ext_vector_type(8)));
typedef float f32x4 __attribute__((ext_vector_type(4)));

__device__ __forceinline__ uint32_t hash32(uint32_t chain, uint32_t ctr) {
  uint32_t h = chain * 0x9E3779B9u ^ (ctr * 0x85EBCA6Bu);
  h ^= h >> 16; h *= 0x7FEB352Du;
  h ^= h >> 15; h *= 0x846CA68Bu;
  h ^= h >> 16;
  return h;
}
__device__ __forceinline__ float urand(uint32_t chain, uint32_t ctr) {
  return (float)(hash32(chain, ctr) >> 8) * (1.0f / 16777216.0f);
}
__device__ __forceinline__ uint32_t f2bf(float f) {
  uint32_t b = __builtin_bit_cast(uint32_t, f);
  return (b + 0x7FFFu + ((b >> 16) & 1u)) >> 16;
}
__device__ __forceinline__ float bf2f(uint16_t u) {
  uint32_t b = ((uint32_t)u) << 16;
  return __builtin_bit_cast(float, b);
}
// class -> permuted table position (lane h = (c>>2)&3 gets contiguous slice h*32..h*32+31)
__device__ __forceinline__ int cperm(int c) {
  return ((c >> 2) & 3) * 32 + (c >> 4) * 4 + (c & 3);
}

// ------------- Kernel A: lpib[ks] = bf16 partial of x @ alpha^T (split-K x4, MFMA) -------------
__global__ __launch_bounds__(256) void k_lingemm(const float* __restrict__ x,
                                                 const float* __restrict__ alpha,
                                                 uint16_t* __restrict__ lpib) {
  __shared__ uint4 sA[256];
  __shared__ uint4 sB[1024];
  const int t = threadIdx.x;
  const int mt = blockIdx.x >> 2;
  const int ks = blockIdx.x & 3;
  const int m0 = mt * 32;
  const int w = t >> 6;
  const int l = t & 63;

  f32x4 acc[2][2] = {{{0.f, 0.f, 0.f, 0.f}, {0.f, 0.f, 0.f, 0.f}},
                     {{0.f, 0.f, 0.f, 0.f}, {0.f, 0.f, 0.f, 0.f}}};

  for (int kk = 0; kk < 4; ++kk) {
    const int k0 = ks * 256 + kk * 64;
    __syncthreads();
    {
      int row = t >> 3, c = t & 7;
      const float* px = &x[(m0 + row) * Ff + k0 + c * 8];
      float4 f0 = *(const float4*)px;
      float4 f1 = *(const float4*)(px + 4);
      uint4 v;
      v.x = f2bf(f0.x) | (f2bf(f0.y) << 16);
      v.y = f2bf(f0.z) | (f2bf(f0.w) << 16);
      v.z = f2bf(f1.x) | (f2bf(f1.y) << 16);
      v.w = f2bf(f1.z) | (f2bf(f1.w) << 16);
      sA[row * 8 + (c ^ (row & 7))] = v;
      #pragma unroll
      for (int rr = 0; rr < 4; ++rr) {
        int idx = t + rr * 256;
        int rowb = idx >> 3, cb = idx & 7;
        const float* pa = &alpha[rowb * Ff + k0 + cb * 8];
        float4 g0 = *(const float4*)pa;
        float4 g1 = *(const float4*)(pa + 4);
        uint4 vb;
        vb.x = f2bf(g0.x) | (f2bf(g0.y) << 16);
        vb.y = f2bf(g0.z) | (f2bf(g0.w) << 16);
        vb.z = f2bf(g1.x) | (f2bf(g1.y) << 16);
        vb.w = f2bf(g1.z) | (f2bf(g1.w) << 16);
        sB[rowb * 8 + (cb ^ (rowb & 7))] = vb;
      }
    }
    __syncthreads();
    #pragma unroll
    for (int kc = 0; kc < 2; ++kc) {
      int chunk = kc * 4 + (l >> 4);
      bf8 av[2], bv[2];
      #pragma unroll
      for (int fm = 0; fm < 2; ++fm) {
        int row = fm * 16 + (l & 15);
        av[fm] = __builtin_bit_cast(bf8, sA[row * 8 + (chunk ^ (row & 7))]);
      }
      #pragma unroll
      for (int fn = 0; fn < 2; ++fn) {
        int rowb = w * 32 + fn * 16 + (l & 15);
        bv[fn] = __builtin_bit_cast(bf8, sB[rowb * 8 + (chunk ^ (rowb & 7))]);
      }
      #pragma unroll
      for (int fm = 0; fm < 2; ++fm)
        #pragma unroll
        for (int fn = 0; fn < 2; ++fn)
          acc[fm][fn] = __builtin_amdgcn_mfma_f32_16x16x32_bf16(av[fm], bv[fn], acc[fm][fn], 0, 0, 0);
    }
  }
  #pragma unroll
  for (int fm = 0; fm < 2; ++fm)
    #pragma unroll
    for (int fn = 0; fn < 2; ++fn)
      #pragma unroll
      for (int r = 0; r < 4; ++r) {
        int row = m0 + fm * 16 + (l >> 4) * 4 + r;
        int col = w * 32 + fn * 16 + (l & 15);
        lpib[ks * NM + row * Mm + col] = (uint16_t)f2bf(acc[fm][fn][r]);
      }
}

// ------------- Kernel B: fused init(MFMA) + Gibbs sweep + final reduction -------------
// 512 blocks x 512 threads (4 n-rows, 32 chains each, 4 lanes/chain), 2 blocks/CU.
__global__ __launch_bounds__(512, 4) void k_gibbs(const float* __restrict__ beta0g,
                                                  const float* __restrict__ betag,
                                                  const int* __restrict__ yg,
                                                  const float* __restrict__ alpha0,
                                                  const uint16_t* __restrict__ lpib,
                                                  float* __restrict__ out) {
  __shared__ __attribute__((aligned(16))) char SM[74384];
  uint16_t* bsb = (uint16_t*)SM;            // phase A: beta bf16 [112][128] (28672 B)
  float* b0p = (float*)(SM + 28672);        // [128] permuted beta0 (512 B)
  __half* tab = (__half*)SM;                // phase B: ep2 @0, em2 @TOFF (65600 B)
  float* elpi = (float*)(SM + 65600);       // [4][ELS]
  float* lpil = (float*)(SM + 67712);       // [4][128]
  uint32_t* zsl = (uint32_t*)(SM + 69760);  // [128][4]
  float* lsel = (float*)(SM + 71808);       // [128]
  float* red = (float*)(SM + 72320);        // [512]
  int* yl = (int*)(SM + 74368);             // [4]
  const int t = threadIdx.x;
  const int n0 = blockIdx.x * 4;
  const int lane = t & 63;

  // ---- phase A: stage beta as bf16, permuted beta0, lpi sums ----
  for (int idx = t; idx < 112 * 32; idx += 512) {
    int row = idx >> 5, c4 = (idx & 31) * 4;
    float4 v = *(const float4*)&betag[row * Mm + c4];
    uint2 o;
    o.x = f2bf(v.x) | (f2bf(v.y) << 16);
    o.y = f2bf(v.z) | (f2bf(v.w) << 16);
    *(uint2*)&bsb[row * 128 + c4] = o;
  }
  if (t < 128) {
    b0p[cperm(t)] = (t < Cc) ? beta0g[t] : 0.0f;
  }
  {
    int nls = t >> 7, j = t & 127;
    int g = (n0 + nls) * Mm + j;
    float lv = bf2f(lpib[g]) + bf2f(lpib[NM + g]) + bf2f(lpib[2 * NM + g]) +
               bf2f(lpib[3 * NM + g]) + alpha0[j];
    lpil[nls * Mm + j] = lv;
    elpi[nls * ELS + j] = __expf(lv);
  }
  if (t < 4) yl[t] = yg[n0 + t];
  __syncthreads();

  // chain mapping (matches MFMA C layout): chain = wave*16 + (lane&15), class-slice h = lane>>4
  const int li = lane & 15;
  const int h = lane >> 4;
  const int cl = (t >> 6) * 16 + li;       // chain-local 0..127
  const int nl = cl >> 5;                  // wave-uniform
  const int s = cl & 31;
  const uint32_t chain = (uint32_t)((n0 + nl) * Ss + s);
  const int c0 = h * 32;                   // my table slice (halfs)
  const int yv = yl[nl];
  const int pyv = cperm(yv);

  // ---- Z0: lane (li,h) draws word h of chain li, then share ----
  uint32_t zw0, zw1, zw2, zw3;
  {
    uint32_t zz = 0;
    #pragma unroll 1
    for (int b5 = 0; b5 < 32; ++b5) {
      int mloc = (b5 + h * 8) & 31;
      int m = h * 32 + mloc;
      float u = urand(chain, (uint32_t)m);
      float el = elpi[nl * ELS + m];
      zz |= (u * (1.0f + el) < el) ? (1u << mloc) : 0u;
    }
    zw0 = (uint32_t)__shfl((int)zz, li + 0);
    zw1 = (uint32_t)__shfl((int)zz, li + 16);
    zw2 = (uint32_t)__shfl((int)zz, li + 32);
    zw3 = (uint32_t)__shfl((int)zz, li + 48);
  }

  // ---- init lin = Z0 . beta via MFMA: D[class][chain], 28 MFMA per wave ----
  f32x4 acc[7];
  #pragma unroll
  for (int T = 0; T < 7; ++T) acc[T] = (f32x4){0.f, 0.f, 0.f, 0.f};
  #pragma unroll
  for (int ks = 0; ks < 4; ++ks) {
    uint32_t zw = (ks == 0) ? zw0 : ((ks == 1) ? zw1 : ((ks == 2) ? zw2 : zw3));
    uint32_t bits8 = (zw >> (h * 8)) & 0xFFu;
    uint4 pk;
    {
      uint32_t p0 = ((bits8 >> 0) & 1u) ? 0x3F80u : 0xBF80u;
      uint32_t p1 = ((bits8 >> 1) & 1u) ? 0x3F80u : 0xBF80u;
      uint32_t p2 = ((bits8 >> 2) & 1u) ? 0x3F80u : 0xBF80u;
      uint32_t p3 = ((bits8 >> 3) & 1u) ? 0x3F80u : 0xBF80u;
      uint32_t p4 = ((bits8 >> 4) & 1u) ? 0x3F80u : 0xBF80u;
      uint32_t p5 = ((bits8 >> 5) & 1u) ? 0x3F80u : 0xBF80u;
      uint32_t p6 = ((bits8 >> 6) & 1u) ? 0x3F80u : 0xBF80u;
      uint32_t p7 = ((bits8 >> 7) & 1u) ? 0x3F80u : 0xBF80u;
      pk.x = p0 | (p1 << 16); pk.y = p2 | (p3 << 16);
      pk.z = p4 | (p5 << 16); pk.w = p6 | (p7 << 16);
    }
    bf8 B = __builtin_bit_cast(bf8, pk);
    #pragma unroll
    for (int T = 0; T < 7; ++T) {
      bf8 A = __builtin_bit_cast(bf8, *(const uint4*)&bsb[(T * 16 + li) * 128 + ks * 32 + h * 8]);
      acc[T] = __builtin_amdgcn_mfma_f32_16x16x32_bf16(A, B, acc[T], 0, 0, 0);
    }
  }

  // ---- E = exp(lin + beta0)*2^-6 packed f16; my classes i=0..27 (slice-contiguous) ----
  const __half2 HZERO = __builtin_bit_cast(__half2, 0u);
  __half2 E2[16];
  #pragma unroll
  for (int k = 0; k < 14; ++k) {
    float2 b0v = *(const float2*)&b0p[c0 + 2 * k];
    float ea = __expf(acc[(2 * k) >> 2][(2 * k) & 3] + b0v.x) * ESC;
    float eb = __expf(acc[(2 * k + 1) >> 2][(2 * k + 1) & 3] + b0v.y) * ESC;
    E2[k] = __floats2half2_rn(ea, eb);
  }
  E2[14] = HZERO; E2[15] = HZERO;
  if (h != 0) { E2[12] = HZERO; E2[13] = HZERO; }   // T=6 classes >= 100 for h>=1

  float Sb;
  {
    const __half2 one2 = __floats2half2_rn(1.0f, 1.0f);
    __half2 a0 = HZERO, a1 = HZERO, a2 = HZERO, a3 = HZERO;
    #pragma unroll
    for (int k = 0; k < 4; ++k) {
      a0 = __hfma2(E2[4 * k + 0], one2, a0);
      a1 = __hfma2(E2[4 * k + 1], one2, a1);
      a2 = __hfma2(E2[4 * k + 2], one2, a2);
      a3 = __hfma2(E2[4 * k + 3], one2, a3);
    }
    __half2 sv = __hadd2(__hadd2(a0, a1), __hadd2(a2, a3));
    float d = __low2float(sv) + __high2float(sv);
    float d1 = d + __shfl_xor(d, 16);
    Sb = d1 + __shfl_xor(d1, 32);
  }

  // ---- phase B: rebuild LDS as f16 tables (global beta, L3-hot), permuted positions ----
  __syncthreads();
  for (int idx = t; idx < 32 * Cc; idx += 512) {
    int j4 = idx / Cc;
    int c = idx - j4 * Cc;
    int p = cperm(c);
    float4 bv = *(const float4*)&betag[c * Mm + j4 * 4];
    int j = j4 * 4;
    tab[(j + 0) * SCP + p] = __float2half(__expf(2.0f * bv.x));
    tab[TOFF + (j + 0) * SCP + p] = __float2half(__expf(-2.0f * bv.x));
    tab[(j + 1) * SCP + p] = __float2half(__expf(2.0f * bv.y));
    tab[TOFF + (j + 1) * SCP + p] = __float2half(__expf(-2.0f * bv.y));
    tab[(j + 2) * SCP + p] = __float2half(__expf(2.0f * bv.z));
    tab[TOFF + (j + 2) * SCP + p] = __float2half(__expf(-2.0f * bv.z));
    tab[(j + 3) * SCP + p] = __float2half(__expf(2.0f * bv.w));
    tab[TOFF + (j + 3) * SCP + p] = __float2half(__expf(-2.0f * bv.w));
  }
  for (int idx = t; idx < Mm * 28; idx += 512) {
    int j = idx / 28;
    int c = Cc + (idx - j * 28);
    int p = cperm(c);
    tab[j * SCP + p] = __float2half(1.0f);
    tab[TOFF + j * SCP + p] = __float2half(1.0f);
  }
  __syncthreads();

  // ---- Gibbs sweep (software-pipelined ping-pong prefetch) ----
  uint4 va[4], vb[4];
  auto pf = [&](uint4 (&dst)[4], uint32_t bit, int j) {
    const uint4* p4 = (const uint4*)(tab + (bit ? TOFF : 0) + j * SCP + c0);
    dst[0] = p4[0]; dst[1] = p4[1]; dst[2] = p4[2]; dst[3] = p4[3];
  };
  auto step = [&](uint4 (&v)[4], uint32_t zjp, float eyel, float u) -> uint32_t {
    __half2 a0 = HZERO, a1 = HZERO, a2 = HZERO, a3 = HZERO;
    #pragma unroll
    for (int k = 0; k < 4; ++k) {
      a0 = __hfma2(E2[4 * k + 0], __builtin_bit_cast(__half2, v[k].x), a0);
      a1 = __hfma2(E2[4 * k + 1], __builtin_bit_cast(__half2, v[k].y), a1);
      a2 = __hfma2(E2[4 * k + 2], __builtin_bit_cast(__half2, v[k].z), a2);
      a3 = __hfma2(E2[4 * k + 3], __builtin_bit_cast(__half2, v[k].w), a3);
    }
    __half2 sv = __hadd2(__hadd2(a0, a1), __hadd2(a2, a3));
    float d = __low2float(sv) + __high2float(sv);
    float d1 = d + __shfl_xor(d, 16);
    float D = d1 + __shfl_xor(d1, 32);
    float Spos = zjp ? Sb : D;
    float Sneg = zjp ? D : Sb;
    float odds = eyel * Sneg * __builtin_amdgcn_rcpf(Spos);
    uint32_t znp = (u * (1.0f + odds) < odds) ? 1u : 0u;
    if ((znp ^ zjp) != 0u) {
      #pragma unroll
      for (int k = 0; k < 4; ++k) {
        E2[4 * k + 0] = __hmul2(E2[4 * k + 0], __builtin_bit_cast(__half2, v[k].x));
        E2[4 * k + 1] = __hmul2(E2[4 * k + 1], __builtin_bit_cast(__half2, v[k].y));
        E2[4 * k + 2] = __hmul2(E2[4 * k + 2], __builtin_bit_cast(__half2, v[k].z));
        E2[4 * k + 3] = __hmul2(E2[4 * k + 3], __builtin_bit_cast(__half2, v[k].w));
      }
      Sb = D;
    }
    return znp;
  };

  pf(va, zw0 & 1u, 0);   // prologue

  #pragma unroll 1
  for (int jb = 0; jb < Mm; jb += 4) {
    int w = jb >> 5;
    uint32_t zwv = (w == 0) ? zw0 : ((w == 1) ? zw1 : ((w == 2) ? zw2 : zw3));
    const int sh = jb & 31;
    uint32_t b0 = (zwv >> (sh + 0)) & 1u;
    uint32_t b1 = (zwv >> (sh + 1)) & 1u;
    uint32_t b2 = (zwv >> (sh + 2)) & 1u;
    uint32_t b3 = (zwv >> (sh + 3)) & 1u;
    uint32_t b4;
    if (sh == 28) {
      uint32_t nw = (w == 0) ? zw1 : ((w == 1) ? zw2 : ((w == 2) ? zw3 : 0u));
      b4 = nw & 1u;
    } else {
      b4 = (zwv >> (sh + 4)) & 1u;
    }
    float4 elv = *(const float4*)&elpi[nl * ELS + jb];
    float eyel0 = __half2float(tab[(jb + 0) * SCP + pyv]) * elv.x;
    float eyel1 = __half2float(tab[(jb + 1) * SCP + pyv]) * elv.y;
    float eyel2 = __half2float(tab[(jb + 2) * SCP + pyv]) * elv.z;
    float eyel3 = __half2float(tab[(jb + 3) * SCP + pyv]) * elv.w;
    uint32_t h1 = hash32(chain, 256u + (uint32_t)jb);
    uint32_t h2 = hash32(chain, 258u + (uint32_t)jb);
    float u0 = (float)(h1 & 0xFFFFu) * (1.0f / 65536.0f);
    float u1 = (float)(h1 >> 16) * (1.0f / 65536.0f);
    float u2 = (float)(h2 & 0xFFFFu) * (1.0f / 65536.0f);
    float u3 = (float)(h2 >> 16) * (1.0f / 65536.0f);

    pf(vb, b1, jb + 1);
    b0 = step(va, b0, eyel0, u0);
    pf(va, b2, jb + 2);
    b1 = step(vb, b1, eyel1, u1);
    pf(vb, b3, jb + 3);
    b2 = step(va, b2, eyel2, u2);
    pf(va, b4, (jb + 4) & 127);
    b3 = step(vb, b3, eyel3, u3);

    uint32_t nib = b0 | (b1 << 1) | (b2 << 2) | (b3 << 3);
    zwv = (zwv & ~(0xFu << sh)) | (nib << sh);
    if (w == 0) zw0 = zwv; else if (w == 1) zw1 = zwv;
    else if (w == 2) zw2 = zwv; else zw3 = zwv;
  }

  // ---- outputs to LDS ----
  float Sf;
  {
    const __half2 one2 = __floats2half2_rn(1.0f, 1.0f);
    __half2 a0 = HZERO, a1 = HZERO, a2 = HZERO, a3 = HZERO;
    #pragma unroll
    for (int k = 0; k < 4; ++k) {
      a0 = __hfma2(E2[4 * k + 0], one2, a0);
      a1 = __hfma2(E2[4 * k + 1], one2, a1);
      a2 = __hfma2(E2[4 * k + 2], one2, a2);
      a3 = __hfma2(E2[4 * k + 3], one2, a3);
    }
    __half2 sv = __hadd2(__hadd2(a0, a1), __hadd2(a2, a3));
    float d = __low2float(sv) + __high2float(sv);
    float d1 = d + __shfl_xor(d, 16);
    Sf = d1 + __shfl_xor(d1, 32);
  }
  if (h == 0) {
    lsel[cl] = __logf(Sf) + ESCLOG;
    zsl[cl * 4 + 0] = zw0; zsl[cl * 4 + 1] = zw1;
    zsl[cl * 4 + 2] = zw2; zsl[cl * 4 + 3] = zw3;
  }
  __syncthreads();

  // ---- fused final: moments + all four terms for this block's 4 n-rows ----
  {
    int nl2 = t >> 7;       // 0..3
    int mp = t & 127;       // m
    int wsel = mp >> 5, sh0 = mp & 31;
    int cnt = 0;
    #pragma unroll 1
    for (int s2 = 0; s2 < 32; ++s2)
      cnt += (int)((zsl[(nl2 * 32 + s2) * 4 + wsel] >> sh0) & 1u);
    float EI = (float)cnt * (1.0f / 32.0f);
    float EII = 2.0f * EI - 1.0f;
    float l = lpil[nl2 * Mm + mp];
    int yv2 = yl[nl2];
    float bb = betag[yv2 * Mm + mp];
    float sp = (l > 20.0f) ? l : __logf(1.0f + __expf(l));
    float term = EII * bb + EI * l - sp;
    if (t < 128) term -= lsel[t] * (1.0f / 32.0f);
    if (t < 4) term += beta0g[yl[t]];
    red[t] = term;
  }
  __syncthreads();
  for (int off = 256; off > 0; off >>= 1) {
    if (t < off) red[t] += red[t + off];
    __syncthreads();
  }
  if (t == 0) atomicAdd(out, red[0]);
}

extern "C" void kernel_launch(void* const* d_in, const int* in_sizes, int n_in,
                              void* d_out, int out_size, void* d_ws, size_t ws_size,
                              hipStream_t stream) {
  const float* x = (const float*)d_in[0];
  const int* y = (const int*)d_in[1];
  const float* alpha0 = (const float*)d_in[2];
  const float* alpha = (const float*)d_in[3];
  const float* beta0 = (const float*)d_in[4];
  const float* beta = (const float*)d_in[5];
  float* out = (float*)d_out;

  uint16_t* lpib = (uint16_t*)d_ws;   // 4 bf16 split-K planes = 2 MB

  hipMemsetAsync(d_out, 0, sizeof(float), stream);
  k_lingemm<<<256, 256, 0, stream>>>(x, alpha, lpib);
  k_gibbs<<<512, 512, 0, stream>>>(beta0, beta, y, alpha0, lpib, out);
}

// Round 9
// 103.144 us; speedup vs baseline: 6.2730x; 1.0083x over previous
//
#include <hip/hip_runtime.h>
#include <hip/hip_fp16.h>
#include <stdint.h>

#define Nn 2048
#define Ff 1024
#define Mm 128
#define Cc 100
#define Ss 32
#define NM (Nn * Mm)
#define ELS 132
#define SCP 128          // table row stride in halfs
#define TOFF 16416       // em2 offset in halfs: byte 32832 == 64 mod 128 -> +4 bank-quad phase
#define ESC 0.015625f          // 2^-6 scale on E
#define ESCLOG 4.15888308336f  // 6*ln2

typedef _Float16 h2f __attribute__((ext_vector_type(2)));
typedef short bf8 __attribute__((ext_vector_type(8)));
typedef float f32x4 __attribute__((ext_vector_type(4)));

// 4-lane quad sum via DPP quad_perm (pure VALU, no LDS pipe)
__device__ __forceinline__ float qsum4(float x) {
  int a = __builtin_amdgcn_update_dpp(0, __builtin_bit_cast(int, x), 0xB1, 0xF, 0xF, false);
  float xf = x + __builtin_bit_cast(float, a);
  int b = __builtin_amdgcn_update_dpp(0, __builtin_bit_cast(int, xf), 0x4E, 0xF, 0xF, false);
  return xf + __builtin_bit_cast(float, b);
}

__device__ __forceinline__ float dot2f(h2f a, h2f b, float c) {
#if __has_builtin(__builtin_amdgcn_fdot2)
  return __builtin_amdgcn_fdot2(a, b, c, false);
#else
  return fmaf((float)a[0], (float)b[0], fmaf((float)a[1], (float)b[1], c));
#endif
}

__device__ __forceinline__ uint32_t hash32(uint32_t chain, uint32_t ctr) {
  uint32_t h = chain * 0x9E3779B9u ^ (ctr * 0x85EBCA6Bu);
  h ^= h >> 16; h *= 0x7FEB352Du;
  h ^= h >> 15; h *= 0x846CA68Bu;
  h ^= h >> 16;
  return h;
}
__device__ __forceinline__ float urand(uint32_t chain, uint32_t ctr) {
  return (float)(hash32(chain, ctr) >> 8) * (1.0f / 16777216.0f);
}
__device__ __forceinline__ uint32_t f2bf(float f) {
  uint32_t b = __builtin_bit_cast(uint32_t, f);
  return (b + 0x7FFFu + ((b >> 16) & 1u)) >> 16;
}
__device__ __forceinline__ float bf2f(uint16_t u) {
  uint32_t b = ((uint32_t)u) << 16;
  return __builtin_bit_cast(float, b);
}
// class -> permuted position: window h=(c>>2)&3 holds contiguous slice [h*32, h*32+32)
__device__ __forceinline__ int cperm(int c) {
  return ((c >> 2) & 3) * 32 + (c >> 4) * 4 + (c & 3);
}
// chunk rotation within window: logical chunk k of window w stored at chunk (k+w)&3
__device__ __forceinline__ int swz(int p) {
  int win = p >> 5, o = p & 31;
  return win * 32 + (((o >> 3) + win) & 3) * 8 + (o & 7);
}

// ------------- Kernel A: lpib[ks] = bf16 partial of x @ alpha^T (split-K x4, MFMA) -------------
__global__ __launch_bounds__(256) void k_lingemm(const float* __restrict__ x,
                                                 const float* __restrict__ alpha,
                                                 uint16_t* __restrict__ lpib) {
  __shared__ uint4 sA[256];
  __shared__ uint4 sB[1024];
  const int t = threadIdx.x;
  const int mt = blockIdx.x >> 2;
  const int ks = blockIdx.x & 3;
  const int m0 = mt * 32;
  const int w = t >> 6;
  const int l = t & 63;

  f32x4 acc[2][2] = {{{0.f, 0.f, 0.f, 0.f}, {0.f, 0.f, 0.f, 0.f}},
                     {{0.f, 0.f, 0.f, 0.f}, {0.f, 0.f, 0.f, 0.f}}};

  for (int kk = 0; kk < 4; ++kk) {
    const int k0 = ks * 256 + kk * 64;
    __syncthreads();
    {
      int row = t >> 3, c = t & 7;
      const float* px = &x[(m0 + row) * Ff + k0 + c * 8];
      float4 f0 = *(const float4*)px;
      float4 f1 = *(const float4*)(px + 4);
      uint4 v;
      v.x = f2bf(f0.x) | (f2bf(f0.y) << 16);
      v.y = f2bf(f0.z) | (f2bf(f0.w) << 16);
      v.z = f2bf(f1.x) | (f2bf(f1.y) << 16);
      v.w = f2bf(f1.z) | (f2bf(f1.w) << 16);
      sA[row * 8 + (c ^ (row & 7))] = v;
      #pragma unroll
      for (int rr = 0; rr < 4; ++rr) {
        int idx = t + rr * 256;
        int rowb = idx >> 3, cb = idx & 7;
        const float* pa = &alpha[rowb * Ff + k0 + cb * 8];
        float4 g0 = *(const float4*)pa;
        float4 g1 = *(const float4*)(pa + 4);
        uint4 vb;
        vb.x = f2bf(g0.x) | (f2bf(g0.y) << 16);
        vb.y = f2bf(g0.z) | (f2bf(g0.w) << 16);
        vb.z = f2bf(g1.x) | (f2bf(g1.y) << 16);
        vb.w = f2bf(g1.z) | (f2bf(g1.w) << 16);
        sB[rowb * 8 + (cb ^ (rowb & 7))] = vb;
      }
    }
    __syncthreads();
    #pragma unroll
    for (int kc = 0; kc < 2; ++kc) {
      int chunk = kc * 4 + (l >> 4);
      bf8 av[2], bv[2];
      #pragma unroll
      for (int fm = 0; fm < 2; ++fm) {
        int row = fm * 16 + (l & 15);
        av[fm] = __builtin_bit_cast(bf8, sA[row * 8 + (chunk ^ (row & 7))]);
      }
      #pragma unroll
      for (int fn = 0; fn < 2; ++fn) {
        int rowb = w * 32 + fn * 16 + (l & 15);
        bv[fn] = __builtin_bit_cast(bf8, sB[rowb * 8 + (chunk ^ (rowb & 7))]);
      }
      #pragma unroll
      for (int fm = 0; fm < 2; ++fm)
        #pragma unroll
        for (int fn = 0; fn < 2; ++fn)
          acc[fm][fn] = __builtin_amdgcn_mfma_f32_16x16x32_bf16(av[fm], bv[fn], acc[fm][fn], 0, 0, 0);
    }
  }
  #pragma unroll
  for (int fm = 0; fm < 2; ++fm)
    #pragma unroll
    for (int fn = 0; fn < 2; ++fn)
      #pragma unroll
      for (int r = 0; r < 4; ++r) {
        int row = m0 + fm * 16 + (l >> 4) * 4 + r;
        int col = w * 32 + fn * 16 + (l & 15);
        lpib[ks * NM + row * Mm + col] = (uint16_t)f2bf(acc[fm][fn][r]);
      }
}

// ------------- Kernel B: fused init(MFMA) + quad-layout Gibbs sweep + final reduction -------------
// 256 blocks x 1024 threads: 8 n-rows, 256 chains/block, 4 lanes/chain (lane-quads).
__global__ __launch_bounds__(1024, 4) void k_gibbs(const float* __restrict__ beta0g,
                                                   const float* __restrict__ betag,
                                                   const int* __restrict__ yg,
                                                   const float* __restrict__ alpha0,
                                                   const uint16_t* __restrict__ lpib,
                                                   float* __restrict__ out) {
  __shared__ __attribute__((aligned(16))) char SM[79584];
  uint16_t* bsb = (uint16_t*)SM;            // phase A: beta bf16 [112][128] (28672 B, in tab region)
  __half* tab = (__half*)SM;                // phase B: ep2 @0, em2 @TOFF (65600 B)
  float* elpi = (float*)(SM + 65600);       // [8][ELS] (4224 B); aliased by red in final phase
  float* lpil = (float*)(SM + 69824);       // [8][128] (4096 B)
  uint32_t* zsl = (uint32_t*)(SM + 73920);  // [256][4] (4096 B)
  float* lsel = (float*)(SM + 78016);       // [256]    (1024 B)
  int* yl = (int*)(SM + 79040);             // [8]
  float* b0p = (float*)(SM + 79072);        // [128] permuted beta0
  float* red = (float*)(SM + 65600);        // [1024] final-phase alias of elpi

  const int t = threadIdx.x;
  const int n0 = blockIdx.x * 8;
  const int L = t & 63;

  // ---- phase A: stage beta bf16 (clamped rows), permuted beta0, lpi sums ----
  for (int idx = t; idx < 112 * 32; idx += 1024) {
    int row = idx >> 5, c4 = (idx & 31) * 4;
    int rr = (row < Cc) ? row : 0;           // clamp: rows >=100 are discarded downstream
    float4 v = *(const float4*)&betag[rr * Mm + c4];
    uint2 o;
    o.x = f2bf(v.x) | (f2bf(v.y) << 16);
    o.y = f2bf(v.z) | (f2bf(v.w) << 16);
    *(uint2*)&bsb[row * 128 + c4] = o;
  }
  if (t < 128) b0p[cperm(t)] = (t < Cc) ? beta0g[t] : 0.0f;
  {
    int nls = t >> 7, j = t & 127;
    int g = (n0 + nls) * Mm + j;
    float lv = bf2f(lpib[g]) + bf2f(lpib[NM + g]) + bf2f(lpib[2 * NM + g]) +
               bf2f(lpib[3 * NM + g]) + alpha0[j];
    lpil[nls * Mm + j] = lv;
    elpi[nls * ELS + j] = __expf(lv);
  }
  if (t < 8) yl[t] = yg[n0 + t];
  __syncthreads();

  // quad mapping: chain cl = t>>2, slice hq = t&3
  const int cl = t >> 2;
  const int hq = t & 3;
  const int nl = cl >> 5;                 // wave-uniform (16 chains/wave, 32-aligned)
  const int s = cl & 31;
  const uint32_t chain = (uint32_t)((n0 + nl) * Ss + s);
  const int yv = yl[nl];

  // ---- Z0: lane draws word hq of chain cl (bank-staggered elpi reads) ----
  uint32_t zz = 0;
  {
    #pragma unroll 1
    for (int b5 = 0; b5 < 32; ++b5) {
      int mloc = (b5 + hq * 8) & 31;
      int m = hq * 32 + mloc;
      float u = urand(chain, (uint32_t)m);
      float el = elpi[nl * ELS + m];
      zz |= (u * (1.0f + el) < el) ? (1u << mloc) : 0u;
    }
  }

  // ---- init lin = Z0 . beta via MFMA (MFMA-layout roles: chain=L&15, slice=L>>4) ----
  f32x4 acc[7];
  #pragma unroll
  for (int T = 0; T < 7; ++T) acc[T] = (f32x4){0.f, 0.f, 0.f, 0.f};
  #pragma unroll
  for (int ks = 0; ks < 4; ++ks) {
    uint32_t zw = (uint32_t)__shfl((int)zz, ((L & 15) << 2) | ks, 64);
    uint32_t bits8 = (zw >> ((L >> 4) * 8)) & 0xFFu;
    uint4 pk;
    {
      uint32_t p0 = ((bits8 >> 0) & 1u) ? 0x3F80u : 0xBF80u;
      uint32_t p1 = ((bits8 >> 1) & 1u) ? 0x3F80u : 0xBF80u;
      uint32_t p2 = ((bits8 >> 2) & 1u) ? 0x3F80u : 0xBF80u;
      uint32_t p3 = ((bits8 >> 3) & 1u) ? 0x3F80u : 0xBF80u;
      uint32_t p4 = ((bits8 >> 4) & 1u) ? 0x3F80u : 0xBF80u;
      uint32_t p5 = ((bits8 >> 5) & 1u) ? 0x3F80u : 0xBF80u;
      uint32_t p6 = ((bits8 >> 6) & 1u) ? 0x3F80u : 0xBF80u;
      uint32_t p7 = ((bits8 >> 7) & 1u) ? 0x3F80u : 0xBF80u;
      pk.x = p0 | (p1 << 16); pk.y = p2 | (p3 << 16);
      pk.z = p4 | (p5 << 16); pk.w = p6 | (p7 << 16);
    }
    bf8 B = __builtin_bit_cast(bf8, pk);
    #pragma unroll
    for (int T = 0; T < 7; ++T) {
      bf8 A = __builtin_bit_cast(bf8, *(const uint4*)&bsb[(T * 16 + (L & 15)) * 128 + ks * 32 + (L >> 4) * 8]);
      acc[T] = __builtin_amdgcn_mfma_f32_16x16x32_bf16(A, B, acc[T], 0, 0, 0);
    }
  }

  // ---- E = exp(lin + beta0)*2^-6 packed f16 (MFMA layout: window = L>>4) ----
  const __half2 HZERO = __builtin_bit_cast(__half2, 0u);
  __half2 E2[16];
  {
    int c0m = (L >> 4) * 32;
    #pragma unroll
    for (int k = 0; k < 14; ++k) {
      float2 b0v = *(const float2*)&b0p[c0m + 2 * k];
      float ea = __expf(acc[(2 * k) >> 2][(2 * k) & 3] + b0v.x) * ESC;
      float eb = __expf(acc[(2 * k + 1) >> 2][(2 * k + 1) & 3] + b0v.y) * ESC;
      E2[k] = __floats2half2_rn(ea, eb);
    }
    E2[14] = HZERO; E2[15] = HZERO;
    if ((L >> 4) != 0) { E2[12] = HZERO; E2[13] = HZERO; }  // classes >=100
  }

  // ---- one-time shuffle to quad layout: lane 4i+h gets window h of chain i ----
  {
    int src = (L >> 2) | ((L & 3) << 4);
    #pragma unroll
    for (int k = 0; k < 14; ++k)
      E2[k] = __builtin_bit_cast(__half2, (uint32_t)__shfl((int)__builtin_bit_cast(uint32_t, E2[k]), src, 64));
  }
  uint32_t zw0 = (uint32_t)__shfl((int)zz, (L & ~3) | 0, 64);
  uint32_t zw1 = (uint32_t)__shfl((int)zz, (L & ~3) | 1, 64);
  uint32_t zw2 = (uint32_t)__shfl((int)zz, (L & ~3) | 2, 64);
  uint32_t zw3 = (uint32_t)__shfl((int)zz, (L & ~3) | 3, 64);

  const h2f one2 = {(_Float16)1.0f, (_Float16)1.0f};
  float Sb;
  {
    float d0 = 0.f, d1 = 0.f;
    #pragma unroll
    for (int k = 0; k < 16; ++k) {
      if (k & 1) d1 = dot2f(__builtin_bit_cast(h2f, E2[k]), one2, d1);
      else d0 = dot2f(__builtin_bit_cast(h2f, E2[k]), one2, d0);
    }
    Sb = qsum4(d0 + d1);
  }

  // ---- phase B: rebuild LDS as f16 tables, permuted+chunk-rotated positions ----
  __syncthreads();
  for (int idx = t; idx < 32 * Cc; idx += 1024) {
    int j4 = idx / Cc;
    int c = idx - j4 * Cc;
    int ps = swz(cperm(c));
    float4 bv = *(const float4*)&betag[c * Mm + j4 * 4];
    int j = j4 * 4;
    tab[(j + 0) * SCP + ps] = __float2half(__expf(2.0f * bv.x));
    tab[TOFF + (j + 0) * SCP + ps] = __float2half(__expf(-2.0f * bv.x));
    tab[(j + 1) * SCP + ps] = __float2half(__expf(2.0f * bv.y));
    tab[TOFF + (j + 1) * SCP + ps] = __float2half(__expf(-2.0f * bv.y));
    tab[(j + 2) * SCP + ps] = __float2half(__expf(2.0f * bv.z));
    tab[TOFF + (j + 2) * SCP + ps] = __float2half(__expf(-2.0f * bv.z));
    tab[(j + 3) * SCP + ps] = __float2half(__expf(2.0f * bv.w));
    tab[TOFF + (j + 3) * SCP + ps] = __float2half(__expf(-2.0f * bv.w));
  }
  for (int idx = t; idx < Mm * 28; idx += 1024) {
    int j = idx / 28;
    int c = Cc + (idx - j * 28);
    int ps = swz(cperm(c));
    tab[j * SCP + ps] = __float2half(1.0f);
    tab[TOFF + j * SCP + ps] = __float2half(1.0f);
  }
  __syncthreads();

  // ---- Gibbs sweep: ping-pong prefetch, quad-DPP reduce, conflict-free reads ----
  const int pyv_s = swz(cperm(yv));
  const int rot0 = ((0 + hq) & 3) * 8;
  const int rot1 = ((1 + hq) & 3) * 8;
  const int rot2 = ((2 + hq) & 3) * 8;
  const int rot3 = ((3 + hq) & 3) * 8;

  uint4 va[4], vb[4];
  auto pf = [&](uint4 (&dst)[4], uint32_t bit, int j) {
    const __half* p = tab + (bit ? TOFF : 0) + j * SCP + hq * 32;
    dst[0] = *(const uint4*)(p + rot0);
    dst[1] = *(const uint4*)(p + rot1);
    dst[2] = *(const uint4*)(p + rot2);
    dst[3] = *(const uint4*)(p + rot3);
  };
  auto step = [&](uint4 (&v)[4], uint32_t zjp, float eyel, float u) -> uint32_t {
    float d0 = 0.f, d1 = 0.f, d2 = 0.f, d3 = 0.f;
    #pragma unroll
    for (int k = 0; k < 4; ++k) {
      d0 = dot2f(__builtin_bit_cast(h2f, E2[4 * k + 0]), __builtin_bit_cast(h2f, v[k].x), d0);
      d1 = dot2f(__builtin_bit_cast(h2f, E2[4 * k + 1]), __builtin_bit_cast(h2f, v[k].y), d1);
      d2 = dot2f(__builtin_bit_cast(h2f, E2[4 * k + 2]), __builtin_bit_cast(h2f, v[k].z), d2);
      d3 = dot2f(__builtin_bit_cast(h2f, E2[4 * k + 3]), __builtin_bit_cast(h2f, v[k].w), d3);
    }
    float D = qsum4((d0 + d1) + (d2 + d3));
    float Spos = zjp ? Sb : D;
    float Sneg = zjp ? D : Sb;
    float odds = eyel * Sneg * __builtin_amdgcn_rcpf(Spos);
    uint32_t znp = (u * (1.0f + odds) < odds) ? 1u : 0u;
    if ((znp ^ zjp) != 0u) {
      #pragma unroll
      for (int k = 0; k < 4; ++k) {
        E2[4 * k + 0] = __hmul2(E2[4 * k + 0], __builtin_bit_cast(__half2, v[k].x));
        E2[4 * k + 1] = __hmul2(E2[4 * k + 1], __builtin_bit_cast(__half2, v[k].y));
        E2[4 * k + 2] = __hmul2(E2[4 * k + 2], __builtin_bit_cast(__half2, v[k].z));
        E2[4 * k + 3] = __hmul2(E2[4 * k + 3], __builtin_bit_cast(__half2, v[k].w));
      }
      Sb = D;
    }
    return znp;
  };

  pf(va, zw0 & 1u, 0);   // prologue

  #pragma unroll 1
  for (int jb = 0; jb < Mm; jb += 4) {
    int w = jb >> 5;
    uint32_t zwv = (w == 0) ? zw0 : ((w == 1) ? zw1 : ((w == 2) ? zw2 : zw3));
    const int sh = jb & 31;
    uint32_t b0 = (zwv >> (sh + 0)) & 1u;
    uint32_t b1 = (zwv >> (sh + 1)) & 1u;
    uint32_t b2 = (zwv >> (sh + 2)) & 1u;
    uint32_t b3 = (zwv >> (sh + 3)) & 1u;
    uint32_t b4;
    if (sh == 28) {
      uint32_t nw = (w == 0) ? zw1 : ((w == 1) ? zw2 : ((w == 2) ? zw3 : 0u));
      b4 = nw & 1u;
    } else {
      b4 = (zwv >> (sh + 4)) & 1u;
    }
    float4 elv = *(const float4*)&elpi[nl * ELS + jb];
    float eyel0 = __half2float(tab[(jb + 0) * SCP + pyv_s]) * elv.x;
    float eyel1 = __half2float(tab[(jb + 1) * SCP + pyv_s]) * elv.y;
    float eyel2 = __half2float(tab[(jb + 2) * SCP + pyv_s]) * elv.z;
    float eyel3 = __half2float(tab[(jb + 3) * SCP + pyv_s]) * elv.w;
    uint32_t h1 = hash32(chain, 256u + (uint32_t)jb);
    uint32_t h2 = hash32(chain, 258u + (uint32_t)jb);
    float u0 = (float)(h1 & 0xFFFFu) * (1.0f / 65536.0f);
    float u1 = (float)(h1 >> 16) * (1.0f / 65536.0f);
    float u2 = (float)(h2 & 0xFFFFu) * (1.0f / 65536.0f);
    float u3 = (float)(h2 >> 16) * (1.0f / 65536.0f);

    pf(vb, b1, jb + 1);
    b0 = step(va, b0, eyel0, u0);
    pf(va, b2, jb + 2);
    b1 = step(vb, b1, eyel1, u1);
    pf(vb, b3, jb + 3);
    b2 = step(va, b2, eyel2, u2);
    pf(va, b4, (jb + 4) & 127);
    b3 = step(vb, b3, eyel3, u3);

    uint32_t nib = b0 | (b1 << 1) | (b2 << 2) | (b3 << 3);
    zwv = (zwv & ~(0xFu << sh)) | (nib << sh);
    if (w == 0) zw0 = zwv; else if (w == 1) zw1 = zwv;
    else if (w == 2) zw2 = zwv; else zw3 = zwv;
  }

  // ---- outputs to LDS ----
  float Sf;
  {
    float d0 = 0.f, d1 = 0.f;
    #pragma unroll
    for (int k = 0; k < 16; ++k) {
      if (k & 1) d1 = dot2f(__builtin_bit_cast(h2f, E2[k]), one2, d1);
      else d0 = dot2f(__builtin_bit_cast(h2f, E2[k]), one2, d0);
    }
    Sf = qsum4(d0 + d1);
  }
  if (hq == 0) {
    lsel[cl] = __logf(Sf) + ESCLOG;
    zsl[cl * 4 + 0] = zw0; zsl[cl * 4 + 1] = zw1;
    zsl[cl * 4 + 2] = zw2; zsl[cl * 4 + 3] = zw3;
  }
  __syncthreads();

  // ---- fused final: moments + all four terms for this block's 8 n-rows ----
  {
    int nl2 = t >> 7;       // 0..7
    int mp = t & 127;       // m
    int wsel = mp >> 5, sh0 = mp & 31;
    int cnt = 0;
    #pragma unroll 1
    for (int s2 = 0; s2 < 32; ++s2)
      cnt += (int)((zsl[(nl2 * 32 + s2) * 4 + wsel] >> sh0) & 1u);
    float EI = (float)cnt * (1.0f / 32.0f);
    float EII = 2.0f * EI - 1.0f;
    float l = lpil[nl2 * Mm + mp];
    int yv2 = yl[nl2];
    float bb = betag[yv2 * Mm + mp];
    float sp = (l > 20.0f) ? l : __logf(1.0f + __expf(l));
    float term = EII * bb + EI * l - sp;
    if (t < 256) term -= lsel[t] * (1.0f / 32.0f);
    if (t < 8) term += beta0g[yl[t]];
    red[t] = term;
  }
  __syncthreads();
  for (int off = 512; off > 0; off >>= 1) {
    if (t < off) red[t] += red[t + off];
    __syncthreads();
  }
  if (t == 0) atomicAdd(out, red[0]);
}

extern "C" void kernel_launch(void* const* d_in, const int* in_sizes, int n_in,
                              void* d_out, int out_size, void* d_ws, size_t ws_size,
                              hipStream_t stream) {
  const float* x = (const float*)d_in[0];
  const int* y = (const int*)d_in[1];
  const float* alpha0 = (const float*)d_in[2];
  const float* alpha = (const float*)d_in[3];
  const float* beta0 = (const float*)d_in[4];
  const float* beta = (const float*)d_in[5];
  float* out = (float*)d_out;

  uint16_t* lpib = (uint16_t*)d_ws;   // 4 bf16 split-K planes = 2 MB

  hipMemsetAsync(d_out, 0, sizeof(float), stream);
  k_lingemm<<<256, 256, 0, stream>>>(x, alpha, lpib);
  k_gibbs<<<256, 1024, 0, stream>>>(beta0, beta, y, alpha0, lpib, out);
}

// Round 10
// 96.811 us; speedup vs baseline: 6.6834x; 1.0654x over previous
//
#include <hip/hip_runtime.h>
#include <hip/hip_fp16.h>
#include <stdint.h>

#define Nn 2048
#define Ff 1024
#define Mm 128
#define Cc 100
#define Ss 32
#define NM (Nn * Mm)
#define ELS 132
#define SCP 128          // table row stride in halfs
#define TOFF 16416       // em2 offset in halfs (byte 32832 == 64 mod 128 -> +4 bank-quad phase)
#define ESC 0.015625f          // 2^-6 scale on E
#define ESCLOG 4.15888308336f  // 6*ln2

typedef _Float16 h2f __attribute__((ext_vector_type(2)));
typedef short bf8 __attribute__((ext_vector_type(8)));
typedef float f32x4 __attribute__((ext_vector_type(4)));

__device__ __forceinline__ float qsum4(float x) {
  int a = __builtin_amdgcn_update_dpp(0, __builtin_bit_cast(int, x), 0xB1, 0xF, 0xF, false);
  float xf = x + __builtin_bit_cast(float, a);
  int b = __builtin_amdgcn_update_dpp(0, __builtin_bit_cast(int, xf), 0x4E, 0xF, 0xF, false);
  return xf + __builtin_bit_cast(float, b);
}

__device__ __forceinline__ float dot2f(h2f a, h2f b, float c) {
#if __has_builtin(__builtin_amdgcn_fdot2)
  return __builtin_amdgcn_fdot2(a, b, c, false);
#else
  return fmaf((float)a[0], (float)b[0], fmaf((float)a[1], (float)b[1], c));
#endif
}
__device__ __forceinline__ float d2(__half2 e, uint32_t v, float c) {
  return dot2f(__builtin_bit_cast(h2f, e), __builtin_bit_cast(h2f, v), c);
}
__device__ __forceinline__ __half2 m2(__half2 e, uint32_t v) {
  return __hmul2(e, __builtin_bit_cast(__half2, v));
}

__device__ __forceinline__ uint32_t hash32(uint32_t chain, uint32_t ctr) {
  uint32_t h = chain * 0x9E3779B9u ^ (ctr * 0x85EBCA6Bu);
  h ^= h >> 16; h *= 0x7FEB352Du;
  h ^= h >> 15; h *= 0x846CA68Bu;
  h ^= h >> 16;
  return h;
}
__device__ __forceinline__ float urand(uint32_t chain, uint32_t ctr) {
  return (float)(hash32(chain, ctr) >> 8) * (1.0f / 16777216.0f);
}
__device__ __forceinline__ uint32_t f2bf(float f) {
  uint32_t b = __builtin_bit_cast(uint32_t, f);
  return (b + 0x7FFFu + ((b >> 16) & 1u)) >> 16;
}
__device__ __forceinline__ float bf2f(uint16_t u) {
  uint32_t b = ((uint32_t)u) << 16;
  return __builtin_bit_cast(float, b);
}
// class -> permuted position: window h=(c>>2)&3 holds contiguous slice [h*32, h*32+32)
__device__ __forceinline__ int cperm(int c) {
  return ((c >> 2) & 3) * 32 + (c >> 4) * 4 + (c & 3);
}
// chunk rotation within window: logical 16B chunk k of window w stored at chunk (k+w)&3
__device__ __forceinline__ int swz(int p) {
  int win = p >> 5, o = p & 31;
  return win * 32 + (((o >> 3) + win) & 3) * 8 + (o & 7);
}

// ------------- Kernel A: lpib[ks] = bf16 partial of x @ alpha^T (split-K x4, MFMA) -------------
__global__ __launch_bounds__(256) void k_lingemm(const float* __restrict__ x,
                                                 const float* __restrict__ alpha,
                                                 uint16_t* __restrict__ lpib) {
  __shared__ uint4 sA[256];
  __shared__ uint4 sB[1024];
  const int t = threadIdx.x;
  const int mt = blockIdx.x >> 2;
  const int ks = blockIdx.x & 3;
  const int m0 = mt * 32;
  const int w = t >> 6;
  const int l = t & 63;

  f32x4 acc[2][2] = {{{0.f, 0.f, 0.f, 0.f}, {0.f, 0.f, 0.f, 0.f}},
                     {{0.f, 0.f, 0.f, 0.f}, {0.f, 0.f, 0.f, 0.f}}};

  for (int kk = 0; kk < 4; ++kk) {
    const int k0 = ks * 256 + kk * 64;
    __syncthreads();
    {
      int row = t >> 3, c = t & 7;
      const float* px = &x[(m0 + row) * Ff + k0 + c * 8];
      float4 f0 = *(const float4*)px;
      float4 f1 = *(const float4*)(px + 4);
      uint4 v;
      v.x = f2bf(f0.x) | (f2bf(f0.y) << 16);
      v.y = f2bf(f0.z) | (f2bf(f0.w) << 16);
      v.z = f2bf(f1.x) | (f2bf(f1.y) << 16);
      v.w = f2bf(f1.z) | (f2bf(f1.w) << 16);
      sA[row * 8 + (c ^ (row & 7))] = v;
      #pragma unroll
      for (int rr = 0; rr < 4; ++rr) {
        int idx = t + rr * 256;
        int rowb = idx >> 3, cb = idx & 7;
        const float* pa = &alpha[rowb * Ff + k0 + cb * 8];
        float4 g0 = *(const float4*)pa;
        float4 g1 = *(const float4*)(pa + 4);
        uint4 vb;
        vb.x = f2bf(g0.x) | (f2bf(g0.y) << 16);
        vb.y = f2bf(g0.z) | (f2bf(g0.w) << 16);
        vb.z = f2bf(g1.x) | (f2bf(g1.y) << 16);
        vb.w = f2bf(g1.z) | (f2bf(g1.w) << 16);
        sB[rowb * 8 + (cb ^ (rowb & 7))] = vb;
      }
    }
    __syncthreads();
    #pragma unroll
    for (int kc = 0; kc < 2; ++kc) {
      int chunk = kc * 4 + (l >> 4);
      bf8 av[2], bv[2];
      #pragma unroll
      for (int fm = 0; fm < 2; ++fm) {
        int row = fm * 16 + (l & 15);
        av[fm] = __builtin_bit_cast(bf8, sA[row * 8 + (chunk ^ (row & 7))]);
      }
      #pragma unroll
      for (int fn = 0; fn < 2; ++fn) {
        int rowb = w * 32 + fn * 16 + (l & 15);
        bv[fn] = __builtin_bit_cast(bf8, sB[rowb * 8 + (chunk ^ (rowb & 7))]);
      }
      #pragma unroll
      for (int fm = 0; fm < 2; ++fm)
        #pragma unroll
        for (int fn = 0; fn < 2; ++fn)
          acc[fm][fn] = __builtin_amdgcn_mfma_f32_16x16x32_bf16(av[fm], bv[fn], acc[fm][fn], 0, 0, 0);
    }
  }
  #pragma unroll
  for (int fm = 0; fm < 2; ++fm)
    #pragma unroll
    for (int fn = 0; fn < 2; ++fn)
      #pragma unroll
      for (int r = 0; r < 4; ++r) {
        int row = m0 + fm * 16 + (l >> 4) * 4 + r;
        int col = w * 32 + fn * 16 + (l & 15);
        lpib[ks * NM + row * Mm + col] = (uint16_t)f2bf(acc[fm][fn][r]);
      }
}

// macro: prefetch table slices for step j into named regs B0..B3 (B3 is uint2)
#define PF(B0, B1, B2, B3, bit, j) {                                          \
    const __half* p_ = tab + ((bit) ? TOFF : 0) + (j) * SCP + hq * 32;        \
    B0 = *(const uint4*)(p_ + rot0);                                          \
    B1 = *(const uint4*)(p_ + rot1);                                          \
    B2 = *(const uint4*)(p_ + rot2);                                          \
    B3 = *(const uint2*)(p_ + rot3); }

// macro: one Gibbs step on named regs (E2_0..E2_13, Sb updated in place)
#define STEP(B0, B1, B2, B3, zjp, eyel, u, bout) {                            \
    float d0_ = d2(E2_0, B0.x, 0.f), d1_ = d2(E2_1, B0.y, 0.f);               \
    float d2_ = d2(E2_2, B0.z, 0.f), d3_ = d2(E2_3, B0.w, 0.f);               \
    d0_ = d2(E2_4, B1.x, d0_); d1_ = d2(E2_5, B1.y, d1_);                     \
    d2_ = d2(E2_6, B1.z, d2_); d3_ = d2(E2_7, B1.w, d3_);                     \
    d0_ = d2(E2_8, B2.x, d0_); d1_ = d2(E2_9, B2.y, d1_);                     \
    d2_ = d2(E2_10, B2.z, d2_); d3_ = d2(E2_11, B2.w, d3_);                   \
    d0_ = d2(E2_12, B3.x, d0_); d1_ = d2(E2_13, B3.y, d1_);                   \
    float D_ = qsum4((d0_ + d1_) + (d2_ + d3_));                              \
    float Sp_ = (zjp) ? Sb : D_;                                              \
    float Sn_ = (zjp) ? D_ : Sb;                                              \
    float odds_ = (eyel) * Sn_ * __builtin_amdgcn_rcpf(Sp_);                  \
    uint32_t znp_ = ((u) * (1.0f + odds_) < odds_) ? 1u : 0u;                 \
    if ((znp_ ^ (zjp)) != 0u) {                                               \
      E2_0 = m2(E2_0, B0.x); E2_1 = m2(E2_1, B0.y);                           \
      E2_2 = m2(E2_2, B0.z); E2_3 = m2(E2_3, B0.w);                           \
      E2_4 = m2(E2_4, B1.x); E2_5 = m2(E2_5, B1.y);                           \
      E2_6 = m2(E2_6, B1.z); E2_7 = m2(E2_7, B1.w);                           \
      E2_8 = m2(E2_8, B2.x); E2_9 = m2(E2_9, B2.y);                           \
      E2_10 = m2(E2_10, B2.z); E2_11 = m2(E2_11, B2.w);                       \
      E2_12 = m2(E2_12, B3.x); E2_13 = m2(E2_13, B3.y);                       \
      Sb = D_;                                                                \
    }                                                                         \
    bout = znp_; }

#define MKE(k)                                                                \
  {                                                                           \
    float2 b0v = *(const float2*)&b0p[c0m + 2 * (k)];                         \
    float ea_ = __expf(acc[(2 * (k)) >> 2][(2 * (k)) & 3] + b0v.x) * ESC;     \
    float eb_ = __expf(acc[(2 * (k) + 1) >> 2][(2 * (k) + 1) & 3] + b0v.y) * ESC; \
    E2_##k = __floats2half2_rn(ea_, eb_);                                     \
  }

#define SHF(k) E2_##k = __builtin_bit_cast(__half2,                           \
    (uint32_t)__shfl((int)__builtin_bit_cast(uint32_t, E2_##k), src, 64));

// ------------- Kernel B: fused init(MFMA) + named-reg Gibbs sweep + final reduction -------------
// 256 blocks x 1024 threads: 8 n-rows, 256 chains/block, 4 lanes/chain (lane-quads).
__global__ __launch_bounds__(1024, 4) void k_gibbs(const float* __restrict__ beta0g,
                                                   const float* __restrict__ betag,
                                                   const int* __restrict__ yg,
                                                   const float* __restrict__ alpha0,
                                                   const uint16_t* __restrict__ lpib,
                                                   float* __restrict__ out) {
  __shared__ __attribute__((aligned(16))) char SM[79584];
  uint16_t* bsb = (uint16_t*)SM;            // phase A: beta bf16 [112][128] swizzled (28672 B)
  __half* tab = (__half*)SM;                // phase B: ep2 @0, em2 @TOFF (65664 B)
  float* elpi = (float*)(SM + 65600);       // [8][ELS]; aliased by red in final phase
  float* lpil = (float*)(SM + 69824);       // [8][128]
  uint32_t* zsl = (uint32_t*)(SM + 73920);  // [256][4]
  float* lsel = (float*)(SM + 78016);       // [256]
  int* yl = (int*)(SM + 79040);             // [8]
  float* b0p = (float*)(SM + 79072);        // [128] permuted beta0
  float* red = (float*)(SM + 65600);        // [1024] final-phase alias

  const int t = threadIdx.x;
  const int n0 = blockIdx.x * 8;
  const int L = t & 63;

  // ---- phase A: stage beta bf16 (row-swizzled 16B chunks), permuted beta0, lpi sums ----
  for (int idx = t; idx < 112 * 32; idx += 1024) {
    int row = idx >> 5, u = idx & 31;
    int rr = (row < Cc) ? row : 0;
    float4 v = *(const float4*)&betag[rr * Mm + u * 4];
    uint2 o;
    o.x = f2bf(v.x) | (f2bf(v.y) << 16);
    o.y = f2bf(v.z) | (f2bf(v.w) << 16);
    int k = u >> 1, sub = u & 1;
    int kp = k ^ (row & 15);
    *(uint2*)&bsb[row * 128 + kp * 8 + sub * 4] = o;
  }
  if (t < 128) b0p[cperm(t)] = (t < Cc) ? beta0g[t] : 0.0f;
  {
    int nls = t >> 7, j = t & 127;
    int g = (n0 + nls) * Mm + j;
    float lv = bf2f(lpib[g]) + bf2f(lpib[NM + g]) + bf2f(lpib[2 * NM + g]) +
               bf2f(lpib[3 * NM + g]) + alpha0[j];
    lpil[nls * Mm + j] = lv;
    elpi[nls * ELS + j] = __expf(lv);
  }
  if (t < 8) yl[t] = yg[n0 + t];
  __syncthreads();

  // quad mapping: chain cl = t>>2, slice hq = t&3
  const int cl = t >> 2;
  const int hq = t & 3;
  const int nl = cl >> 5;                 // wave-uniform
  const int s = cl & 31;
  const uint32_t chain = (uint32_t)((n0 + nl) * Ss + s);
  const int yv = yl[nl];

  // ---- Z0: lane draws word hq of chain cl ----
  uint32_t zz = 0;
  {
    #pragma unroll 1
    for (int b5 = 0; b5 < 32; ++b5) {
      int mloc = (b5 + hq * 8) & 31;
      int m = hq * 32 + mloc;
      float u = urand(chain, (uint32_t)m);
      float el = elpi[nl * ELS + m];
      zz |= (u * (1.0f + el) < el) ? (1u << mloc) : 0u;
    }
  }

  // ---- init lin = Z0 . beta via MFMA (MFMA roles: chain = L&15, window hw = L>>4) ----
  f32x4 acc[7];
  #pragma unroll
  for (int T = 0; T < 7; ++T) acc[T] = (f32x4){0.f, 0.f, 0.f, 0.f};
  {
    const int liw = L & 15, hw = L >> 4;
    #pragma unroll
    for (int ks = 0; ks < 4; ++ks) {
      uint32_t zw = (uint32_t)__shfl((int)zz, (liw << 2) | ks, 64);
      uint32_t bits8 = (zw >> (hw * 8)) & 0xFFu;
      uint4 pk;
      {
        uint32_t p0 = ((bits8 >> 0) & 1u) ? 0x3F80u : 0xBF80u;
        uint32_t p1 = ((bits8 >> 1) & 1u) ? 0x3F80u : 0xBF80u;
        uint32_t p2 = ((bits8 >> 2) & 1u) ? 0x3F80u : 0xBF80u;
        uint32_t p3 = ((bits8 >> 3) & 1u) ? 0x3F80u : 0xBF80u;
        uint32_t p4 = ((bits8 >> 4) & 1u) ? 0x3F80u : 0xBF80u;
        uint32_t p5 = ((bits8 >> 5) & 1u) ? 0x3F80u : 0xBF80u;
        uint32_t p6 = ((bits8 >> 6) & 1u) ? 0x3F80u : 0xBF80u;
        uint32_t p7 = ((bits8 >> 7) & 1u) ? 0x3F80u : 0xBF80u;
        pk.x = p0 | (p1 << 16); pk.y = p2 | (p3 << 16);
        pk.z = p4 | (p5 << 16); pk.w = p6 | (p7 << 16);
      }
      bf8 B = __builtin_bit_cast(bf8, pk);
      #pragma unroll
      for (int T = 0; T < 7; ++T) {
        int row = T * 16 + liw;
        int kk = ks * 4 + hw;
        bf8 A = __builtin_bit_cast(bf8, *(const uint4*)&bsb[row * 128 + (kk ^ (row & 15)) * 8]);
        acc[T] = __builtin_amdgcn_mfma_f32_16x16x32_bf16(A, B, acc[T], 0, 0, 0);
      }
    }
  }

  // ---- E = exp(lin + beta0)*2^-6 packed f16 (MFMA layout), then quad shuffle ----
  const __half2 HZERO = __builtin_bit_cast(__half2, 0u);
  __half2 E2_0, E2_1, E2_2, E2_3, E2_4, E2_5, E2_6, E2_7;
  __half2 E2_8, E2_9, E2_10, E2_11, E2_12, E2_13;
  {
    int c0m = (L >> 4) * 32;
    MKE(0) MKE(1) MKE(2) MKE(3) MKE(4) MKE(5) MKE(6)
    MKE(7) MKE(8) MKE(9) MKE(10) MKE(11) MKE(12) MKE(13)
    if ((L >> 4) != 0) { E2_12 = HZERO; E2_13 = HZERO; }  // classes >= 100
  }
  {
    int src = (L >> 2) | ((L & 3) << 4);
    SHF(0) SHF(1) SHF(2) SHF(3) SHF(4) SHF(5) SHF(6)
    SHF(7) SHF(8) SHF(9) SHF(10) SHF(11) SHF(12) SHF(13)
  }
  uint32_t zw0 = (uint32_t)__shfl((int)zz, (L & ~3) | 0, 64);
  uint32_t zw1 = (uint32_t)__shfl((int)zz, (L & ~3) | 1, 64);
  uint32_t zw2 = (uint32_t)__shfl((int)zz, (L & ~3) | 2, 64);
  uint32_t zw3 = (uint32_t)__shfl((int)zz, (L & ~3) | 3, 64);

  const uint32_t ONE2 = 0x3C003C00u;   // (1.0h, 1.0h)
  float Sb;
  {
    float d0_ = d2(E2_0, ONE2, 0.f), d1_ = d2(E2_1, ONE2, 0.f);
    float d2_ = d2(E2_2, ONE2, 0.f), d3_ = d2(E2_3, ONE2, 0.f);
    d0_ = d2(E2_4, ONE2, d0_); d1_ = d2(E2_5, ONE2, d1_);
    d2_ = d2(E2_6, ONE2, d2_); d3_ = d2(E2_7, ONE2, d3_);
    d0_ = d2(E2_8, ONE2, d0_); d1_ = d2(E2_9, ONE2, d1_);
    d2_ = d2(E2_10, ONE2, d2_); d3_ = d2(E2_11, ONE2, d3_);
    d0_ = d2(E2_12, ONE2, d0_); d1_ = d2(E2_13, ONE2, d1_);
    Sb = qsum4((d0_ + d1_) + (d2_ + d3_));
  }

  // ---- phase B: rebuild LDS as f16 tables, permuted+chunk-rotated positions ----
  __syncthreads();
  for (int idx = t; idx < 32 * Cc; idx += 1024) {
    int j4 = idx / Cc;
    int c = idx - j4 * Cc;
    int ps = swz(cperm(c));
    float4 bv = *(const float4*)&betag[c * Mm + j4 * 4];
    int j = j4 * 4;
    tab[(j + 0) * SCP + ps] = __float2half(__expf(2.0f * bv.x));
    tab[TOFF + (j + 0) * SCP + ps] = __float2half(__expf(-2.0f * bv.x));
    tab[(j + 1) * SCP + ps] = __float2half(__expf(2.0f * bv.y));
    tab[TOFF + (j + 1) * SCP + ps] = __float2half(__expf(-2.0f * bv.y));
    tab[(j + 2) * SCP + ps] = __float2half(__expf(2.0f * bv.z));
    tab[TOFF + (j + 2) * SCP + ps] = __float2half(__expf(-2.0f * bv.z));
    tab[(j + 3) * SCP + ps] = __float2half(__expf(2.0f * bv.w));
    tab[TOFF + (j + 3) * SCP + ps] = __float2half(__expf(-2.0f * bv.w));
  }
  // pad classes 100..111 AND unreachable positions 28..31 of each window -> 1.0
  for (int idx = t; idx < Mm * 28; idx += 1024) {
    int j = idx / 28;
    int c = Cc + (idx - j * 28);
    int ps = swz(cperm(c));
    tab[j * SCP + ps] = __float2half(1.0f);
    tab[TOFF + j * SCP + ps] = __float2half(1.0f);
  }
  for (int idx = t; idx < Mm * 16; idx += 1024) {
    int j = idx >> 4;
    int win = (idx >> 2) & 3, o = 28 + (idx & 3);
    int ps = win * 32 + (((o >> 3) + win) & 3) * 8 + (o & 7);
    tab[j * SCP + ps] = __float2half(1.0f);
    tab[TOFF + j * SCP + ps] = __float2half(1.0f);
  }
  __syncthreads();

  // ---- Gibbs sweep: named-reg ping-pong prefetch, quad-DPP reduce ----
  const int pyv_s = swz(cperm(yv));
  const int rot0 = ((0 + hq) & 3) * 8;
  const int rot1 = ((1 + hq) & 3) * 8;
  const int rot2 = ((2 + hq) & 3) * 8;
  const int rot3 = ((3 + hq) & 3) * 8;

  uint4 va0, va1, va2, vb0, vb1, vb2;
  uint2 va3, vb3;

  PF(va0, va1, va2, va3, zw0 & 1u, 0)   // prologue

  #pragma unroll 1
  for (int jb = 0; jb < Mm; jb += 4) {
    int w = jb >> 5;
    uint32_t zwv = (w == 0) ? zw0 : ((w == 1) ? zw1 : ((w == 2) ? zw2 : zw3));
    const int sh = jb & 31;
    uint32_t b0 = (zwv >> (sh + 0)) & 1u;
    uint32_t b1 = (zwv >> (sh + 1)) & 1u;
    uint32_t b2 = (zwv >> (sh + 2)) & 1u;
    uint32_t b3 = (zwv >> (sh + 3)) & 1u;
    uint32_t b4;
    if (sh == 28) {
      uint32_t nw = (w == 0) ? zw1 : ((w == 1) ? zw2 : ((w == 2) ? zw3 : 0u));
      b4 = nw & 1u;
    } else {
      b4 = (zwv >> (sh + 4)) & 1u;
    }
    float4 elv = *(const float4*)&elpi[nl * ELS + jb];
    float eyel0 = __half2float(tab[(jb + 0) * SCP + pyv_s]) * elv.x;
    float eyel1 = __half2float(tab[(jb + 1) * SCP + pyv_s]) * elv.y;
    float eyel2 = __half2float(tab[(jb + 2) * SCP + pyv_s]) * elv.z;
    float eyel3 = __half2float(tab[(jb + 3) * SCP + pyv_s]) * elv.w;
    uint32_t h1 = hash32(chain, 256u + (uint32_t)jb);
    uint32_t h2 = hash32(chain, 258u + (uint32_t)jb);
    float u0 = (float)(h1 & 0xFFFFu) * (1.0f / 65536.0f);
    float u1 = (float)(h1 >> 16) * (1.0f / 65536.0f);
    float u2 = (float)(h2 & 0xFFFFu) * (1.0f / 65536.0f);
    float u3 = (float)(h2 >> 16) * (1.0f / 65536.0f);

    PF(vb0, vb1, vb2, vb3, b1, jb + 1)
    STEP(va0, va1, va2, va3, b0, eyel0, u0, b0)
    PF(va0, va1, va2, va3, b2, jb + 2)
    STEP(vb0, vb1, vb2, vb3, b1, eyel1, u1, b1)
    PF(vb0, vb1, vb2, vb3, b3, jb + 3)
    STEP(va0, va1, va2, va3, b2, eyel2, u2, b2)
    PF(va0, va1, va2, va3, b4, (jb + 4) & 127)
    STEP(vb0, vb1, vb2, vb3, b3, eyel3, u3, b3)

    uint32_t nib = b0 | (b1 << 1) | (b2 << 2) | (b3 << 3);
    zwv = (zwv & ~(0xFu << sh)) | (nib << sh);
    if (w == 0) zw0 = zwv; else if (w == 1) zw1 = zwv;
    else if (w == 2) zw2 = zwv; else zw3 = zwv;
  }

  // ---- outputs to LDS ----
  float Sf;
  {
    float d0_ = d2(E2_0, ONE2, 0.f), d1_ = d2(E2_1, ONE2, 0.f);
    float d2_ = d2(E2_2, ONE2, 0.f), d3_ = d2(E2_3, ONE2, 0.f);
    d0_ = d2(E2_4, ONE2, d0_); d1_ = d2(E2_5, ONE2, d1_);
    d2_ = d2(E2_6, ONE2, d2_); d3_ = d2(E2_7, ONE2, d3_);
    d0_ = d2(E2_8, ONE2, d0_); d1_ = d2(E2_9, ONE2, d1_);
    d2_ = d2(E2_10, ONE2, d2_); d3_ = d2(E2_11, ONE2, d3_);
    d0_ = d2(E2_12, ONE2, d0_); d1_ = d2(E2_13, ONE2, d1_);
    Sf = qsum4((d0_ + d1_) + (d2_ + d3_));
  }
  if (hq == 0) {
    lsel[cl] = __logf(Sf) + ESCLOG;
    zsl[cl * 4 + 0] = zw0; zsl[cl * 4 + 1] = zw1;
    zsl[cl * 4 + 2] = zw2; zsl[cl * 4 + 3] = zw3;
  }
  __syncthreads();

  // ---- fused final: moments + all four terms for this block's 8 n-rows ----
  {
    int nl2 = t >> 7;
    int mp = t & 127;
    int wsel = mp >> 5, sh0 = mp & 31;
    int cnt = 0;
    #pragma unroll 1
    for (int s2 = 0; s2 < 32; ++s2)
      cnt += (int)((zsl[(nl2 * 32 + s2) * 4 + wsel] >> sh0) & 1u);
    float EI = (float)cnt * (1.0f / 32.0f);
    float EII = 2.0f * EI - 1.0f;
    float l = lpil[nl2 * Mm + mp];
    int yv2 = yl[nl2];
    float bb = betag[yv2 * Mm + mp];
    float sp = (l > 20.0f) ? l : __logf(1.0f + __expf(l));
    float term = EII * bb + EI * l - sp;
    if (t < 256) term -= lsel[t] * (1.0f / 32.0f);
    if (t < 8) term += beta0g[yl[t]];
    red[t] = term;
  }
  __syncthreads();
  for (int off = 512; off > 0; off >>= 1) {
    if (t < off) red[t] += red[t + off];
    __syncthreads();
  }
  if (t == 0) atomicAdd(out, red[0]);
}

extern "C" void kernel_launch(void* const* d_in, const int* in_sizes, int n_in,
                              void* d_out, int out_size, void* d_ws, size_t ws_size,
                              hipStream_t stream) {
  const float* x = (const float*)d_in[0];
  const int* y = (const int*)d_in[1];
  const float* alpha0 = (const float*)d_in[2];
  const float* alpha = (const float*)d_in[3];
  const float* beta0 = (const float*)d_in[4];
  const float* beta = (const float*)d_in[5];
  float* out = (float*)d_out;

  uint16_t* lpib = (uint16_t*)d_ws;   // 4 bf16 split-K planes = 2 MB

  hipMemsetAsync(d_out, 0, sizeof(float), stream);
  k_lingemm<<<256, 256, 0, stream>>>(x, alpha, lpib);
  k_gibbs<<<256, 1024, 0, stream>>>(beta0, beta, y, alpha0, lpib, out);
}

// Round 11
// 92.609 us; speedup vs baseline: 6.9866x; 1.0454x over previous
//
#include <hip/hip_runtime.h>
#include <hip/hip_fp16.h>
#include <stdint.h>

#define Nn 2048
#define Ff 1024
#define Mm 128
#define Cc 100
#define Ss 32
#define NM (Nn * Mm)
#define ELS 132
#define SCP 128          // table row stride in halfs
#define TOFF 16416       // em2 offset in halfs (byte 32832 == 64 mod 128 -> +4 bank-quad phase)
#define ESC 0.015625f          // 2^-6 scale on E
#define ESCLOG 4.15888308336f  // 6*ln2

typedef _Float16 h2f __attribute__((ext_vector_type(2)));
typedef short bf8 __attribute__((ext_vector_type(8)));
typedef float f32x4 __attribute__((ext_vector_type(4)));

__device__ __forceinline__ float qsum4(float x) {
  int a = __builtin_amdgcn_update_dpp(0, __builtin_bit_cast(int, x), 0xB1, 0xF, 0xF, false);
  float xf = x + __builtin_bit_cast(float, a);
  int b = __builtin_amdgcn_update_dpp(0, __builtin_bit_cast(int, xf), 0x4E, 0xF, 0xF, false);
  return xf + __builtin_bit_cast(float, b);
}

__device__ __forceinline__ float dot2f(h2f a, h2f b, float c) {
#if __has_builtin(__builtin_amdgcn_fdot2)
  return __builtin_amdgcn_fdot2(a, b, c, false);
#else
  return fmaf((float)a[0], (float)b[0], fmaf((float)a[1], (float)b[1], c));
#endif
}
__device__ __forceinline__ float d2(__half2 e, uint32_t v, float c) {
  return dot2f(__builtin_bit_cast(h2f, e), __builtin_bit_cast(h2f, v), c);
}
__device__ __forceinline__ __half2 m2(__half2 e, uint32_t v) {
  return __hmul2(e, __builtin_bit_cast(__half2, v));
}

__device__ __forceinline__ uint32_t hash32(uint32_t chain, uint32_t ctr) {
  uint32_t h = chain * 0x9E3779B9u ^ (ctr * 0x85EBCA6Bu);
  h ^= h >> 16; h *= 0x7FEB352Du;
  h ^= h >> 15; h *= 0x846CA68Bu;
  h ^= h >> 16;
  return h;
}
__device__ __forceinline__ float urand(uint32_t chain, uint32_t ctr) {
  return (float)(hash32(chain, ctr) >> 8) * (1.0f / 16777216.0f);
}
__device__ __forceinline__ uint32_t f2bf(float f) {
  uint32_t b = __builtin_bit_cast(uint32_t, f);
  return (b + 0x7FFFu + ((b >> 16) & 1u)) >> 16;
}
__device__ __forceinline__ float bf2f(uint16_t u) {
  uint32_t b = ((uint32_t)u) << 16;
  return __builtin_bit_cast(float, b);
}
__device__ __forceinline__ int cperm(int c) {
  return ((c >> 2) & 3) * 32 + (c >> 4) * 4 + (c & 3);
}
__device__ __forceinline__ int swz(int p) {
  int win = p >> 5, o = p & 31;
  return win * 32 + (((o >> 3) + win) & 3) * 8 + (o & 7);
}

// ------------- Kernel A: lpib[ks] = bf16 partial of x @ alpha^T (split-K x4, MFMA) -------------
__global__ __launch_bounds__(256) void k_lingemm(const float* __restrict__ x,
                                                 const float* __restrict__ alpha,
                                                 uint16_t* __restrict__ lpib) {
  __shared__ uint4 sA[256];
  __shared__ uint4 sB[1024];
  const int t = threadIdx.x;
  const int mt = blockIdx.x >> 2;
  const int ks = blockIdx.x & 3;
  const int m0 = mt * 32;
  const int w = t >> 6;
  const int l = t & 63;

  f32x4 acc[2][2] = {{{0.f, 0.f, 0.f, 0.f}, {0.f, 0.f, 0.f, 0.f}},
                     {{0.f, 0.f, 0.f, 0.f}, {0.f, 0.f, 0.f, 0.f}}};

  for (int kk = 0; kk < 4; ++kk) {
    const int k0 = ks * 256 + kk * 64;
    __syncthreads();
    {
      int row = t >> 3, c = t & 7;
      const float* px = &x[(m0 + row) * Ff + k0 + c * 8];
      float4 f0 = *(const float4*)px;
      float4 f1 = *(const float4*)(px + 4);
      uint4 v;
      v.x = f2bf(f0.x) | (f2bf(f0.y) << 16);
      v.y = f2bf(f0.z) | (f2bf(f0.w) << 16);
      v.z = f2bf(f1.x) | (f2bf(f1.y) << 16);
      v.w = f2bf(f1.z) | (f2bf(f1.w) << 16);
      sA[row * 8 + (c ^ (row & 7))] = v;
      #pragma unroll
      for (int rr = 0; rr < 4; ++rr) {
        int idx = t + rr * 256;
        int rowb = idx >> 3, cb = idx & 7;
        const float* pa = &alpha[rowb * Ff + k0 + cb * 8];
        float4 g0 = *(const float4*)pa;
        float4 g1 = *(const float4*)(pa + 4);
        uint4 vb;
        vb.x = f2bf(g0.x) | (f2bf(g0.y) << 16);
        vb.y = f2bf(g0.z) | (f2bf(g0.w) << 16);
        vb.z = f2bf(g1.x) | (f2bf(g1.y) << 16);
        vb.w = f2bf(g1.z) | (f2bf(g1.w) << 16);
        sB[rowb * 8 + (cb ^ (rowb & 7))] = vb;
      }
    }
    __syncthreads();
    #pragma unroll
    for (int kc = 0; kc < 2; ++kc) {
      int chunk = kc * 4 + (l >> 4);
      bf8 av[2], bv[2];
      #pragma unroll
      for (int fm = 0; fm < 2; ++fm) {
        int row = fm * 16 + (l & 15);
        av[fm] = __builtin_bit_cast(bf8, sA[row * 8 + (chunk ^ (row & 7))]);
      }
      #pragma unroll
      for (int fn = 0; fn < 2; ++fn) {
        int rowb = w * 32 + fn * 16 + (l & 15);
        bv[fn] = __builtin_bit_cast(bf8, sB[rowb * 8 + (chunk ^ (rowb & 7))]);
      }
      #pragma unroll
      for (int fm = 0; fm < 2; ++fm)
        #pragma unroll
        for (int fn = 0; fn < 2; ++fn)
          acc[fm][fn] = __builtin_amdgcn_mfma_f32_16x16x32_bf16(av[fm], bv[fn], acc[fm][fn], 0, 0, 0);
    }
  }
  #pragma unroll
  for (int fm = 0; fm < 2; ++fm)
    #pragma unroll
    for (int fn = 0; fn < 2; ++fn)
      #pragma unroll
      for (int r = 0; r < 4; ++r) {
        int row = m0 + fm * 16 + (l >> 4) * 4 + r;
        int col = w * 32 + fn * 16 + (l & 15);
        lpib[ks * NM + row * Mm + col] = (uint16_t)f2bf(acc[fm][fn][r]);
      }
}

// prefetch table slice for step j into named regs (B3 is uint2)
#define PF(B0, B1, B2, B3, bit, j) {                                          \
    const __half* p_ = tab + ((bit) ? TOFF : 0) + (j) * SCP + hq * 32;        \
    B0 = *(const uint4*)(p_ + rot0);                                          \
    B1 = *(const uint4*)(p_ + rot1);                                          \
    B2 = *(const uint4*)(p_ + rot2);                                          \
    B3 = *(const uint2*)(p_ + rot3); }

// one Gibbs step on named regs (E2_0..E2_13, Sb updated in place)
#define STEP(B0, B1, B2, B3, zjp, eyel, u, bout) {                            \
    float d0_ = d2(E2_0, B0.x, 0.f), d1_ = d2(E2_1, B0.y, 0.f);               \
    float d2_ = d2(E2_2, B0.z, 0.f), d3_ = d2(E2_3, B0.w, 0.f);               \
    d0_ = d2(E2_4, B1.x, d0_); d1_ = d2(E2_5, B1.y, d1_);                     \
    d2_ = d2(E2_6, B1.z, d2_); d3_ = d2(E2_7, B1.w, d3_);                     \
    d0_ = d2(E2_8, B2.x, d0_); d1_ = d2(E2_9, B2.y, d1_);                     \
    d2_ = d2(E2_10, B2.z, d2_); d3_ = d2(E2_11, B2.w, d3_);                   \
    d0_ = d2(E2_12, B3.x, d0_); d1_ = d2(E2_13, B3.y, d1_);                   \
    float D_ = qsum4((d0_ + d1_) + (d2_ + d3_));                              \
    float Sp_ = (zjp) ? Sb : D_;                                              \
    float Sn_ = (zjp) ? D_ : Sb;                                              \
    float odds_ = (eyel) * Sn_ * __builtin_amdgcn_rcpf(Sp_);                  \
    uint32_t znp_ = ((u) * (1.0f + odds_) < odds_) ? 1u : 0u;                 \
    if ((znp_ ^ (zjp)) != 0u) {                                               \
      E2_0 = m2(E2_0, B0.x); E2_1 = m2(E2_1, B0.y);                           \
      E2_2 = m2(E2_2, B0.z); E2_3 = m2(E2_3, B0.w);                           \
      E2_4 = m2(E2_4, B1.x); E2_5 = m2(E2_5, B1.y);                           \
      E2_6 = m2(E2_6, B1.z); E2_7 = m2(E2_7, B1.w);                           \
      E2_8 = m2(E2_8, B2.x); E2_9 = m2(E2_9, B2.y);                           \
      E2_10 = m2(E2_10, B2.z); E2_11 = m2(E2_11, B2.w);                       \
      E2_12 = m2(E2_12, B3.x); E2_13 = m2(E2_13, B3.y);                       \
      Sb = D_;                                                                \
    }                                                                         \
    bout = znp_; }

#define MKE(k)                                                                \
  {                                                                           \
    float2 b0v = *(const float2*)&b0p[c0m + 2 * (k)];                         \
    float ea_ = __expf(acc[(2 * (k)) >> 2][(2 * (k)) & 3] + b0v.x) * ESC;     \
    float eb_ = __expf(acc[(2 * (k) + 1) >> 2][(2 * (k) + 1) & 3] + b0v.y) * ESC; \
    E2_##k = __floats2half2_rn(ea_, eb_);                                     \
  }

#define SHF(k) E2_##k = __builtin_bit_cast(__half2,                           \
    (uint32_t)__shfl((int)__builtin_bit_cast(uint32_t, E2_##k), src, 64));

// ------------- Kernel B: fused init(MFMA) + deep-prefetch Gibbs sweep + final reduction -------------
// 256 blocks x 1024 threads: 8 n-rows, 256 chains/block, 4 lanes/chain (lane-quads).
__global__ __launch_bounds__(1024, 4) void k_gibbs(const float* __restrict__ beta0g,
                                                   const float* __restrict__ betag,
                                                   const int* __restrict__ yg,
                                                   const float* __restrict__ alpha0,
                                                   const uint16_t* __restrict__ lpib,
                                                   float* __restrict__ out) {
  __shared__ __attribute__((aligned(16))) char SM[83808];
  uint16_t* bsb = (uint16_t*)SM;            // phase A: beta bf16 [112][128] swizzled (28672 B)
  __half* tab = (__half*)SM;                // phase B: ep2 @0, em2 @TOFF (65664 B)
  float* elpi = (float*)(SM + 65600);       // [8][ELS]; aliased by red in final phase
  float* lpil = (float*)(SM + 69824);       // [8][128]
  uint32_t* zsl = (uint32_t*)(SM + 73920);  // [256][4]
  float* lsel = (float*)(SM + 78016);       // [256]
  int* yl = (int*)(SM + 79040);             // [8]
  float* b0p = (float*)(SM + 79072);        // [128] permuted beta0
  float* eyelLUT = (float*)(SM + 79584);    // [8][ELS]: exp(2*beta[y][j]) * exp(lpi[n][j])
  float* red = (float*)(SM + 65600);        // [1024] final-phase alias

  const int t = threadIdx.x;
  const int n0 = blockIdx.x * 8;
  const int L = t & 63;

  // ---- phase A: stage beta bf16 (row-swizzled 16B chunks), permuted beta0, lpi sums ----
  for (int idx = t; idx < 112 * 32; idx += 1024) {
    int row = idx >> 5, u = idx & 31;
    int rr = (row < Cc) ? row : 0;
    float4 v = *(const float4*)&betag[rr * Mm + u * 4];
    uint2 o;
    o.x = f2bf(v.x) | (f2bf(v.y) << 16);
    o.y = f2bf(v.z) | (f2bf(v.w) << 16);
    int k = u >> 1, sub = u & 1;
    int kp = k ^ (row & 15);
    *(uint2*)&bsb[row * 128 + kp * 8 + sub * 4] = o;
  }
  if (t < 128) b0p[cperm(t)] = (t < Cc) ? beta0g[t] : 0.0f;
  {
    int nls = t >> 7, j = t & 127;
    int g = (n0 + nls) * Mm + j;
    float lv = bf2f(lpib[g]) + bf2f(lpib[NM + g]) + bf2f(lpib[2 * NM + g]) +
               bf2f(lpib[3 * NM + g]) + alpha0[j];
    lpil[nls * Mm + j] = lv;
    elpi[nls * ELS + j] = __expf(lv);
  }
  if (t < 8) yl[t] = yg[n0 + t];
  __syncthreads();

  // eyelLUT: coalesced global beta read (L2-hot), f32 exact; elpi entry written by this thread
  {
    int nl2 = t >> 7, j = t & 127;
    float b = betag[yl[nl2] * Mm + j];
    eyelLUT[nl2 * ELS + j] = __expf(2.0f * b) * elpi[nl2 * ELS + j];
  }

  // quad mapping: chain cl = t>>2, slice hq = t&3
  const int cl = t >> 2;
  const int hq = t & 3;
  const int nl = cl >> 5;                 // wave-uniform
  const int s = cl & 31;
  const uint32_t chain = (uint32_t)((n0 + nl) * Ss + s);

  // ---- Z0: lane draws word hq of chain cl ----
  uint32_t zz = 0;
  {
    #pragma unroll 1
    for (int b5 = 0; b5 < 32; ++b5) {
      int mloc = (b5 + hq * 8) & 31;
      int m = hq * 32 + mloc;
      float u = urand(chain, (uint32_t)m);
      float el = elpi[nl * ELS + m];
      zz |= (u * (1.0f + el) < el) ? (1u << mloc) : 0u;
    }
  }

  // ---- init lin = Z0 . beta via MFMA (MFMA roles: chain = L&15, window hw = L>>4) ----
  f32x4 acc[7];
  #pragma unroll
  for (int T = 0; T < 7; ++T) acc[T] = (f32x4){0.f, 0.f, 0.f, 0.f};
  {
    const int liw = L & 15, hw = L >> 4;
    #pragma unroll
    for (int ks = 0; ks < 4; ++ks) {
      uint32_t zw = (uint32_t)__shfl((int)zz, (liw << 2) | ks, 64);
      uint32_t bits8 = (zw >> (hw * 8)) & 0xFFu;
      uint4 pk;
      {
        uint32_t p0 = ((bits8 >> 0) & 1u) ? 0x3F80u : 0xBF80u;
        uint32_t p1 = ((bits8 >> 1) & 1u) ? 0x3F80u : 0xBF80u;
        uint32_t p2 = ((bits8 >> 2) & 1u) ? 0x3F80u : 0xBF80u;
        uint32_t p3 = ((bits8 >> 3) & 1u) ? 0x3F80u : 0xBF80u;
        uint32_t p4 = ((bits8 >> 4) & 1u) ? 0x3F80u : 0xBF80u;
        uint32_t p5 = ((bits8 >> 5) & 1u) ? 0x3F80u : 0xBF80u;
        uint32_t p6 = ((bits8 >> 6) & 1u) ? 0x3F80u : 0xBF80u;
        uint32_t p7 = ((bits8 >> 7) & 1u) ? 0x3F80u : 0xBF80u;
        pk.x = p0 | (p1 << 16); pk.y = p2 | (p3 << 16);
        pk.z = p4 | (p5 << 16); pk.w = p6 | (p7 << 16);
      }
      bf8 B = __builtin_bit_cast(bf8, pk);
      #pragma unroll
      for (int T = 0; T < 7; ++T) {
        int row = T * 16 + liw;
        int kk = ks * 4 + hw;
        bf8 A = __builtin_bit_cast(bf8, *(const uint4*)&bsb[row * 128 + (kk ^ (row & 15)) * 8]);
        acc[T] = __builtin_amdgcn_mfma_f32_16x16x32_bf16(A, B, acc[T], 0, 0, 0);
      }
    }
  }

  // ---- E = exp(lin + beta0)*2^-6 packed f16 (MFMA layout), then quad shuffle ----
  const __half2 HZERO = __builtin_bit_cast(__half2, 0u);
  __half2 E2_0, E2_1, E2_2, E2_3, E2_4, E2_5, E2_6, E2_7;
  __half2 E2_8, E2_9, E2_10, E2_11, E2_12, E2_13;
  {
    int c0m = (L >> 4) * 32;
    MKE(0) MKE(1) MKE(2) MKE(3) MKE(4) MKE(5) MKE(6)
    MKE(7) MKE(8) MKE(9) MKE(10) MKE(11) MKE(12) MKE(13)
    if ((L >> 4) != 0) { E2_12 = HZERO; E2_13 = HZERO; }  // classes >= 100
  }
  {
    int src = (L >> 2) | ((L & 3) << 4);
    SHF(0) SHF(1) SHF(2) SHF(3) SHF(4) SHF(5) SHF(6)
    SHF(7) SHF(8) SHF(9) SHF(10) SHF(11) SHF(12) SHF(13)
  }
  uint32_t zw0 = (uint32_t)__shfl((int)zz, (L & ~3) | 0, 64);
  uint32_t zw1 = (uint32_t)__shfl((int)zz, (L & ~3) | 1, 64);
  uint32_t zw2 = (uint32_t)__shfl((int)zz, (L & ~3) | 2, 64);
  uint32_t zw3 = (uint32_t)__shfl((int)zz, (L & ~3) | 3, 64);

  const uint32_t ONE2 = 0x3C003C00u;   // (1.0h, 1.0h)
  float Sb;
  {
    float d0_ = d2(E2_0, ONE2, 0.f), d1_ = d2(E2_1, ONE2, 0.f);
    float d2_ = d2(E2_2, ONE2, 0.f), d3_ = d2(E2_3, ONE2, 0.f);
    d0_ = d2(E2_4, ONE2, d0_); d1_ = d2(E2_5, ONE2, d1_);
    d2_ = d2(E2_6, ONE2, d2_); d3_ = d2(E2_7, ONE2, d3_);
    d0_ = d2(E2_8, ONE2, d0_); d1_ = d2(E2_9, ONE2, d1_);
    d2_ = d2(E2_10, ONE2, d2_); d3_ = d2(E2_11, ONE2, d3_);
    d0_ = d2(E2_12, ONE2, d0_); d1_ = d2(E2_13, ONE2, d1_);
    Sb = qsum4((d0_ + d1_) + (d2_ + d3_));
  }

  // ---- phase B: rebuild LDS as f16 tables, permuted+chunk-rotated positions ----
  __syncthreads();
  for (int idx = t; idx < 32 * Cc; idx += 1024) {
    int j4 = idx / Cc;
    int c = idx - j4 * Cc;
    int ps = swz(cperm(c));
    float4 bv = *(const float4*)&betag[c * Mm + j4 * 4];
    int j = j4 * 4;
    tab[(j + 0) * SCP + ps] = __float2half(__expf(2.0f * bv.x));
    tab[TOFF + (j + 0) * SCP + ps] = __float2half(__expf(-2.0f * bv.x));
    tab[(j + 1) * SCP + ps] = __float2half(__expf(2.0f * bv.y));
    tab[TOFF + (j + 1) * SCP + ps] = __float2half(__expf(-2.0f * bv.y));
    tab[(j + 2) * SCP + ps] = __float2half(__expf(2.0f * bv.z));
    tab[TOFF + (j + 2) * SCP + ps] = __float2half(__expf(-2.0f * bv.z));
    tab[(j + 3) * SCP + ps] = __float2half(__expf(2.0f * bv.w));
    tab[TOFF + (j + 3) * SCP + ps] = __float2half(__expf(-2.0f * bv.w));
  }
  for (int idx = t; idx < Mm * 28; idx += 1024) {
    int j = idx / 28;
    int c = Cc + (idx - j * 28);
    int ps = swz(cperm(c));
    tab[j * SCP + ps] = __float2half(1.0f);
    tab[TOFF + j * SCP + ps] = __float2half(1.0f);
  }
  for (int idx = t; idx < Mm * 16; idx += 1024) {
    int j = idx >> 4;
    int win = (idx >> 2) & 3, o = 28 + (idx & 3);
    int ps = win * 32 + (((o >> 3) + win) & 3) * 8 + (o & 7);
    tab[j * SCP + ps] = __float2half(1.0f);
    tab[TOFF + j * SCP + ps] = __float2half(1.0f);
  }
  __syncthreads();

  // ---- Gibbs sweep: pair-level ping-pong, depth-2/3 static prefetch ----
  const int rot0 = ((0 + hq) & 3) * 8;
  const int rot1 = ((1 + hq) & 3) * 8;
  const int rot2 = ((2 + hq) & 3) * 8;
  const int rot3 = ((3 + hq) & 3) * 8;

  uint4 sA00, sA01, sA02, sA10, sA11, sA12;
  uint2 sA03, sA13;
  uint4 sB00, sB01, sB02, sB10, sB11, sB12;
  uint2 sB03, sB13;

  // prologue: steps 0,1 into A; eyel group 0
  PF(sA00, sA01, sA02, sA03, zw0 & 1u, 0)
  PF(sA10, sA11, sA12, sA13, (zw0 >> 1) & 1u, 1)
  float4 eycur = *(const float4*)&eyelLUT[nl * ELS];

  #pragma unroll
  for (int w = 0; w < 4; ++w) {
    uint32_t zwv = (w == 0) ? zw0 : ((w == 1) ? zw1 : ((w == 2) ? zw2 : zw3));
    const uint32_t nextw = (w == 0) ? zw1 : ((w == 1) ? zw2 : ((w == 2) ? zw3 : 0u));
    #pragma unroll 1
    for (int g = 0; g < 8; ++g) {
      const int jb = w * 32 + g * 4;
      const int sh = g * 4;
      uint64_t win = (zwv >> sh) | ((uint64_t)nextw << (32 - sh));
      uint32_t b0 = (uint32_t)win & 1u;
      uint32_t b1 = ((uint32_t)(win >> 1)) & 1u;
      uint32_t b2 = ((uint32_t)(win >> 2)) & 1u;
      uint32_t b3 = ((uint32_t)(win >> 3)) & 1u;
      uint32_t c4 = ((uint32_t)(win >> 4)) & 1u;
      uint32_t c5 = ((uint32_t)(win >> 5)) & 1u;
      uint32_t h1 = hash32(chain, 256u + (uint32_t)jb);
      uint32_t h2 = hash32(chain, 258u + (uint32_t)jb);
      float u0 = (float)(h1 & 0xFFFFu) * (1.0f / 65536.0f);
      float u1 = (float)(h1 >> 16) * (1.0f / 65536.0f);
      float u2 = (float)(h2 & 0xFFFFu) * (1.0f / 65536.0f);
      float u3 = (float)(h2 >> 16) * (1.0f / 65536.0f);

      PF(sB00, sB01, sB02, sB03, b2, jb + 2)
      PF(sB10, sB11, sB12, sB13, b3, jb + 3)
      __builtin_amdgcn_sched_barrier(0);
      STEP(sA00, sA01, sA02, sA03, b0, eycur.x, u0, b0)
      STEP(sA10, sA11, sA12, sA13, b1, eycur.y, u1, b1)
      PF(sA00, sA01, sA02, sA03, c4, (jb + 4) & 127)
      PF(sA10, sA11, sA12, sA13, c5, (jb + 5) & 127)
      float4 eyn = *(const float4*)&eyelLUT[nl * ELS + ((jb + 4) & 127)];
      __builtin_amdgcn_sched_barrier(0);
      STEP(sB00, sB01, sB02, sB03, b2, eycur.z, u2, b2)
      STEP(sB10, sB11, sB12, sB13, b3, eycur.w, u3, b3)
      eycur = eyn;

      uint32_t nib = b0 | (b1 << 1) | (b2 << 2) | (b3 << 3);
      zwv = (zwv & ~(0xFu << sh)) | (nib << sh);
    }
    if (w == 0) zw0 = zwv; else if (w == 1) zw1 = zwv;
    else if (w == 2) zw2 = zwv; else zw3 = zwv;
  }

  // ---- outputs to LDS ----
  float Sf;
  {
    float d0_ = d2(E2_0, ONE2, 0.f), d1_ = d2(E2_1, ONE2, 0.f);
    float d2_ = d2(E2_2, ONE2, 0.f), d3_ = d2(E2_3, ONE2, 0.f);
    d0_ = d2(E2_4, ONE2, d0_); d1_ = d2(E2_5, ONE2, d1_);
    d2_ = d2(E2_6, ONE2, d2_); d3_ = d2(E2_7, ONE2, d3_);
    d0_ = d2(E2_8, ONE2, d0_); d1_ = d2(E2_9, ONE2, d1_);
    d2_ = d2(E2_10, ONE2, d2_); d3_ = d2(E2_11, ONE2, d3_);
    d0_ = d2(E2_12, ONE2, d0_); d1_ = d2(E2_13, ONE2, d1_);
    Sf = qsum4((d0_ + d1_) + (d2_ + d3_));
  }
  if (hq == 0) {
    lsel[cl] = __logf(Sf) + ESCLOG;
    zsl[cl * 4 + 0] = zw0; zsl[cl * 4 + 1] = zw1;
    zsl[cl * 4 + 2] = zw2; zsl[cl * 4 + 3] = zw3;
  }
  __syncthreads();

  // ---- fused final: moments + all four terms for this block's 8 n-rows ----
  {
    int nl2 = t >> 7;
    int mp = t & 127;
    int wsel = mp >> 5, sh0 = mp & 31;
    int cnt = 0;
    #pragma unroll 1
    for (int s2 = 0; s2 < 32; ++s2)
      cnt += (int)((zsl[(nl2 * 32 + s2) * 4 + wsel] >> sh0) & 1u);
    float EI = (float)cnt * (1.0f / 32.0f);
    float EII = 2.0f * EI - 1.0f;
    float l = lpil[nl2 * Mm + mp];
    int yv2 = yl[nl2];
    float bb = betag[yv2 * Mm + mp];
    float sp = (l > 20.0f) ? l : __logf(1.0f + __expf(l));
    float term = EII * bb + EI * l - sp;
    if (t < 256) term -= lsel[t] * (1.0f / 32.0f);
    if (t < 8) term += beta0g[yl[t]];
    red[t] = term;
  }
  __syncthreads();
  for (int off = 512; off > 0; off >>= 1) {
    if (t < off) red[t] += red[t + off];
    __syncthreads();
  }
  if (t == 0) atomicAdd(out, red[0]);
}

extern "C" void kernel_launch(void* const* d_in, const int* in_sizes, int n_in,
                              void* d_out, int out_size, void* d_ws, size_t ws_size,
                              hipStream_t stream) {
  const float* x = (const float*)d_in[0];
  const int* y = (const int*)d_in[1];
  const float* alpha0 = (const float*)d_in[2];
  const float* alpha = (const float*)d_in[3];
  const float* beta0 = (const float*)d_in[4];
  const float* beta = (const float*)d_in[5];
  float* out = (float*)d_out;

  uint16_t* lpib = (uint16_t*)d_ws;   // 4 bf16 split-K planes = 2 MB

  hipMemsetAsync(d_out, 0, sizeof(float), stream);
  k_lingemm<<<256, 256, 0, stream>>>(x, alpha, lpib);
  k_gibbs<<<256, 1024, 0, stream>>>(beta0, beta, y, alpha0, lpib, out);
}